// Round 9
// baseline (1064.351 us; speedup 1.0000x reference)
//
#include <hip/hip_runtime.h>
#include <hip/hip_bf16.h>

// Model dims (compile-time)
#define BB 128
#define SS 256
#define DD 128
#define DI 256      // 2*D
#define NH 4
#define DHM 64      // DI/NH
#define DHS 32      // D/NH
#define NROWS (BB*SS)   // 32768

#define WAVE_SYNC() do { asm volatile("s_waitcnt lgkmcnt(0)" ::: "memory"); __builtin_amdgcn_wave_barrier(); } while (0)

typedef __attribute__((ext_vector_type(8))) short short8;
typedef __attribute__((ext_vector_type(4))) float f32x4;
typedef __attribute__((ext_vector_type(2))) float f32x2;
typedef __attribute__((ext_vector_type(2))) int i32x2;

__device__ __forceinline__ float sigmoidf_(float x) { return 1.f / (1.f + __expf(-x)); }
__device__ __forceinline__ float siluf_(float x) { return x / (1.f + __expf(-x)); }
// stable log_sigmoid
__device__ __forceinline__ float logsigf_(float x) {
    return (x >= 0.f) ? -log1pf(__expf(-x)) : x - log1pf(__expf(x));
}
__device__ __forceinline__ float tanhf_(float x) {
    float e = __expf(2.f * x);
    return 1.f - 2.f / (e + 1.f);
}
// fp32 -> bf16 bits, round-to-nearest-even (inputs are finite)
__device__ __forceinline__ ushort bf16u(float x) {
    unsigned u = __float_as_uint(x);
    u += 0x7fffu + ((u >> 16) & 1u);
    return (ushort)(u >> 16);
}
__device__ __forceinline__ float rdlane(float v, int lane) {
    return __int_as_float(__builtin_amdgcn_readlane(__float_as_int(v), lane));
}
// DPP add: x + dpp(x) with given ctrl (VALU-speed cross-lane; bound_ctrl=1 -> 0 fill)
#define DPPADD(x, ctrl) ((x) + __int_as_float(__builtin_amdgcn_update_dpp(0, __float_as_int(x), (ctrl), 0xf, 0xf, true)))

// ---------------- fp32 -> bf16 copy ----------------
__global__ __launch_bounds__(256) void tobf16_kernel(const float* __restrict__ src,
        ushort* __restrict__ dst, int n) {
    int i = blockIdx.x * 256 + threadIdx.x;
    if (i < n) dst[i] = bf16u(src[i]);
}

// ---------------- densify sLSTM block-diag gate weights -> bf16 [i2][pair][256][128] ----------------
// Output channel layout per pair: oc = h*64 + l, l<32 -> gate0 ch l, l>=32 -> gate1 ch l-32.
// (pair 0: gates i,f from xc;  pair 1: gates z,o from xn)
__global__ __launch_bounds__(256) void densify_kernel(const float* __restrict__ wi,
        const float* __restrict__ wf, const float* __restrict__ wz,
        const float* __restrict__ wo, ushort* __restrict__ dst) {
    int idx = blockIdx.x * 256 + threadIdx.x;   // 2*2*256*128 = 262144
    int t = idx & 127;
    int oc = (idx >> 7) & 255;
    int pair = (idx >> 15) & 1;
    int i2 = idx >> 16;
    int h = oc >> 6, l = oc & 63, gate = (l >> 5) & 1, e = l & 31;
    const float* w = pair == 0 ? (gate == 0 ? wi : wf) : (gate == 0 ? wz : wo);
    float val = ((t >> 5) == h) ? w[i2 * 4096 + h * 1024 + e * 32 + (t & 31)] : 0.f;
    dst[idx] = bf16u(val);
}

// ---------------- embedding ----------------
__global__ __launch_bounds__(256) void embed_kernel(const int* __restrict__ x,
        const float* __restrict__ emb, float* __restrict__ h, int total) {
    int i = blockIdx.x * 256 + threadIdx.x;
    if (i >= total) return;
    int row = i >> 7;          // D=128
    int c = i & 127;
    h[i] = emb[x[row] * DD + c];
}

// ---------------- LayerNorm over D=128 (block=64 threads, 1 row); fp32 + bf16 out ----------------
__global__ __launch_bounds__(64) void ln128_kernel(const float* __restrict__ x,
        const float* __restrict__ w, float* __restrict__ out, ushort* __restrict__ outb) {
    int row = blockIdx.x;
    int lane = threadIdx.x;
    const float* xr = x + (size_t)row * DD;
    float a = xr[lane], b = xr[lane + 64];
    float s1 = a + b, s2 = a * a + b * b;
    #pragma unroll
    for (int o = 32; o; o >>= 1) { s1 += __shfl_xor(s1, o); s2 += __shfl_xor(s2, o); }
    float mu = s1 * (1.f / 128.f);
    float var = s2 * (1.f / 128.f) - mu * mu;
    float inv = rsqrtf(var + 1e-5f);
    float va = (a - mu) * inv * w[lane];
    float vb = (b - mu) * inv * w[lane + 64];
    float* orow = out + (size_t)row * DD;
    orow[lane] = va; orow[lane + 64] = vb;
    ushort* brow = outb + (size_t)row * DD;
    brow[lane] = bf16u(va); brow[lane + 64] = bf16u(vb);
}

// ---------------- bf16 MFMA GEMM: C[M,N] (+)= A[M,K](lda) @ W[N,K]^T ----------------
// 128x128 tile, BK=32, 4 waves (2x2 of 64x64), XOR-swizzled 16B chunks in LDS.
__global__ __launch_bounds__(256, 2) void gemm_bf16_kernel(const ushort* __restrict__ A, int lda,
        const ushort* __restrict__ W, float* __restrict__ C, int ldc, int K, int addC) {
    __shared__ ushort As[128 * 32];
    __shared__ ushort Bs[128 * 32];
    int m0 = blockIdx.x * 128;
    int n0 = blockIdx.y * 128;
    int tid = threadIdx.x;
    int wv = tid >> 6, l = tid & 63;
    int lr = l & 15, lg = l >> 4, g4 = lg * 4;
    int wr = wv >> 1, wc = wv & 1;
    int sr = tid >> 1;                  // staging row 0..127
    int sc = (tid & 1) * 2;             // staging chunk base {0,2}

    f32x4 acc[4][4] = {};
    for (int k0 = 0; k0 < K; k0 += 32) {
        __syncthreads();
        #pragma unroll
        for (int u = 0; u < 2; ++u) {
            int c = sc + u;
            uint4 av = *(const uint4*)(A + (size_t)(m0 + sr) * lda + k0 + c * 8);
            *(uint4*)(As + sr * 32 + ((c ^ (sr & 3)) * 8)) = av;
            uint4 wv4 = *(const uint4*)(W + (size_t)(n0 + sr) * K + k0 + c * 8);
            *(uint4*)(Bs + sr * 32 + ((c ^ (sr & 3)) * 8)) = wv4;
        }
        __syncthreads();
        short8 af[4], bf[4];
        #pragma unroll
        for (int fm = 0; fm < 4; ++fm) {
            int row = wr * 64 + fm * 16 + lr;
            af[fm] = *(const short8*)(As + row * 32 + ((lg ^ (row & 3)) * 8));
        }
        #pragma unroll
        for (int fn = 0; fn < 4; ++fn) {
            int row = wc * 64 + fn * 16 + lr;
            bf[fn] = *(const short8*)(Bs + row * 32 + ((lg ^ (row & 3)) * 8));
        }
        #pragma unroll
        for (int fm = 0; fm < 4; ++fm)
            #pragma unroll
            for (int fn = 0; fn < 4; ++fn)
                acc[fm][fn] = __builtin_amdgcn_mfma_f32_16x16x32_bf16(af[fm], bf[fn], acc[fm][fn], 0, 0, 0);
    }
    #pragma unroll
    for (int fm = 0; fm < 4; ++fm) {
        #pragma unroll
        for (int fn = 0; fn < 4; ++fn) {
            #pragma unroll
            for (int r = 0; r < 4; ++r) {
                size_t idx = (size_t)(m0 + wr * 64 + fm * 16 + g4 + r) * ldc + n0 + wc * 64 + fn * 16 + lr;
                if (addC) C[idx] += acc[fm][fn][r]; else C[idx] = acc[fm][fn][r];
            }
        }
    }
}

// ---------------- depthwise causal conv (K=4) + silu (fp32 out + optional bf16 out) ----------------
__global__ __launch_bounds__(256) void conv_silu_kernel(const float* __restrict__ x, int ldx, int C,
        const float* __restrict__ w, const float* __restrict__ bias,
        float* __restrict__ out, int ldo, ushort* __restrict__ outb, int total) {
    int i = blockIdx.x * 256 + threadIdx.x;
    if (i >= total) return;
    int c = i % C;
    size_t row = (size_t)(i / C);
    int s = (int)(row & (SS - 1));
    float acc = bias[c];
    #pragma unroll
    for (int j = 0; j < 4; ++j) {
        int ss = s - 3 + j;
        if (ss >= 0) acc += x[(row + (size_t)(ss - s)) * ldx + c] * w[c * 4 + j];
    }
    float val = siluf_(acc);
    out[row * ldo + c] = val;
    if (outb) outb[row * ldo + c] = bf16u(val);
}

// ---------------- mLSTM block-diagonal q,k,v (8x8 blocks) + bf16 per-head copies ----------------
__global__ __launch_bounds__(256) void mqkv_kernel(const float* __restrict__ xca,
        const float* __restrict__ xz, const float* __restrict__ qw,
        const float* __restrict__ kw, const float* __restrict__ vw,
        float* __restrict__ q, float* __restrict__ k, float* __restrict__ v,
        ushort* __restrict__ qb16, ushort* __restrict__ kb16, int total) {
    int i = blockIdx.x * 256 + threadIdx.x;
    if (i >= total) return;
    int c = i & 255;
    size_t row = (size_t)(i >> 8);
    int nb = c >> 3, e = c & 7;
    const float* xc8 = xca + row * 256 + nb * 8;
    const float* xi8 = xz + row * 512 + nb * 8;
    const float* qw8 = qw + (size_t)(nb * 8 + e) * 8;
    const float* kw8 = kw + (size_t)(nb * 8 + e) * 8;
    const float* vw8 = vw + (size_t)(nb * 8 + e) * 8;
    float aq = 0.f, ak = 0.f, av = 0.f;
    #pragma unroll
    for (int t = 0; t < 8; ++t) {
        float xcv = xc8[t], xiv = xi8[t];
        aq += xcv * qw8[t];
        ak += xcv * kw8[t];
        av += xiv * vw8[t];
    }
    q[i] = aq; k[i] = ak; v[i] = av;
    // bf16 per-head layout [bh][s][64] for the MFMA core
    int h2 = c >> 6, dd = c & 63;
    size_t be = ((((row >> 8) << 2) + h2) * 256 + (row & 255)) * 64 + dd;
    qb16[be] = bf16u(aq);
    kb16[be] = bf16u(ak);
}

// ---------------- mLSTM input/forget gate projections (dot-768 per (row,h)) ----------------
__global__ __launch_bounds__(256) void mgate_kernel(const float* __restrict__ q,
        const float* __restrict__ k, const float* __restrict__ v,
        const float* __restrict__ igw, const float* __restrict__ igb,
        const float* __restrict__ fgw, const float* __restrict__ fgb,
        float* __restrict__ ip, float* __restrict__ fp) {
    int row = blockIdx.x;
    int t = threadIdx.x;
    float qv = q[(size_t)row * 256 + t];
    float kv = k[(size_t)row * 256 + t];
    float vv = v[(size_t)row * 256 + t];
    float pi[4], pf[4];
    #pragma unroll
    for (int hh = 0; hh < 4; ++hh) {
        const float* wi = igw + hh * 768;
        const float* wf = fgw + hh * 768;
        pi[hh] = qv * wi[t] + kv * wi[256 + t] + vv * wi[512 + t];
        pf[hh] = qv * wf[t] + kv * wf[256 + t] + vv * wf[512 + t];
    }
    #pragma unroll
    for (int hh = 0; hh < 4; ++hh) {
        #pragma unroll
        for (int o = 32; o; o >>= 1) {
            pi[hh] += __shfl_xor(pi[hh], o);
            pf[hh] += __shfl_xor(pf[hh], o);
        }
    }
    __shared__ float red[2][4][4];
    int wave = t >> 6, lane = t & 63;
    if (lane == 0) {
        #pragma unroll
        for (int hh = 0; hh < 4; ++hh) { red[0][wave][hh] = pi[hh]; red[1][wave][hh] = pf[hh]; }
    }
    __syncthreads();
    if (t < 8) {
        int g = t >> 2, hh = t & 3;
        float s = red[g][0][hh] + red[g][1][hh] + red[g][2][hh] + red[g][3][hh];
        int b = row >> 8, sidx = row & 255;
        size_t oidx = (size_t)(b * NH + hh) * SS + sidx;
        if (g == 0) ip[oidx] = s + igb[hh];
        else        fp[oidx] = s + fgb[hh];
    }
}

// ---------------- mLSTM decay prefix scan: L (cum log-sigmoid), E = ip - L, PM = prefix-max(E) ----------------
__global__ __launch_bounds__(64) void mprep_kernel(const float* __restrict__ ip,
        const float* __restrict__ fp, float* __restrict__ L,
        float* __restrict__ E, float* __restrict__ PM) {
    int bh = blockIdx.x;
    int lane = threadIdx.x;
    __shared__ float sfp[SS], sip[SS], sL[SS], sE[SS], sPM[SS];
    for (int u = lane; u < SS; u += 64) {
        sfp[u] = fp[(size_t)bh * SS + u];
        sip[u] = ip[(size_t)bh * SS + u];
    }
    __syncthreads();
    if (lane == 0) {
        float run = 0.f, pm = -INFINITY;
        for (int j = 0; j < SS; ++j) {
            run += logsigf_(sfp[j]);
            float e = sip[j] - run;
            pm = fmaxf(pm, e);
            sL[j] = run; sE[j] = e; sPM[j] = pm;
        }
    }
    __syncthreads();
    for (int u = lane; u < SS; u += 64) {
        L[(size_t)bh * SS + u] = sL[u];
        E[(size_t)bh * SS + u] = sE[u];
        PM[(size_t)bh * SS + u] = sPM[u];
    }
}

// ---------------- V transpose to [bh][64][256] bf16 ----------------
__global__ __launch_bounds__(256) void vtrans_kernel(const float* __restrict__ v,
        ushort* __restrict__ vt) {
    int blk = blockIdx.x;
    int st = blk & 3, bh = blk >> 2;
    int b = bh >> 2, h = bh & 3;
    int tid = threadIdx.x;
    __shared__ float tile[64][65];
    int s0 = st * 64;
    #pragma unroll
    for (int u = 0; u < 16; ++u) {
        int idx = u * 256 + tid;
        int sl = idx >> 6, dl = idx & 63;
        tile[sl][dl] = v[((size_t)(b * 256 + s0 + sl)) * 256 + h * 64 + dl];
    }
    __syncthreads();
    #pragma unroll
    for (int u = 0; u < 16; ++u) {
        int idx = u * 256 + tid;
        int dl = idx >> 6, sl = idx & 63;
        vt[((size_t)bh * 64 + dl) * 256 + s0 + sl] = bf16u(tile[sl][dl]);
    }
}

// ---------------- mLSTM parallel core via MFMA ----------------
__global__ __launch_bounds__(256, 2) void mlstm_mfma_kernel(
        const ushort* __restrict__ qb, const ushort* __restrict__ kb,
        const ushort* __restrict__ vt, const float* __restrict__ Lg,
        const float* __restrict__ Eg, const float* __restrict__ PMg,
        float* __restrict__ hmout) {
    int bh = blockIdx.x;
    int b = bh >> 2, h = bh & 3;
    int tid = threadIdx.x;
    int wv = tid >> 6, l = tid & 63;
    int lr = l & 15, lg = l >> 4, g4 = lg * 4;

    __shared__ ushort Kb[16384];     // 32 KB
    __shared__ ushort Vt[16384];     // 32 KB
    __shared__ ushort Pl[4 * 640];   // per-wave 16x40 bf16
    __shared__ float sE[SS], sPM[SS], sL[SS];

    const size_t gb16 = (size_t)bh * 16384;
    #pragma unroll
    for (int p2 = 0; p2 < 8; ++p2) {
        int id = p2 * 256 + tid;
        int r = id >> 3, c = id & 7;
        uint4 kval = *(const uint4*)(kb + gb16 + r * 64 + c * 8);
        *(uint4*)(Kb + r * 64 + ((c ^ (r & 7)) * 8)) = kval;
        int d = id >> 5, c2 = id & 31;
        uint4 vval = *(const uint4*)(vt + gb16 + d * 256 + c2 * 8);
        *(uint4*)(Vt + d * 256 + ((c2 ^ (d & 7)) * 8)) = vval;
    }
    sE[tid]  = Eg[(size_t)bh * SS + tid];
    sPM[tid] = PMg[(size_t)bh * SS + tid];
    sL[tid]  = Lg[(size_t)bh * SS + tid];
    __syncthreads();

    f32x4 O[4][4] = {};
    float csum[4][4] = {};
    const int pmap[4] = {wv, 7 - wv, 8 + wv, 15 - wv};
    ushort* Pw = Pl + wv * 640;
    size_t obase = (size_t)b * SS * 512 + h * 64;

    #pragma unroll
    for (int rf = 0; rf < 4; ++rf) {
        int p = pmap[rf];
        int r0 = p * 16;
        short8 qf0 = *(const short8*)(qb + gb16 + (r0 + lr) * 64 + lg * 8);
        short8 qf1 = *(const short8*)(qb + gb16 + (r0 + lr) * 64 + 32 + lg * 8);
        float pmv[4], lv[4];
        #pragma unroll
        for (int r = 0; r < 4; ++r) { pmv[r] = sPM[r0 + g4 + r]; lv[r] = sL[r0 + g4 + r]; }
        int jtmax = r0 >> 5;
        #pragma unroll 1
        for (int jt = 0; jt <= jtmax; ++jt) {
            int jb = jt * 32;
            f32x4 s0 = {0.f, 0.f, 0.f, 0.f}, s1 = {0.f, 0.f, 0.f, 0.f};
            {
                int j = jb + lr;
                int sw = j & 7;
                short8 k00 = *(const short8*)(Kb + j * 64 + ((lg)     ^ sw) * 8);
                short8 k01 = *(const short8*)(Kb + j * 64 + ((4 + lg) ^ sw) * 8);
                int j2 = jb + 16 + lr;
                int sw2 = j2 & 7;
                short8 k10 = *(const short8*)(Kb + j2 * 64 + ((lg)     ^ sw2) * 8);
                short8 k11 = *(const short8*)(Kb + j2 * 64 + ((4 + lg) ^ sw2) * 8);
                s0 = __builtin_amdgcn_mfma_f32_16x16x32_bf16(qf0, k00, s0, 0, 0, 0);
                s0 = __builtin_amdgcn_mfma_f32_16x16x32_bf16(qf1, k01, s0, 0, 0, 0);
                s1 = __builtin_amdgcn_mfma_f32_16x16x32_bf16(qf0, k10, s1, 0, 0, 0);
                s1 = __builtin_amdgcn_mfma_f32_16x16x32_bf16(qf1, k11, s1, 0, 0, 0);
            }
            float e0 = sE[jb + lr], e1 = sE[jb + 16 + lr];
            int j0 = jb + lr, j1 = jb + 16 + lr;
            #pragma unroll
            for (int r = 0; r < 4; ++r) {
                int i = r0 + g4 + r;
                float sc0 = (j0 <= i) ? s0[r] * 0.125f * __expf(e0 - pmv[r]) : 0.f;
                float sc1 = (j1 <= i) ? s1[r] * 0.125f * __expf(e1 - pmv[r]) : 0.f;
                csum[rf][r] += sc0 + sc1;
                Pw[(g4 + r) * 40 + lr] = bf16u(sc0);
                Pw[(g4 + r) * 40 + 16 + lr] = bf16u(sc1);
            }
            WAVE_SYNC();
            short8 pf = *(const short8*)(Pw + lr * 40 + lg * 8);
            #pragma unroll
            for (int dc = 0; dc < 4; ++dc) {
                int d = dc * 16 + lr;
                int chunk = (jt * 4 + lg) ^ (d & 7);
                short8 vf = *(const short8*)(Vt + d * 256 + chunk * 8);
                O[rf][dc] = __builtin_amdgcn_mfma_f32_16x16x32_bf16(pf, vf, O[rf][dc], 0, 0, 0);
            }
        }
        float rinv[4];
        #pragma unroll
        for (int r = 0; r < 4; ++r) {
            float cs = csum[rf][r];
            cs += __shfl_xor(cs, 1); cs += __shfl_xor(cs, 2);
            cs += __shfl_xor(cs, 4); cs += __shfl_xor(cs, 8);
            float nrm = fmaxf(fabsf(cs), __expf(-(lv[r] + pmv[r]))) + 1e-6f;
            rinv[r] = 1.f / nrm;
        }
        #pragma unroll
        for (int dc = 0; dc < 4; ++dc)
            #pragma unroll
            for (int r = 0; r < 4; ++r)
                hmout[obase + (size_t)(r0 + g4 + r) * 512 + dc * 16 + lr] = O[rf][dc][r] * rinv[r];
    }
}

// ---------------- mLSTM post: group-LN(64) + skip + silu(z) -> bf16 [NR][256] ----------------
__global__ __launch_bounds__(256) void mpost_kernel(const float* __restrict__ xzbuf,
        const float* __restrict__ xca, const float* __restrict__ onw,
        const float* __restrict__ skip, ushort* __restrict__ outb) {
    int row = blockIdx.x;
    int t = threadIdx.x;
    size_t base = (size_t)row * 512;
    float hm = xzbuf[base + t];
    float s1 = hm, s2 = hm * hm;
    #pragma unroll
    for (int o = 32; o; o >>= 1) { s1 += __shfl_xor(s1, o); s2 += __shfl_xor(s2, o); }
    float mu = s1 * (1.f / 64.f);
    float var = s2 * (1.f / 64.f) - mu * mu;
    float xnv = (hm - mu) * rsqrtf(var + 1e-5f) * onw[t];
    float z = xzbuf[base + 256 + t];
    float val = (xnv + skip[t] * xca[(size_t)row * 256 + t]) * siluf_(z);
    outb[(size_t)row * 256 + t] = bf16u(val);
}

// ---------------- sLSTM sequential scan: one wave per (b,h), packed-bf16 weights in registers ----------------
// gif[row][256]: col h*64+l = x-gate (l<32: i ch l, l>=32: f ch l-32); gzo likewise (z,o).
// R8 post-mortem: allocator pins this kernel at ~72 VGPRs and will NOT hold a 64-reg f32 weight
// array (launch_bounds(64,1) did not change it) -> weights were re-fetched every step (~1690 cyc).
// Fix: halve the demand. Pack (col l, col 64+l) as bf16x2 in ONE u32 -> 32 weight VGPRs.
// Unpack is 1 VALU op each (p<<16 and p&0xffff0000 are exact bf16->f32 casts). Prefetch depth 4.
// Total live ~64 regs < 72: fits the allocation the compiler already chooses.
__global__ __launch_bounds__(64, 1) void slstm_scan_kernel(const float* __restrict__ gif,
        const float* __restrict__ gzo, const float* __restrict__ rec_w,
        const float* __restrict__ bias, const float* __restrict__ gnw,
        float* __restrict__ hbuf) {
    int bh = blockIdx.x;
    int b = bh >> 2, h = bh & 3;
    int l = threadIdx.x;
    int c = l & 31;
    bool lo = (l < 32);
    unsigned wpk[32];   // bf16(col 64+l) << 16 | bf16(col l)
    const float* wp = rec_w + (size_t)h * 4096 + l;
    #pragma unroll
    for (int d = 0; d < 32; ++d) {
        float w0v = wp[d * 128];
        float w1v = wp[d * 128 + 64];
        wpk[d] = ((unsigned)bf16u(w1v) << 16) | (unsigned)bf16u(w0v);
    }
    float b0 = bias[h * 128 + l];
    float b1 = bias[h * 128 + 64 + l];
    float gw = gnw[h * 32 + c];
    float cst = 0.f, nst = 0.f, mst = 0.f, hreg = 0.f;
    size_t gb = (size_t)b * SS * 256 + h * 64 + l;
    size_t hb = (size_t)b * SS * 128 + h * 32 + c;
    float pg0[4], pg1[4], ph[4];
    #pragma unroll
    for (int u = 0; u < 4; ++u) {
        pg0[u] = gif[gb + (size_t)u * 256];
        pg1[u] = gzo[gb + (size_t)u * 256];
        ph[u]  = hbuf[hb + (size_t)u * 128];
    }
    for (int s = 0; s < SS; s += 4) {
        #pragma unroll
        for (int u = 0; u < 4; ++u) {
            // recurrent matvec: readlane broadcast + bf16-unpack weights, ILP-4 partials
            float a00 = 0.f, a01 = 0.f, a02 = 0.f, a03 = 0.f;
            float a10 = 0.f, a11 = 0.f, a12 = 0.f, a13 = 0.f;
            #pragma unroll
            for (int d = 0; d < 32; d += 4) {
                float h0 = rdlane(hreg, d);
                float h1 = rdlane(hreg, d + 1);
                float h2 = rdlane(hreg, d + 2);
                float h3 = rdlane(hreg, d + 3);
                unsigned p0 = wpk[d], p1 = wpk[d + 1], p2 = wpk[d + 2], p3 = wpk[d + 3];
                a00 += __uint_as_float(p0 << 16) * h0;
                a10 += __uint_as_float(p0 & 0xffff0000u) * h0;
                a01 += __uint_as_float(p1 << 16) * h1;
                a11 += __uint_as_float(p1 & 0xffff0000u) * h1;
                a02 += __uint_as_float(p2 << 16) * h2;
                a12 += __uint_as_float(p2 & 0xffff0000u) * h2;
                a03 += __uint_as_float(p3 << 16) * h3;
                a13 += __uint_as_float(p3 & 0xffff0000u) * h3;
            }
            float raw0 = pg0[u] + ((a00 + a01) + (a02 + a03)) + b0;
            float raw1 = pg1[u] + ((a10 + a11) + (a12 + a13)) + b1;
            float hcur = ph[u];
            int s4 = s + 4 + u;
            if (s4 < SS) {
                pg0[u] = gif[gb + (size_t)s4 * 256];
                pg1[u] = gzo[gb + (size_t)s4 * 256];
                ph[u]  = hbuf[hb + (size_t)s4 * 128];
            }
            // half-swap via permlane32_swap (VALU)
            i32x2 r0p = __builtin_amdgcn_permlane32_swap(__float_as_int(raw0), __float_as_int(raw0), false, false);
            i32x2 r1p = __builtin_amdgcn_permlane32_swap(__float_as_int(raw1), __float_as_int(raw1), false, false);
            float q0 = __int_as_float(lo ? r0p.y : r0p.x);
            float q1 = __int_as_float(lo ? r1p.y : r1p.x);
            float iraw = lo ? raw0 : q0;
            float zraw = lo ? raw1 : q1;
            float fraw = lo ? q0 : raw0;
            float oraw = lo ? q1 : raw1;
            float lfm = mst + fminf(fraw, 0.f) - __logf(1.f + __expf(-fabsf(fraw)));
            float mnew = fmaxf(iraw, lfm);
            float ig = __expf(iraw - mnew);
            float fg = __expf(lfm - mnew);
            float e2z = __expf(2.f * zraw);
            float tz = 1.f - 2.f * __builtin_amdgcn_rcpf(e2z + 1.f);
            cst = fg * cst + ig * tz;
            nst = fg * nst + ig;
            mst = mnew;
            float sg = __builtin_amdgcn_rcpf(1.f + __expf(-oraw));
            float hv = sg * cst * __builtin_amdgcn_rcpf(nst);
            hreg = hv;
            // fused group-LN(32) + residual; DPP tree sum over all 64 lanes (= 2x 32-sum)
            float s1 = hv, s2 = hv * hv;
            s1 = DPPADD(s1, 0x111); s2 = DPPADD(s2, 0x111);   // row_shr:1
            s1 = DPPADD(s1, 0x112); s2 = DPPADD(s2, 0x112);   // row_shr:2
            s1 = DPPADD(s1, 0x114); s2 = DPPADD(s2, 0x114);   // row_shr:4
            s1 = DPPADD(s1, 0x118); s2 = DPPADD(s2, 0x118);   // row_shr:8
            s1 = DPPADD(s1, 0x142); s2 = DPPADD(s2, 0x142);   // row_bcast:15
            s1 = DPPADD(s1, 0x143); s2 = DPPADD(s2, 0x143);   // row_bcast:31
            float mu = rdlane(s1, 63) * (1.f / 64.f);
            float var = rdlane(s2, 63) * (1.f / 64.f) - mu * mu;
            float outv = (hv - mu) * rsqrtf(var + 1e-5f) * gw;
            if (lo) hbuf[hb + (size_t)(s + u) * 128] = hcur + outv;
        }
    }
}

// ---------------- gated-GELU (exact erf) -> bf16 ----------------
__global__ __launch_bounds__(256) void geluglu_kernel(const float* __restrict__ xzbuf,
        ushort* __restrict__ gg, int total) {
    int i = blockIdx.x * 256 + threadIdx.x;
    if (i >= total) return;
    int c = i & 255;
    size_t row = (size_t)(i >> 8);
    float g = xzbuf[row * 512 + c];
    float u = xzbuf[row * 512 + 256 + c];
    float ge = 0.5f * g * (1.f + erff(g * 0.70710678118654752f));
    gg[i] = bf16u(ge * u);
}

extern "C" void kernel_launch(void* const* d_in, const int* in_sizes, int n_in,
                              void* d_out, int out_size, void* d_ws, size_t ws_size,
                              hipStream_t stream) {
    const int*   x        = (const int*)d_in[0];
    const float* emb      = (const float*)d_in[1];
    const float* m_ln_w   = (const float*)d_in[2];
    const float* m_up_w   = (const float*)d_in[3];
    const float* m_conv_w = (const float*)d_in[4];
    const float* m_conv_b = (const float*)d_in[5];
    const float* m_q_w    = (const float*)d_in[6];
    const float* m_k_w    = (const float*)d_in[7];
    const float* m_v_w    = (const float*)d_in[8];
    const float* m_ig_w   = (const float*)d_in[9];
    const float* m_ig_b   = (const float*)d_in[10];
    const float* m_fg_w   = (const float*)d_in[11];
    const float* m_fg_b   = (const float*)d_in[12];
    const float* m_on_w   = (const float*)d_in[13];
    const float* m_skip   = (const float*)d_in[14];
    const float* m_down_w = (const float*)d_in[15];
    const float* s_ln1_w  = (const float*)d_in[16];
    const float* s_conv_w = (const float*)d_in[17];
    const float* s_conv_b = (const float*)d_in[18];
    const float* s_ig_w   = (const float*)d_in[19];
    const float* s_fg_w   = (const float*)d_in[20];
    const float* s_zg_w   = (const float*)d_in[21];
    const float* s_og_w   = (const float*)d_in[22];
    const float* s_rec_w  = (const float*)d_in[23];
    const float* s_bias   = (const float*)d_in[24];
    const float* s_gn_w   = (const float*)d_in[25];
    const float* s_ln2_w  = (const float*)d_in[26];
    const float* s_ff_up_w   = (const float*)d_in[27];
    const float* s_ff_down_w = (const float*)d_in[28];
    const float* post_norm_w = (const float*)d_in[29];
    float* out = (float*)d_out;

    float* ws = (float*)d_ws;
    const size_t NR = NROWS;
    float* h   = ws;                   // NR*128
    float* xn  = h   + NR * 128;       // NR*128 fp32 (later qb16 alias)
    float* xz  = xn  + NR * 128;       // NR*512
    float* xca = xz  + NR * 512;       // NR*256
    float* q   = xca + NR * 256;       // NR*256 (q fp32; later mpostb bf16; later gif fp32)
    float* k   = q   + NR * 256;       // NR*256 (k fp32; later vtb bf16; later gzo fp32)
    float* v   = k   + NR * 256;       // NR*256 (v fp32)
    float* gip = v   + NR * 256;       // 512*256
    float* gfp = gip + 512 * 256;
    float* gL  = gfp + 512 * 256;
    float* gE  = gL  + 512 * 256;
    float* gPM = gE  + 512 * 256;
    float* extra = gPM + 512 * 256;
    // bf16 regions
    ushort* xnb   = (ushort*)extra;                    // NR*128 bf16
    ushort* upb   = (ushort*)(extra + NR * 64);        // 512*128
    ushort* downb = upb + 512 * 128;                   // 128*256
    ushort* ffupb = downb + 128 * 256;                 // 2*512*128
    ushort* ffdownb = ffupb + 2 * 512 * 128;           // 2*128*256
    ushort* sgwb  = ffdownb + 2 * 128 * 256;           // 2*2*256*128
    // aliases (regions dead at time of use)
    ushort* qb16   = (ushort*)xn;     // NR*256 bf16
    ushort* kb16   = (ushort*)out;    // NR*256 bf16
    ushort* vtb    = (ushort*)k;      // NR*256 bf16
    ushort* mpostb = (ushort*)q;      // NR*256 bf16
    ushort* xcb    = (ushort*)(xca + NR * 128);   // NR*128 bf16
    ushort* ggb    = (ushort*)xca;    // NR*256 bf16
    float* gif = q;                   // NR*256 fp32
    float* gzo = k;                   // NR*256 fp32

    // ---- weight conversions ----
    tobf16_kernel<<<(512 * 128 + 255) / 256, 256, 0, stream>>>(m_up_w, upb, 512 * 128);
    tobf16_kernel<<<(128 * 256 + 255) / 256, 256, 0, stream>>>(m_down_w, downb, 128 * 256);
    tobf16_kernel<<<(2 * 512 * 128 + 255) / 256, 256, 0, stream>>>(s_ff_up_w, ffupb, 2 * 512 * 128);
    tobf16_kernel<<<(2 * 128 * 256 + 255) / 256, 256, 0, stream>>>(s_ff_down_w, ffdownb, 2 * 128 * 256);
    densify_kernel<<<(2 * 2 * 256 * 128) / 256, 256, 0, stream>>>(s_ig_w, s_fg_w, s_zg_w, s_og_w, sgwb);

    // ---- embedding + pre-LN ----
    embed_kernel<<<(NR * 128) / 256, 256, 0, stream>>>(x, emb, h, NR * 128);
    ln128_kernel<<<NR, 64, 0, stream>>>(h, m_ln_w, xn, xnb);
    // ---- mLSTM up-projection (bf16 MFMA) ----
    gemm_bf16_kernel<<<dim3(NR / 128, 4), 256, 0, stream>>>(xnb, 128, upb, xz, 512, 128, 0);
    // ---- causal conv + silu ----
    conv_silu_kernel<<<(NR * 256) / 256, 256, 0, stream>>>(xz, 512, 256, m_conv_w, m_conv_b, xca, 256, nullptr, NR * 256);
    // ---- block-diag q,k,v (+ bf16 copies) ----
    mqkv_kernel<<<(NR * 256) / 256, 256, 0, stream>>>(xca, xz, m_q_w, m_k_w, m_v_w, q, k, v, qb16, kb16, NR * 256);
    // ---- i/f gate projections ----
    mgate_kernel<<<NR, 256, 0, stream>>>(q, k, v, m_ig_w, m_ig_b, m_fg_w, m_fg_b, gip, gfp);
    // ---- decay prefix scan ----
    mprep_kernel<<<BB * NH, 64, 0, stream>>>(gip, gfp, gL, gE, gPM);
    // ---- V transpose to bf16 (into dead k fp32 space) ----
    vtrans_kernel<<<BB * NH * 4, 256, 0, stream>>>(v, vtb);
    // ---- mLSTM parallel core via MFMA (hm -> x_in half of xz) ----
    mlstm_mfma_kernel<<<BB * NH, 256, 0, stream>>>(qb16, kb16, vtb, gL, gE, gPM, xz);
    // ---- post: group-LN + skip + silu(z) -> bf16 (q region now dead) ----
    mpost_kernel<<<NR, 256, 0, stream>>>(xz, xca, m_on_w, m_skip, mpostb);
    // ---- down-projection + residual (bf16 MFMA, accumulate) ----
    gemm_bf16_kernel<<<dim3(NR / 128, 1), 256, 0, stream>>>(mpostb, 256, downb, h, 128, 256, 1);

    // ---- two sLSTM blocks ----
    for (int i2 = 0; i2 < 2; ++i2) {
        ln128_kernel<<<NR, 64, 0, stream>>>(h, s_ln1_w + i2 * 128, xn, xnb);
        conv_silu_kernel<<<(NR * 128) / 256, 256, 0, stream>>>(xn, 128, 128, s_conv_w + i2 * 128 * 4, s_conv_b + i2 * 128, xca, 128, xcb, NR * 128);
        // gates via dense bf16 GEMMs: [i|f]-perm = xc @ Wif'^T, [z|o]-perm = xn @ Wzo'^T
        gemm_bf16_kernel<<<dim3(NR / 128, 2), 256, 0, stream>>>(xcb, 128, sgwb + (size_t)(i2 * 2 + 0) * 256 * 128, gif, 256, 128, 0);
        gemm_bf16_kernel<<<dim3(NR / 128, 2), 256, 0, stream>>>(xnb, 128, sgwb + (size_t)(i2 * 2 + 1) * 256 * 128, gzo, 256, 128, 0);
        // scan with fused group-LN + residual into h
        slstm_scan_kernel<<<BB * NH, 64, 0, stream>>>(gif, gzo,
                s_rec_w + i2 * 4 * 32 * 128, s_bias + i2 * 4 * 128, s_gn_w + i2 * 128, h);
        ln128_kernel<<<NR, 64, 0, stream>>>(h, s_ln2_w + i2 * 128, xn, xnb);
        gemm_bf16_kernel<<<dim3(NR / 128, 4), 256, 0, stream>>>(xnb, 128, ffupb + (size_t)i2 * 512 * 128, xz, 512, 128, 0);
        geluglu_kernel<<<(NR * 256) / 256, 256, 0, stream>>>(xz, ggb, NR * 256);
        gemm_bf16_kernel<<<dim3(NR / 128, 1), 256, 0, stream>>>(ggb, 256, ffdownb + (size_t)i2 * 128 * 256, h, 128, 256, 1);
    }
    // ---- final LN -> out ----
    ln128_kernel<<<NR, 64, 0, stream>>>(h, post_norm_w, out, xnb);
}

// Round 10
// 1006.882 us; speedup vs baseline: 1.0571x; 1.0571x over previous
//
#include <hip/hip_runtime.h>
#include <hip/hip_bf16.h>

// Model dims (compile-time)
#define BB 128
#define SS 256
#define DD 128
#define DI 256      // 2*D
#define NH 4
#define DHM 64      // DI/NH
#define DHS 32      // D/NH
#define NROWS (BB*SS)   // 32768

#define WAVE_SYNC() do { asm volatile("s_waitcnt lgkmcnt(0)" ::: "memory"); __builtin_amdgcn_wave_barrier(); } while (0)

typedef __attribute__((ext_vector_type(8))) short short8;
typedef __attribute__((ext_vector_type(4))) float f32x4;
typedef __attribute__((ext_vector_type(2))) float f32x2;
typedef __attribute__((ext_vector_type(2))) int i32x2;

__device__ __forceinline__ float sigmoidf_(float x) { return 1.f / (1.f + __expf(-x)); }
__device__ __forceinline__ float siluf_(float x) { return x / (1.f + __expf(-x)); }
// stable log_sigmoid
__device__ __forceinline__ float logsigf_(float x) {
    return (x >= 0.f) ? -log1pf(__expf(-x)) : x - log1pf(__expf(x));
}
__device__ __forceinline__ float tanhf_(float x) {
    float e = __expf(2.f * x);
    return 1.f - 2.f / (e + 1.f);
}
// fp32 -> bf16 bits, round-to-nearest-even (inputs are finite)
__device__ __forceinline__ ushort bf16u(float x) {
    unsigned u = __float_as_uint(x);
    u += 0x7fffu + ((u >> 16) & 1u);
    return (ushort)(u >> 16);
}
__device__ __forceinline__ float rdlane(float v, int lane) {
    return __int_as_float(__builtin_amdgcn_readlane(__float_as_int(v), lane));
}
// DPP add: x + dpp(x) with given ctrl (VALU-speed cross-lane; bound_ctrl=1 -> 0 fill)
#define DPPADD(x, ctrl) ((x) + __int_as_float(__builtin_amdgcn_update_dpp(0, __float_as_int(x), (ctrl), 0xf, 0xf, true)))

// ---------------- fp32 -> bf16 copy ----------------
__global__ __launch_bounds__(256) void tobf16_kernel(const float* __restrict__ src,
        ushort* __restrict__ dst, int n) {
    int i = blockIdx.x * 256 + threadIdx.x;
    if (i < n) dst[i] = bf16u(src[i]);
}

// ---------------- densify sLSTM block-diag gate weights -> bf16 [i2][pair][256][128] ----------------
__global__ __launch_bounds__(256) void densify_kernel(const float* __restrict__ wi,
        const float* __restrict__ wf, const float* __restrict__ wz,
        const float* __restrict__ wo, ushort* __restrict__ dst) {
    int idx = blockIdx.x * 256 + threadIdx.x;   // 2*2*256*128 = 262144
    int t = idx & 127;
    int oc = (idx >> 7) & 255;
    int pair = (idx >> 15) & 1;
    int i2 = idx >> 16;
    int h = oc >> 6, l = oc & 63, gate = (l >> 5) & 1, e = l & 31;
    const float* w = pair == 0 ? (gate == 0 ? wi : wf) : (gate == 0 ? wz : wo);
    float val = ((t >> 5) == h) ? w[i2 * 4096 + h * 1024 + e * 32 + (t & 31)] : 0.f;
    dst[idx] = bf16u(val);
}

// ---------------- densify mLSTM gate weights -> bf16 [16][768] (rows 0-3 ig, 4-7 fg, 8-15 zero) ----------------
__global__ __launch_bounds__(256) void densify_mgate_kernel(const float* __restrict__ igw,
        const float* __restrict__ fgw, ushort* __restrict__ dst) {
    int idx = blockIdx.x * 256 + threadIdx.x;   // 16*768 = 12288
    if (idx >= 16 * 768) return;
    int t = idx % 768, j = idx / 768;
    float v = 0.f;
    if (j < 4) v = igw[j * 768 + t];
    else if (j < 8) v = fgw[(j - 4) * 768 + t];
    dst[idx] = bf16u(v);
}

// ---------------- embedding ----------------
__global__ __launch_bounds__(256) void embed_kernel(const int* __restrict__ x,
        const float* __restrict__ emb, float* __restrict__ h, int total) {
    int i = blockIdx.x * 256 + threadIdx.x;
    if (i >= total) return;
    int row = i >> 7;          // D=128
    int c = i & 127;
    h[i] = emb[x[row] * DD + c];
}

// ---------------- LayerNorm over D=128 (block=64 threads, 1 row); fp32 + bf16 out ----------------
__global__ __launch_bounds__(64) void ln128_kernel(const float* __restrict__ x,
        const float* __restrict__ w, float* __restrict__ out, ushort* __restrict__ outb) {
    int row = blockIdx.x;
    int lane = threadIdx.x;
    const float* xr = x + (size_t)row * DD;
    float a = xr[lane], b = xr[lane + 64];
    float s1 = a + b, s2 = a * a + b * b;
    #pragma unroll
    for (int o = 32; o; o >>= 1) { s1 += __shfl_xor(s1, o); s2 += __shfl_xor(s2, o); }
    float mu = s1 * (1.f / 128.f);
    float var = s2 * (1.f / 128.f) - mu * mu;
    float inv = rsqrtf(var + 1e-5f);
    float va = (a - mu) * inv * w[lane];
    float vb = (b - mu) * inv * w[lane + 64];
    float* orow = out + (size_t)row * DD;
    orow[lane] = va; orow[lane + 64] = vb;
    ushort* brow = outb + (size_t)row * DD;
    brow[lane] = bf16u(va); brow[lane + 64] = bf16u(vb);
}

// ---------------- bf16 MFMA GEMM: C[M,N] (+)= A[M,K](lda) @ W[N,K]^T ----------------
// 128x128 tile, BK=32, 4 waves (2x2 of 64x64), XOR-swizzled 16B chunks in LDS.
__global__ __launch_bounds__(256, 2) void gemm_bf16_kernel(const ushort* __restrict__ A, int lda,
        const ushort* __restrict__ W, float* __restrict__ C, int ldc, int K, int addC) {
    __shared__ ushort As[128 * 32];
    __shared__ ushort Bs[128 * 32];
    int m0 = blockIdx.x * 128;
    int n0 = blockIdx.y * 128;
    int tid = threadIdx.x;
    int wv = tid >> 6, l = tid & 63;
    int lr = l & 15, lg = l >> 4, g4 = lg * 4;
    int wr = wv >> 1, wc = wv & 1;
    int sr = tid >> 1;                  // staging row 0..127
    int sc = (tid & 1) * 2;             // staging chunk base {0,2}

    f32x4 acc[4][4] = {};
    for (int k0 = 0; k0 < K; k0 += 32) {
        __syncthreads();
        #pragma unroll
        for (int u = 0; u < 2; ++u) {
            int c = sc + u;
            uint4 av = *(const uint4*)(A + (size_t)(m0 + sr) * lda + k0 + c * 8);
            *(uint4*)(As + sr * 32 + ((c ^ (sr & 3)) * 8)) = av;
            uint4 wv4 = *(const uint4*)(W + (size_t)(n0 + sr) * K + k0 + c * 8);
            *(uint4*)(Bs + sr * 32 + ((c ^ (sr & 3)) * 8)) = wv4;
        }
        __syncthreads();
        short8 af[4], bf[4];
        #pragma unroll
        for (int fm = 0; fm < 4; ++fm) {
            int row = wr * 64 + fm * 16 + lr;
            af[fm] = *(const short8*)(As + row * 32 + ((lg ^ (row & 3)) * 8));
        }
        #pragma unroll
        for (int fn = 0; fn < 4; ++fn) {
            int row = wc * 64 + fn * 16 + lr;
            bf[fn] = *(const short8*)(Bs + row * 32 + ((lg ^ (row & 3)) * 8));
        }
        #pragma unroll
        for (int fm = 0; fm < 4; ++fm)
            #pragma unroll
            for (int fn = 0; fn < 4; ++fn)
                acc[fm][fn] = __builtin_amdgcn_mfma_f32_16x16x32_bf16(af[fm], bf[fn], acc[fm][fn], 0, 0, 0);
    }
    #pragma unroll
    for (int fm = 0; fm < 4; ++fm) {
        #pragma unroll
        for (int fn = 0; fn < 4; ++fn) {
            #pragma unroll
            for (int r = 0; r < 4; ++r) {
                size_t idx = (size_t)(m0 + wr * 64 + fm * 16 + g4 + r) * ldc + n0 + wc * 64 + fn * 16 + lr;
                if (addC) C[idx] += acc[fm][fn][r]; else C[idx] = acc[fm][fn][r];
            }
        }
    }
}

// ---------------- skinny gate GEMM: [ip|fp] = qkvb @ W16^T + bias (M=NR, N=16(8 valid), K=768) ----------------
// No LDS, no barriers: A-frags straight from global (coalesced 16B), B cached in L2 (24 KB shared).
// Writes transposed layout ip/fp[(b*4+h)*256 + s]. Replaces mgate's 48-shfl-per-thread reduction.
__global__ __launch_bounds__(256) void gategemm_kernel(const ushort* __restrict__ A,
        const ushort* __restrict__ W16, const float* __restrict__ igb,
        const float* __restrict__ fgb, float* __restrict__ ip, float* __restrict__ fp) {
    int tid = threadIdx.x;
    int wv = tid >> 6, l = tid & 63;
    int lr = l & 15, lg = l >> 4, g4 = lg * 4;
    int row0 = blockIdx.x * 128 + wv * 32;
    f32x4 acc[2] = {};
    for (int k0 = 0; k0 < 768; k0 += 32) {
        short8 bfr = *(const short8*)(W16 + lr * 768 + k0 + lg * 8);
        #pragma unroll
        for (int mi = 0; mi < 2; ++mi) {
            short8 afr = *(const short8*)(A + (size_t)(row0 + mi * 16 + lr) * 768 + k0 + lg * 8);
            acc[mi] = __builtin_amdgcn_mfma_f32_16x16x32_bf16(afr, bfr, acc[mi], 0, 0, 0);
        }
    }
    if (lr < 8) {
        float bias = (lr < 4) ? igb[lr] : fgb[lr - 4];
        float* dst = (lr < 4) ? ip : fp;
        int hh = lr & 3;
        #pragma unroll
        for (int mi = 0; mi < 2; ++mi) {
            #pragma unroll
            for (int r = 0; r < 4; ++r) {
                int row = row0 + mi * 16 + g4 + r;
                int b = row >> 8, s = row & 255;
                dst[(size_t)(b * 4 + hh) * 256 + s] = acc[mi][r] + bias;
            }
        }
    }
}

// ---------------- depthwise causal conv (K=4) + silu (fp32 out + optional bf16 out) ----------------
__global__ __launch_bounds__(256) void conv_silu_kernel(const float* __restrict__ x, int ldx, int C,
        const float* __restrict__ w, const float* __restrict__ bias,
        float* __restrict__ out, int ldo, ushort* __restrict__ outb, int total) {
    int i = blockIdx.x * 256 + threadIdx.x;
    if (i >= total) return;
    int c = i % C;
    size_t row = (size_t)(i / C);
    int s = (int)(row & (SS - 1));
    float acc = bias[c];
    #pragma unroll
    for (int j = 0; j < 4; ++j) {
        int ss = s - 3 + j;
        if (ss >= 0) acc += x[(row + (size_t)(ss - s)) * ldx + c] * w[c * 4 + j];
    }
    float val = siluf_(acc);
    out[row * ldo + c] = val;
    if (outb) outb[row * ldo + c] = bf16u(val);
}

// ---------------- mLSTM block-diagonal q,k,v (8x8 blocks) + bf16 outputs ----------------
// qkvb: packed bf16 [row][768] = q|k|v (feeds gategemm); v fp32 (feeds vtrans); qb16/kb16 per-head.
__global__ __launch_bounds__(256) void mqkv_kernel(const float* __restrict__ xca,
        const float* __restrict__ xz, const float* __restrict__ qw,
        const float* __restrict__ kw, const float* __restrict__ vw,
        ushort* __restrict__ qkvb, float* __restrict__ v,
        ushort* __restrict__ qb16, ushort* __restrict__ kb16, int total) {
    int i = blockIdx.x * 256 + threadIdx.x;
    if (i >= total) return;
    int c = i & 255;
    size_t row = (size_t)(i >> 8);
    int nb = c >> 3, e = c & 7;
    const float* xc8 = xca + row * 256 + nb * 8;
    const float* xi8 = xz + row * 512 + nb * 8;
    const float* qw8 = qw + (size_t)(nb * 8 + e) * 8;
    const float* kw8 = kw + (size_t)(nb * 8 + e) * 8;
    const float* vw8 = vw + (size_t)(nb * 8 + e) * 8;
    float aq = 0.f, ak = 0.f, av = 0.f;
    #pragma unroll
    for (int t = 0; t < 8; ++t) {
        float xcv = xc8[t], xiv = xi8[t];
        aq += xcv * qw8[t];
        ak += xcv * kw8[t];
        av += xiv * vw8[t];
    }
    ushort qb = bf16u(aq), kb = bf16u(ak);
    qkvb[row * 768 + c] = qb;
    qkvb[row * 768 + 256 + c] = kb;
    qkvb[row * 768 + 512 + c] = bf16u(av);
    v[i] = av;
    // bf16 per-head layout [bh][s][64] for the MFMA core
    int h2 = c >> 6, dd = c & 63;
    size_t be = ((((row >> 8) << 2) + h2) * 256 + (row & 255)) * 64 + dd;
    qb16[be] = qb;
    kb16[be] = kb;
}

// ---------------- mLSTM decay prefix scan: L (cum log-sigmoid), E = ip - L, PM = prefix-max(E) ----------------
__global__ __launch_bounds__(64) void mprep_kernel(const float* __restrict__ ip,
        const float* __restrict__ fp, float* __restrict__ L,
        float* __restrict__ E, float* __restrict__ PM) {
    int bh = blockIdx.x;
    int lane = threadIdx.x;
    __shared__ float sfp[SS], sip[SS], sL[SS], sE[SS], sPM[SS];
    for (int u = lane; u < SS; u += 64) {
        sfp[u] = fp[(size_t)bh * SS + u];
        sip[u] = ip[(size_t)bh * SS + u];
    }
    __syncthreads();
    if (lane == 0) {
        float run = 0.f, pm = -INFINITY;
        for (int j = 0; j < SS; ++j) {
            run += logsigf_(sfp[j]);
            float e = sip[j] - run;
            pm = fmaxf(pm, e);
            sL[j] = run; sE[j] = e; sPM[j] = pm;
        }
    }
    __syncthreads();
    for (int u = lane; u < SS; u += 64) {
        L[(size_t)bh * SS + u] = sL[u];
        E[(size_t)bh * SS + u] = sE[u];
        PM[(size_t)bh * SS + u] = sPM[u];
    }
}

// ---------------- V transpose to [bh][64][256] bf16 ----------------
__global__ __launch_bounds__(256) void vtrans_kernel(const float* __restrict__ v,
        ushort* __restrict__ vt) {
    int blk = blockIdx.x;
    int st = blk & 3, bh = blk >> 2;
    int b = bh >> 2, h = bh & 3;
    int tid = threadIdx.x;
    __shared__ float tile[64][65];
    int s0 = st * 64;
    #pragma unroll
    for (int u = 0; u < 16; ++u) {
        int idx = u * 256 + tid;
        int sl = idx >> 6, dl = idx & 63;
        tile[sl][dl] = v[((size_t)(b * 256 + s0 + sl)) * 256 + h * 64 + dl];
    }
    __syncthreads();
    #pragma unroll
    for (int u = 0; u < 16; ++u) {
        int idx = u * 256 + tid;
        int dl = idx >> 6, sl = idx & 63;
        vt[((size_t)bh * 64 + dl) * 256 + s0 + sl] = bf16u(tile[sl][dl]);
    }
}

// ---------------- mLSTM parallel core via MFMA ----------------
__global__ __launch_bounds__(256, 2) void mlstm_mfma_kernel(
        const ushort* __restrict__ qb, const ushort* __restrict__ kb,
        const ushort* __restrict__ vt, const float* __restrict__ Lg,
        const float* __restrict__ Eg, const float* __restrict__ PMg,
        float* __restrict__ hmout) {
    int bh = blockIdx.x;
    int b = bh >> 2, h = bh & 3;
    int tid = threadIdx.x;
    int wv = tid >> 6, l = tid & 63;
    int lr = l & 15, lg = l >> 4, g4 = lg * 4;

    __shared__ ushort Kb[16384];     // 32 KB
    __shared__ ushort Vt[16384];     // 32 KB
    __shared__ ushort Pl[4 * 640];   // per-wave 16x40 bf16
    __shared__ float sE[SS], sPM[SS], sL[SS];

    const size_t gb16 = (size_t)bh * 16384;
    #pragma unroll
    for (int p2 = 0; p2 < 8; ++p2) {
        int id = p2 * 256 + tid;
        int r = id >> 3, c = id & 7;
        uint4 kval = *(const uint4*)(kb + gb16 + r * 64 + c * 8);
        *(uint4*)(Kb + r * 64 + ((c ^ (r & 7)) * 8)) = kval;
        int d = id >> 5, c2 = id & 31;
        uint4 vval = *(const uint4*)(vt + gb16 + d * 256 + c2 * 8);
        *(uint4*)(Vt + d * 256 + ((c2 ^ (d & 7)) * 8)) = vval;
    }
    sE[tid]  = Eg[(size_t)bh * SS + tid];
    sPM[tid] = PMg[(size_t)bh * SS + tid];
    sL[tid]  = Lg[(size_t)bh * SS + tid];
    __syncthreads();

    f32x4 O[4][4] = {};
    float csum[4][4] = {};
    const int pmap[4] = {wv, 7 - wv, 8 + wv, 15 - wv};
    ushort* Pw = Pl + wv * 640;
    size_t obase = (size_t)b * SS * 512 + h * 64;

    #pragma unroll
    for (int rf = 0; rf < 4; ++rf) {
        int p = pmap[rf];
        int r0 = p * 16;
        short8 qf0 = *(const short8*)(qb + gb16 + (r0 + lr) * 64 + lg * 8);
        short8 qf1 = *(const short8*)(qb + gb16 + (r0 + lr) * 64 + 32 + lg * 8);
        float pmv[4], lv[4];
        #pragma unroll
        for (int r = 0; r < 4; ++r) { pmv[r] = sPM[r0 + g4 + r]; lv[r] = sL[r0 + g4 + r]; }
        int jtmax = r0 >> 5;
        #pragma unroll 1
        for (int jt = 0; jt <= jtmax; ++jt) {
            int jb = jt * 32;
            f32x4 s0 = {0.f, 0.f, 0.f, 0.f}, s1 = {0.f, 0.f, 0.f, 0.f};
            {
                int j = jb + lr;
                int sw = j & 7;
                short8 k00 = *(const short8*)(Kb + j * 64 + ((lg)     ^ sw) * 8);
                short8 k01 = *(const short8*)(Kb + j * 64 + ((4 + lg) ^ sw) * 8);
                int j2 = jb + 16 + lr;
                int sw2 = j2 & 7;
                short8 k10 = *(const short8*)(Kb + j2 * 64 + ((lg)     ^ sw2) * 8);
                short8 k11 = *(const short8*)(Kb + j2 * 64 + ((4 + lg) ^ sw2) * 8);
                s0 = __builtin_amdgcn_mfma_f32_16x16x32_bf16(qf0, k00, s0, 0, 0, 0);
                s0 = __builtin_amdgcn_mfma_f32_16x16x32_bf16(qf1, k01, s0, 0, 0, 0);
                s1 = __builtin_amdgcn_mfma_f32_16x16x32_bf16(qf0, k10, s1, 0, 0, 0);
                s1 = __builtin_amdgcn_mfma_f32_16x16x32_bf16(qf1, k11, s1, 0, 0, 0);
            }
            float e0 = sE[jb + lr], e1 = sE[jb + 16 + lr];
            int j0 = jb + lr, j1 = jb + 16 + lr;
            #pragma unroll
            for (int r = 0; r < 4; ++r) {
                int i = r0 + g4 + r;
                float sc0 = (j0 <= i) ? s0[r] * 0.125f * __expf(e0 - pmv[r]) : 0.f;
                float sc1 = (j1 <= i) ? s1[r] * 0.125f * __expf(e1 - pmv[r]) : 0.f;
                csum[rf][r] += sc0 + sc1;
                Pw[(g4 + r) * 40 + lr] = bf16u(sc0);
                Pw[(g4 + r) * 40 + 16 + lr] = bf16u(sc1);
            }
            WAVE_SYNC();
            short8 pf = *(const short8*)(Pw + lr * 40 + lg * 8);
            #pragma unroll
            for (int dc = 0; dc < 4; ++dc) {
                int d = dc * 16 + lr;
                int chunk = (jt * 4 + lg) ^ (d & 7);
                short8 vf = *(const short8*)(Vt + d * 256 + chunk * 8);
                O[rf][dc] = __builtin_amdgcn_mfma_f32_16x16x32_bf16(pf, vf, O[rf][dc], 0, 0, 0);
            }
        }
        float rinv[4];
        #pragma unroll
        for (int r = 0; r < 4; ++r) {
            float cs = csum[rf][r];
            cs += __shfl_xor(cs, 1); cs += __shfl_xor(cs, 2);
            cs += __shfl_xor(cs, 4); cs += __shfl_xor(cs, 8);
            float nrm = fmaxf(fabsf(cs), __expf(-(lv[r] + pmv[r]))) + 1e-6f;
            rinv[r] = 1.f / nrm;
        }
        #pragma unroll
        for (int dc = 0; dc < 4; ++dc)
            #pragma unroll
            for (int r = 0; r < 4; ++r)
                hmout[obase + (size_t)(r0 + g4 + r) * 512 + dc * 16 + lr] = O[rf][dc][r] * rinv[r];
    }
}

// ---------------- mLSTM post: group-LN(64) + skip + silu(z) -> bf16 [NR][256] ----------------
__global__ __launch_bounds__(256) void mpost_kernel(const float* __restrict__ xzbuf,
        const float* __restrict__ xca, const float* __restrict__ onw,
        const float* __restrict__ skip, ushort* __restrict__ outb) {
    int row = blockIdx.x;
    int t = threadIdx.x;
    size_t base = (size_t)row * 512;
    float hm = xzbuf[base + t];
    float s1 = hm, s2 = hm * hm;
    #pragma unroll
    for (int o = 32; o; o >>= 1) { s1 += __shfl_xor(s1, o); s2 += __shfl_xor(s2, o); }
    float mu = s1 * (1.f / 64.f);
    float var = s2 * (1.f / 64.f) - mu * mu;
    float xnv = (hm - mu) * rsqrtf(var + 1e-5f) * onw[t];
    float z = xzbuf[base + 256 + t];
    float val = (xnv + skip[t] * xca[(size_t)row * 256 + t]) * siluf_(z);
    outb[(size_t)row * 256 + t] = bf16u(val);
}

// ---------------- sLSTM sequential scan: one wave per (b,h), packed-bf16 weights in registers ----------------
// R10: drop the 32 v_and unpacks — the packed word used directly as f32 IS the hi-half bf16
// value with <2^-8 relative mantissa noise (below the bf16 rounding already applied).
__global__ __launch_bounds__(64, 1) void slstm_scan_kernel(const float* __restrict__ gif,
        const float* __restrict__ gzo, const float* __restrict__ rec_w,
        const float* __restrict__ bias, const float* __restrict__ gnw,
        float* __restrict__ hbuf) {
    int bh = blockIdx.x;
    int b = bh >> 2, h = bh & 3;
    int l = threadIdx.x;
    int c = l & 31;
    bool lo = (l < 32);
    unsigned wpk[32];   // bf16(col 64+l) << 16 | bf16(col l)
    const float* wp = rec_w + (size_t)h * 4096 + l;
    #pragma unroll
    for (int d = 0; d < 32; ++d) {
        float w0v = wp[d * 128];
        float w1v = wp[d * 128 + 64];
        wpk[d] = ((unsigned)bf16u(w1v) << 16) | (unsigned)bf16u(w0v);
    }
    float b0 = bias[h * 128 + l];
    float b1 = bias[h * 128 + 64 + l];
    float gw = gnw[h * 32 + c];
    float cst = 0.f, nst = 0.f, mst = 0.f, hreg = 0.f;
    size_t gb = (size_t)b * SS * 256 + h * 64 + l;
    size_t hb = (size_t)b * SS * 128 + h * 32 + c;
    float pg0[4], pg1[4], ph[4];
    #pragma unroll
    for (int u = 0; u < 4; ++u) {
        pg0[u] = gif[gb + (size_t)u * 256];
        pg1[u] = gzo[gb + (size_t)u * 256];
        ph[u]  = hbuf[hb + (size_t)u * 128];
    }
    for (int s = 0; s < SS; s += 4) {
        #pragma unroll
        for (int u = 0; u < 4; ++u) {
            // recurrent matvec: readlane broadcast, bf16-packed weights, ILP-4 partials
            float a00 = 0.f, a01 = 0.f, a02 = 0.f, a03 = 0.f;
            float a10 = 0.f, a11 = 0.f, a12 = 0.f, a13 = 0.f;
            #pragma unroll
            for (int d = 0; d < 32; d += 4) {
                float h0 = rdlane(hreg, d);
                float h1 = rdlane(hreg, d + 1);
                float h2 = rdlane(hreg, d + 2);
                float h3 = rdlane(hreg, d + 3);
                unsigned p0 = wpk[d], p1 = wpk[d + 1], p2 = wpk[d + 2], p3 = wpk[d + 3];
                a00 += __uint_as_float(p0 << 16) * h0;
                a10 += __uint_as_float(p0) * h0;
                a01 += __uint_as_float(p1 << 16) * h1;
                a11 += __uint_as_float(p1) * h1;
                a02 += __uint_as_float(p2 << 16) * h2;
                a12 += __uint_as_float(p2) * h2;
                a03 += __uint_as_float(p3 << 16) * h3;
                a13 += __uint_as_float(p3) * h3;
            }
            float raw0 = pg0[u] + ((a00 + a01) + (a02 + a03)) + b0;
            float raw1 = pg1[u] + ((a10 + a11) + (a12 + a13)) + b1;
            float hcur = ph[u];
            int s4 = s + 4 + u;
            if (s4 < SS) {
                pg0[u] = gif[gb + (size_t)s4 * 256];
                pg1[u] = gzo[gb + (size_t)s4 * 256];
                ph[u]  = hbuf[hb + (size_t)s4 * 128];
            }
            // half-swap via permlane32_swap (VALU)
            i32x2 r0p = __builtin_amdgcn_permlane32_swap(__float_as_int(raw0), __float_as_int(raw0), false, false);
            i32x2 r1p = __builtin_amdgcn_permlane32_swap(__float_as_int(raw1), __float_as_int(raw1), false, false);
            float q0 = __int_as_float(lo ? r0p.y : r0p.x);
            float q1 = __int_as_float(lo ? r1p.y : r1p.x);
            float iraw = lo ? raw0 : q0;
            float zraw = lo ? raw1 : q1;
            float fraw = lo ? q0 : raw0;
            float oraw = lo ? q1 : raw1;
            float lfm = mst + fminf(fraw, 0.f) - __logf(1.f + __expf(-fabsf(fraw)));
            float mnew = fmaxf(iraw, lfm);
            float ig = __expf(iraw - mnew);
            float fg = __expf(lfm - mnew);
            float e2z = __expf(2.f * zraw);
            float tz = 1.f - 2.f * __builtin_amdgcn_rcpf(e2z + 1.f);
            cst = fg * cst + ig * tz;
            nst = fg * nst + ig;
            mst = mnew;
            float sg = __builtin_amdgcn_rcpf(1.f + __expf(-oraw));
            float hv = sg * cst * __builtin_amdgcn_rcpf(nst);
            hreg = hv;
            // fused group-LN(32) + residual; DPP tree sum over all 64 lanes (= 2x 32-sum)
            float s1 = hv, s2 = hv * hv;
            s1 = DPPADD(s1, 0x111); s2 = DPPADD(s2, 0x111);   // row_shr:1
            s1 = DPPADD(s1, 0x112); s2 = DPPADD(s2, 0x112);   // row_shr:2
            s1 = DPPADD(s1, 0x114); s2 = DPPADD(s2, 0x114);   // row_shr:4
            s1 = DPPADD(s1, 0x118); s2 = DPPADD(s2, 0x118);   // row_shr:8
            s1 = DPPADD(s1, 0x142); s2 = DPPADD(s2, 0x142);   // row_bcast:15
            s1 = DPPADD(s1, 0x143); s2 = DPPADD(s2, 0x143);   // row_bcast:31
            float mu = rdlane(s1, 63) * (1.f / 64.f);
            float var = rdlane(s2, 63) * (1.f / 64.f) - mu * mu;
            float outv = (hv - mu) * rsqrtf(var + 1e-5f) * gw;
            if (lo) hbuf[hb + (size_t)(s + u) * 128] = hcur + outv;
        }
    }
}

// ---------------- gated-GELU (exact erf) -> bf16 ----------------
__global__ __launch_bounds__(256) void geluglu_kernel(const float* __restrict__ xzbuf,
        ushort* __restrict__ gg, int total) {
    int i = blockIdx.x * 256 + threadIdx.x;
    if (i >= total) return;
    int c = i & 255;
    size_t row = (size_t)(i >> 8);
    float g = xzbuf[row * 512 + c];
    float u = xzbuf[row * 512 + 256 + c];
    float ge = 0.5f * g * (1.f + erff(g * 0.70710678118654752f));
    gg[i] = bf16u(ge * u);
}

extern "C" void kernel_launch(void* const* d_in, const int* in_sizes, int n_in,
                              void* d_out, int out_size, void* d_ws, size_t ws_size,
                              hipStream_t stream) {
    const int*   x        = (const int*)d_in[0];
    const float* emb      = (const float*)d_in[1];
    const float* m_ln_w   = (const float*)d_in[2];
    const float* m_up_w   = (const float*)d_in[3];
    const float* m_conv_w = (const float*)d_in[4];
    const float* m_conv_b = (const float*)d_in[5];
    const float* m_q_w    = (const float*)d_in[6];
    const float* m_k_w    = (const float*)d_in[7];
    const float* m_v_w    = (const float*)d_in[8];
    const float* m_ig_w   = (const float*)d_in[9];
    const float* m_ig_b   = (const float*)d_in[10];
    const float* m_fg_w   = (const float*)d_in[11];
    const float* m_fg_b   = (const float*)d_in[12];
    const float* m_on_w   = (const float*)d_in[13];
    const float* m_skip   = (const float*)d_in[14];
    const float* m_down_w = (const float*)d_in[15];
    const float* s_ln1_w  = (const float*)d_in[16];
    const float* s_conv_w = (const float*)d_in[17];
    const float* s_conv_b = (const float*)d_in[18];
    const float* s_ig_w   = (const float*)d_in[19];
    const float* s_fg_w   = (const float*)d_in[20];
    const float* s_zg_w   = (const float*)d_in[21];
    const float* s_og_w   = (const float*)d_in[22];
    const float* s_rec_w  = (const float*)d_in[23];
    const float* s_bias   = (const float*)d_in[24];
    const float* s_gn_w   = (const float*)d_in[25];
    const float* s_ln2_w  = (const float*)d_in[26];
    const float* s_ff_up_w   = (const float*)d_in[27];
    const float* s_ff_down_w = (const float*)d_in[28];
    const float* post_norm_w = (const float*)d_in[29];
    float* out = (float*)d_out;

    float* ws = (float*)d_ws;
    const size_t NR = NROWS;
    float* h   = ws;                   // NR*128
    float* xn  = h   + NR * 128;       // NR*128 fp32 (later qb16 alias)
    float* xz  = xn  + NR * 128;       // NR*512
    float* xca = xz  + NR * 512;       // NR*256
    float* q   = xca + NR * 256;       // NR*256 (qkvb bf16 spans q + half of k; later mpostb; later gif)
    float* k   = q   + NR * 256;       // NR*256 (qkvb tail; later vtb bf16; later gzo fp32)
    float* v   = k   + NR * 256;       // NR*256 (v fp32)
    float* gip = v   + NR * 256;       // 512*256
    float* gfp = gip + 512 * 256;
    float* gL  = gfp + 512 * 256;
    float* gE  = gL  + 512 * 256;
    float* gPM = gE  + 512 * 256;
    float* extra = gPM + 512 * 256;
    // bf16 regions
    ushort* xnb   = (ushort*)extra;                    // NR*128 bf16
    ushort* upb   = (ushort*)(extra + NR * 64);        // 512*128
    ushort* downb = upb + 512 * 128;                   // 128*256
    ushort* ffupb = downb + 128 * 256;                 // 2*512*128
    ushort* ffdownb = ffupb + 2 * 512 * 128;           // 2*128*256
    ushort* sgwb  = ffdownb + 2 * 128 * 256;           // 2*2*256*128
    ushort* w16b  = sgwb + 2 * 2 * 256 * 128;          // 16*768
    // aliases (regions dead at time of use)
    ushort* qkvb   = (ushort*)q;      // NR*768 bf16 (48 MB over q + first half of k; dead after gatege)
    ushort* qb16   = (ushort*)xn;     // NR*256 bf16
    ushort* kb16   = (ushort*)out;    // NR*256 bf16
    ushort* vtb    = (ushort*)k;      // NR*256 bf16 (written by vtrans AFTER gatege consumed qkvb)
    ushort* mpostb = (ushort*)q;      // NR*256 bf16
    ushort* xcb    = (ushort*)(xca + NR * 128);   // NR*128 bf16
    ushort* ggb    = (ushort*)xca;    // NR*256 bf16
    float* gif = q;                   // NR*256 fp32
    float* gzo = k;                   // NR*256 fp32

    // ---- weight conversions ----
    tobf16_kernel<<<(512 * 128 + 255) / 256, 256, 0, stream>>>(m_up_w, upb, 512 * 128);
    tobf16_kernel<<<(128 * 256 + 255) / 256, 256, 0, stream>>>(m_down_w, downb, 128 * 256);
    tobf16_kernel<<<(2 * 512 * 128 + 255) / 256, 256, 0, stream>>>(s_ff_up_w, ffupb, 2 * 512 * 128);
    tobf16_kernel<<<(2 * 128 * 256 + 255) / 256, 256, 0, stream>>>(s_ff_down_w, ffdownb, 2 * 128 * 256);
    densify_kernel<<<(2 * 2 * 256 * 128) / 256, 256, 0, stream>>>(s_ig_w, s_fg_w, s_zg_w, s_og_w, sgwb);
    densify_mgate_kernel<<<(16 * 768 + 255) / 256, 256, 0, stream>>>(m_ig_w, m_fg_w, w16b);

    // ---- embedding + pre-LN ----
    embed_kernel<<<(NR * 128) / 256, 256, 0, stream>>>(x, emb, h, NR * 128);
    ln128_kernel<<<NR, 64, 0, stream>>>(h, m_ln_w, xn, xnb);
    // ---- mLSTM up-projection (bf16 MFMA) ----
    gemm_bf16_kernel<<<dim3(NR / 128, 4), 256, 0, stream>>>(xnb, 128, upb, xz, 512, 128, 0);
    // ---- causal conv + silu ----
    conv_silu_kernel<<<(NR * 256) / 256, 256, 0, stream>>>(xz, 512, 256, m_conv_w, m_conv_b, xca, 256, nullptr, NR * 256);
    // ---- block-diag q,k,v -> packed bf16 qkv + v fp32 + per-head bf16 ----
    mqkv_kernel<<<(NR * 256) / 256, 256, 0, stream>>>(xca, xz, m_q_w, m_k_w, m_v_w, qkvb, v, qb16, kb16, NR * 256);
    // ---- i/f gate projections via skinny MFMA GEMM (replaces shfl-heavy mgate) ----
    gategemm_kernel<<<NR / 128, 256, 0, stream>>>(qkvb, w16b, m_ig_b, m_fg_b, gip, gfp);
    // ---- decay prefix scan ----
    mprep_kernel<<<BB * NH, 64, 0, stream>>>(gip, gfp, gL, gE, gPM);
    // ---- V transpose to bf16 (into k region; qkvb dead now) ----
    vtrans_kernel<<<BB * NH * 4, 256, 0, stream>>>(v, vtb);
    // ---- mLSTM parallel core via MFMA (hm -> x_in half of xz) ----
    mlstm_mfma_kernel<<<BB * NH, 256, 0, stream>>>(qb16, kb16, vtb, gL, gE, gPM, xz);
    // ---- post: group-LN + skip + silu(z) -> bf16 (q region now dead) ----
    mpost_kernel<<<NR, 256, 0, stream>>>(xz, xca, m_on_w, m_skip, mpostb);
    // ---- down-projection + residual (bf16 MFMA, accumulate) ----
    gemm_bf16_kernel<<<dim3(NR / 128, 1), 256, 0, stream>>>(mpostb, 256, downb, h, 128, 256, 1);

    // ---- two sLSTM blocks ----
    for (int i2 = 0; i2 < 2; ++i2) {
        ln128_kernel<<<NR, 64, 0, stream>>>(h, s_ln1_w + i2 * 128, xn, xnb);
        conv_silu_kernel<<<(NR * 128) / 256, 256, 0, stream>>>(xn, 128, 128, s_conv_w + i2 * 128 * 4, s_conv_b + i2 * 128, xca, 128, xcb, NR * 128);
        // gates via dense bf16 GEMMs: [i|f]-perm = xc @ Wif'^T, [z|o]-perm = xn @ Wzo'^T
        gemm_bf16_kernel<<<dim3(NR / 128, 2), 256, 0, stream>>>(xcb, 128, sgwb + (size_t)(i2 * 2 + 0) * 256 * 128, gif, 256, 128, 0);
        gemm_bf16_kernel<<<dim3(NR / 128, 2), 256, 0, stream>>>(xnb, 128, sgwb + (size_t)(i2 * 2 + 1) * 256 * 128, gzo, 256, 128, 0);
        // scan with fused group-LN + residual into h
        slstm_scan_kernel<<<BB * NH, 64, 0, stream>>>(gif, gzo,
                s_rec_w + i2 * 4 * 32 * 128, s_bias + i2 * 4 * 128, s_gn_w + i2 * 128, h);
        ln128_kernel<<<NR, 64, 0, stream>>>(h, s_ln2_w + i2 * 128, xn, xnb);
        gemm_bf16_kernel<<<dim3(NR / 128, 4), 256, 0, stream>>>(xnb, 128, ffupb + (size_t)i2 * 512 * 128, xz, 512, 128, 0);
        geluglu_kernel<<<(NR * 256) / 256, 256, 0, stream>>>(xz, ggb, NR * 256);
        gemm_bf16_kernel<<<dim3(NR / 128, 1), 256, 0, stream>>>(ggb, 256, ffdownb + (size_t)i2 * 128 * 256, h, 128, 256, 1);
    }
    // ---- final LN -> out ----
    ln128_kernel<<<NR, 64, 0, stream>>>(h, post_norm_w, out, xnb);
}

// Round 11
// 974.798 us; speedup vs baseline: 1.0919x; 1.0329x over previous
//
#include <hip/hip_runtime.h>
#include <hip/hip_bf16.h>

// Model dims (compile-time)
#define BB 128
#define SS 256
#define DD 128
#define DI 256      // 2*D
#define NH 4
#define DHM 64      // DI/NH
#define DHS 32      // D/NH
#define NROWS (BB*SS)   // 32768

#define WAVE_SYNC() do { asm volatile("s_waitcnt lgkmcnt(0)" ::: "memory"); __builtin_amdgcn_wave_barrier(); } while (0)

typedef __attribute__((ext_vector_type(8))) short short8;
typedef __attribute__((ext_vector_type(4))) float f32x4;
typedef __attribute__((ext_vector_type(2))) float f32x2;
typedef __attribute__((ext_vector_type(2))) int i32x2;

__device__ __forceinline__ float sigmoidf_(float x) { return 1.f / (1.f + __expf(-x)); }
__device__ __forceinline__ float siluf_(float x) { return x / (1.f + __expf(-x)); }
// stable log_sigmoid
__device__ __forceinline__ float logsigf_(float x) {
    return (x >= 0.f) ? -log1pf(__expf(-x)) : x - log1pf(__expf(x));
}
// fp32 -> bf16 bits, round-to-nearest-even (inputs are finite)
__device__ __forceinline__ ushort bf16u(float x) {
    unsigned u = __float_as_uint(x);
    u += 0x7fffu + ((u >> 16) & 1u);
    return (ushort)(u >> 16);
}
__device__ __forceinline__ float ubf(ushort v) {
    return __uint_as_float((unsigned)v << 16);
}
__device__ __forceinline__ float rdlane(float v, int lane) {
    return __int_as_float(__builtin_amdgcn_readlane(__float_as_int(v), lane));
}
// DPP add: x + dpp(x) with given ctrl (VALU-speed cross-lane; bound_ctrl=1 -> 0 fill)
#define DPPADD(x, ctrl) ((x) + __int_as_float(__builtin_amdgcn_update_dpp(0, __float_as_int(x), (ctrl), 0xf, 0xf, true)))

// ---------------- fp32 -> bf16 copy ----------------
__global__ __launch_bounds__(256) void tobf16_kernel(const float* __restrict__ src,
        ushort* __restrict__ dst, int n) {
    int i = blockIdx.x * 256 + threadIdx.x;
    if (i < n) dst[i] = bf16u(src[i]);
}

// ---------------- densify sLSTM block-diag gate weights -> bf16 [i2][pair][256][128] ----------------
__global__ __launch_bounds__(256) void densify_kernel(const float* __restrict__ wi,
        const float* __restrict__ wf, const float* __restrict__ wz,
        const float* __restrict__ wo, ushort* __restrict__ dst) {
    int idx = blockIdx.x * 256 + threadIdx.x;   // 2*2*256*128 = 262144
    int t = idx & 127;
    int oc = (idx >> 7) & 255;
    int pair = (idx >> 15) & 1;
    int i2 = idx >> 16;
    int h = oc >> 6, l = oc & 63, gate = (l >> 5) & 1, e = l & 31;
    const float* w = pair == 0 ? (gate == 0 ? wi : wf) : (gate == 0 ? wz : wo);
    float val = ((t >> 5) == h) ? w[i2 * 4096 + h * 1024 + e * 32 + (t & 31)] : 0.f;
    dst[idx] = bf16u(val);
}

// ---------------- densify mLSTM gate weights -> bf16 [16][768] (rows 0-3 ig, 4-7 fg, 8-15 zero) ----------------
__global__ __launch_bounds__(256) void densify_mgate_kernel(const float* __restrict__ igw,
        const float* __restrict__ fgw, ushort* __restrict__ dst) {
    int idx = blockIdx.x * 256 + threadIdx.x;   // 16*768 = 12288
    if (idx >= 16 * 768) return;
    int t = idx % 768, j = idx / 768;
    float v = 0.f;
    if (j < 4) v = igw[j * 768 + t];
    else if (j < 8) v = fgw[(j - 4) * 768 + t];
    dst[idx] = bf16u(v);
}

// ---------------- embedding ----------------
__global__ __launch_bounds__(256) void embed_kernel(const int* __restrict__ x,
        const float* __restrict__ emb, float* __restrict__ h, int total) {
    int i = blockIdx.x * 256 + threadIdx.x;
    if (i >= total) return;
    int row = i >> 7;          // D=128
    int c = i & 127;
    h[i] = emb[x[row] * DD + c];
}

// ---------------- LayerNorm over D=128; bf16 out + optional fp32 out ----------------
__global__ __launch_bounds__(64) void ln128_kernel(const float* __restrict__ x,
        const float* __restrict__ w, float* __restrict__ out, ushort* __restrict__ outb) {
    int row = blockIdx.x;
    int lane = threadIdx.x;
    const float* xr = x + (size_t)row * DD;
    float a = xr[lane], b = xr[lane + 64];
    float s1 = a + b, s2 = a * a + b * b;
    #pragma unroll
    for (int o = 32; o; o >>= 1) { s1 += __shfl_xor(s1, o); s2 += __shfl_xor(s2, o); }
    float mu = s1 * (1.f / 128.f);
    float var = s2 * (1.f / 128.f) - mu * mu;
    float inv = rsqrtf(var + 1e-5f);
    float va = (a - mu) * inv * w[lane];
    float vb = (b - mu) * inv * w[lane + 64];
    if (out) {
        float* orow = out + (size_t)row * DD;
        orow[lane] = va; orow[lane + 64] = vb;
    }
    ushort* brow = outb + (size_t)row * DD;
    brow[lane] = bf16u(va); brow[lane + 64] = bf16u(vb);
}

// ---------------- bf16 MFMA GEMM: C[M,N] (+)= A[M,K](lda) @ W[N,K]^T ----------------
// 128x128 tile, BK=32, 4 waves (2x2 of 64x64), XOR-swizzled 16B chunks in LDS.
// Output: bf16 (Cb != null) or fp32 (with optional accumulate).
__global__ __launch_bounds__(256, 2) void gemm_bf16_kernel(const ushort* __restrict__ A, int lda,
        const ushort* __restrict__ W, float* __restrict__ C, ushort* __restrict__ Cb,
        int ldc, int K, int addC) {
    __shared__ ushort As[128 * 32];
    __shared__ ushort Bs[128 * 32];
    int m0 = blockIdx.x * 128;
    int n0 = blockIdx.y * 128;
    int tid = threadIdx.x;
    int wv = tid >> 6, l = tid & 63;
    int lr = l & 15, lg = l >> 4, g4 = lg * 4;
    int wr = wv >> 1, wc = wv & 1;
    int sr = tid >> 1;                  // staging row 0..127
    int sc = (tid & 1) * 2;             // staging chunk base {0,2}

    f32x4 acc[4][4] = {};
    for (int k0 = 0; k0 < K; k0 += 32) {
        __syncthreads();
        #pragma unroll
        for (int u = 0; u < 2; ++u) {
            int c = sc + u;
            uint4 av = *(const uint4*)(A + (size_t)(m0 + sr) * lda + k0 + c * 8);
            *(uint4*)(As + sr * 32 + ((c ^ (sr & 3)) * 8)) = av;
            uint4 wv4 = *(const uint4*)(W + (size_t)(n0 + sr) * K + k0 + c * 8);
            *(uint4*)(Bs + sr * 32 + ((c ^ (sr & 3)) * 8)) = wv4;
        }
        __syncthreads();
        short8 af[4], bf[4];
        #pragma unroll
        for (int fm = 0; fm < 4; ++fm) {
            int row = wr * 64 + fm * 16 + lr;
            af[fm] = *(const short8*)(As + row * 32 + ((lg ^ (row & 3)) * 8));
        }
        #pragma unroll
        for (int fn = 0; fn < 4; ++fn) {
            int row = wc * 64 + fn * 16 + lr;
            bf[fn] = *(const short8*)(Bs + row * 32 + ((lg ^ (row & 3)) * 8));
        }
        #pragma unroll
        for (int fm = 0; fm < 4; ++fm)
            #pragma unroll
            for (int fn = 0; fn < 4; ++fn)
                acc[fm][fn] = __builtin_amdgcn_mfma_f32_16x16x32_bf16(af[fm], bf[fn], acc[fm][fn], 0, 0, 0);
    }
    #pragma unroll
    for (int fm = 0; fm < 4; ++fm) {
        #pragma unroll
        for (int fn = 0; fn < 4; ++fn) {
            #pragma unroll
            for (int r = 0; r < 4; ++r) {
                size_t idx = (size_t)(m0 + wr * 64 + fm * 16 + g4 + r) * ldc + n0 + wc * 64 + fn * 16 + lr;
                if (Cb) Cb[idx] = bf16u(acc[fm][fn][r]);
                else if (addC) C[idx] += acc[fm][fn][r];
                else C[idx] = acc[fm][fn][r];
            }
        }
    }
}

// ---------------- skinny gate GEMM: [ip|fp] = [q|k|v] @ W16^T + bias (M=NR, N=16(8 valid), K=768) ----------------
// Reads per-head bf16 q/k ([bh][s][64]) and row-major v ([row][256]); no LDS, no barriers.
__global__ __launch_bounds__(256) void gategemm_kernel(const ushort* __restrict__ qb,
        const ushort* __restrict__ kb, const ushort* __restrict__ vb,
        const ushort* __restrict__ W16, const float* __restrict__ igb,
        const float* __restrict__ fgb, float* __restrict__ ip, float* __restrict__ fp) {
    int tid = threadIdx.x;
    int wv = tid >> 6, l = tid & 63;
    int lr = l & 15, lg = l >> 4, g4 = lg * 4;
    int row0 = blockIdx.x * 128 + wv * 32;
    f32x4 acc[2] = {};
    #pragma unroll
    for (int k0 = 0; k0 < 768; k0 += 32) {
        short8 bfr = *(const short8*)(W16 + lr * 768 + k0 + lg * 8);
        #pragma unroll
        for (int mi = 0; mi < 2; ++mi) {
            int row = row0 + mi * 16 + lr;
            int b = row >> 8, s = row & 255;
            const ushort* src;
            size_t addr;
            if (k0 < 256) {
                src = qb;
                addr = ((size_t)(b * 4 + (k0 >> 6)) * 256 + s) * 64 + (k0 & 63) + lg * 8;
            } else if (k0 < 512) {
                int kq = k0 - 256;
                src = kb;
                addr = ((size_t)(b * 4 + (kq >> 6)) * 256 + s) * 64 + (kq & 63) + lg * 8;
            } else {
                src = vb;
                addr = (size_t)row * 256 + (k0 - 512) + lg * 8;
            }
            short8 afr = *(const short8*)(src + addr);
            acc[mi] = __builtin_amdgcn_mfma_f32_16x16x32_bf16(afr, bfr, acc[mi], 0, 0, 0);
        }
    }
    if (lr < 8) {
        float bias = (lr < 4) ? igb[lr] : fgb[lr - 4];
        float* dst = (lr < 4) ? ip : fp;
        int hh = lr & 3;
        #pragma unroll
        for (int mi = 0; mi < 2; ++mi) {
            #pragma unroll
            for (int r = 0; r < 4; ++r) {
                int row = row0 + mi * 16 + g4 + r;
                int b = row >> 8, s = row & 255;
                dst[(size_t)(b * 4 + hh) * 256 + s] = acc[mi][r] + bias;
            }
        }
    }
}

// ---------------- sLSTM depthwise causal conv (K=4) + silu: bf16 in [row][128] -> bf16 out ----------------
__global__ __launch_bounds__(256) void conv_silu_s_kernel(const ushort* __restrict__ xb,
        const float* __restrict__ w, const float* __restrict__ bias,
        ushort* __restrict__ outb, int total) {
    int i = blockIdx.x * 256 + threadIdx.x;
    if (i >= total) return;
    int c = i & 127;
    size_t row = (size_t)(i >> 7);
    int s = (int)(row & (SS - 1));
    float acc = bias[c];
    #pragma unroll
    for (int j = 0; j < 4; ++j) {
        int ss = s - 3 + j;
        if (ss >= 0) acc += ubf(xb[(row + (size_t)(j - 3)) * 128 + c]) * w[c * 4 + j];
    }
    outb[i] = bf16u(siluf_(acc));
}

// ---------------- fused mLSTM conv+silu + block-diag q,k,v ----------------
// Reads bf16 xzb [row][512] (x_in|z). Computes conv+silu inline for its 8-channel block,
// then q/k dots on conv output and v dot on raw x_in. Writes xcab bf16 (for mpost skip),
// per-head qb16/kb16 ([bh][s][64]) and row-major vb16 ([row][256]).
__global__ __launch_bounds__(256) void mqkv_kernel(const ushort* __restrict__ xzb,
        const float* __restrict__ cw, const float* __restrict__ cb,
        const float* __restrict__ qw, const float* __restrict__ kw,
        const float* __restrict__ vw, ushort* __restrict__ xcab,
        ushort* __restrict__ qb16, ushort* __restrict__ kb16,
        ushort* __restrict__ vb16, int total) {
    int i = blockIdx.x * 256 + threadIdx.x;
    if (i >= total) return;
    int c = i & 255;
    size_t row = (size_t)(i >> 8);
    int nb = c >> 3, e = c & 7;
    int s = (int)(row & (SS - 1));
    // load 4 tap rows of the 8-channel x_in chunk
    float xin[4][8];
    #pragma unroll
    for (int j = 0; j < 4; ++j) {
        int ss = s - 3 + j;
        if (ss >= 0) {
            short8 v8 = *(const short8*)(xzb + (row + (size_t)(j - 3)) * 512 + nb * 8);
            #pragma unroll
            for (int t = 0; t < 8; ++t) xin[j][t] = ubf((ushort)v8[t]);
        } else {
            #pragma unroll
            for (int t = 0; t < 8; ++t) xin[j][t] = 0.f;
        }
    }
    // conv + silu for the 8 channels (redundant across the 8 threads of this nb — cheap)
    float xc8[8];
    #pragma unroll
    for (int t = 0; t < 8; ++t) {
        int ch = nb * 8 + t;
        float acc = cb[ch];
        #pragma unroll
        for (int j = 0; j < 4; ++j) acc += xin[j][t] * cw[ch * 4 + j];
        xc8[t] = siluf_(acc);
    }
    const float* qw8 = qw + (size_t)(nb * 8 + e) * 8;
    const float* kw8 = kw + (size_t)(nb * 8 + e) * 8;
    const float* vw8 = vw + (size_t)(nb * 8 + e) * 8;
    float aq = 0.f, ak = 0.f, av = 0.f;
    #pragma unroll
    for (int t = 0; t < 8; ++t) {
        aq += xc8[t] * qw8[t];
        ak += xc8[t] * kw8[t];
        av += xin[3][t] * vw8[t];   // j=3 is the current row
    }
    xcab[row * 256 + c] = bf16u(xc8[e]);
    vb16[row * 256 + c] = bf16u(av);
    int h2 = c >> 6, dd = c & 63;
    size_t be = ((((row >> 8) << 2) + h2) * 256 + (row & 255)) * 64 + dd;
    qb16[be] = bf16u(aq);
    kb16[be] = bf16u(ak);
}

// ---------------- mLSTM decay prefix scan: L (cum log-sigmoid), E = ip - L, PM = prefix-max(E) ----------------
__global__ __launch_bounds__(64) void mprep_kernel(const float* __restrict__ ip,
        const float* __restrict__ fp, float* __restrict__ L,
        float* __restrict__ E, float* __restrict__ PM) {
    int bh = blockIdx.x;
    int lane = threadIdx.x;
    __shared__ float sfp[SS], sip[SS], sL[SS], sE[SS], sPM[SS];
    for (int u = lane; u < SS; u += 64) {
        sfp[u] = fp[(size_t)bh * SS + u];
        sip[u] = ip[(size_t)bh * SS + u];
    }
    __syncthreads();
    if (lane == 0) {
        float run = 0.f, pm = -INFINITY;
        for (int j = 0; j < SS; ++j) {
            run += logsigf_(sfp[j]);
            float e = sip[j] - run;
            pm = fmaxf(pm, e);
            sL[j] = run; sE[j] = e; sPM[j] = pm;
        }
    }
    __syncthreads();
    for (int u = lane; u < SS; u += 64) {
        L[(size_t)bh * SS + u] = sL[u];
        E[(size_t)bh * SS + u] = sE[u];
        PM[(size_t)bh * SS + u] = sPM[u];
    }
}

// ---------------- V transpose: bf16 [row][256] -> [bh][64][256] bf16 ----------------
__global__ __launch_bounds__(256) void vtrans_kernel(const ushort* __restrict__ vb,
        ushort* __restrict__ vt) {
    int blk = blockIdx.x;
    int st = blk & 3, bh = blk >> 2;
    int b = bh >> 2, h = bh & 3;
    int tid = threadIdx.x;
    __shared__ ushort tile[64][68];
    int s0 = st * 64;
    #pragma unroll
    for (int u = 0; u < 16; ++u) {
        int idx = u * 256 + tid;
        int sl = idx >> 6, dl = idx & 63;
        tile[sl][dl] = vb[((size_t)(b * 256 + s0 + sl)) * 256 + h * 64 + dl];
    }
    __syncthreads();
    #pragma unroll
    for (int u = 0; u < 16; ++u) {
        int idx = u * 256 + tid;
        int dl = idx >> 6, sl = idx & 63;
        vt[((size_t)bh * 64 + dl) * 256 + s0 + sl] = tile[sl][dl];
    }
}

// ---------------- mLSTM parallel core via MFMA (hm out: fp32 [row][256]) ----------------
__global__ __launch_bounds__(256, 2) void mlstm_mfma_kernel(
        const ushort* __restrict__ qb, const ushort* __restrict__ kb,
        const ushort* __restrict__ vt, const float* __restrict__ Lg,
        const float* __restrict__ Eg, const float* __restrict__ PMg,
        float* __restrict__ hmout) {
    int bh = blockIdx.x;
    int b = bh >> 2, h = bh & 3;
    int tid = threadIdx.x;
    int wv = tid >> 6, l = tid & 63;
    int lr = l & 15, lg = l >> 4, g4 = lg * 4;

    __shared__ ushort Kb[16384];     // 32 KB
    __shared__ ushort Vt[16384];     // 32 KB
    __shared__ ushort Pl[4 * 640];   // per-wave 16x40 bf16
    __shared__ float sE[SS], sPM[SS], sL[SS];

    const size_t gb16 = (size_t)bh * 16384;
    #pragma unroll
    for (int p2 = 0; p2 < 8; ++p2) {
        int id = p2 * 256 + tid;
        int r = id >> 3, c = id & 7;
        uint4 kval = *(const uint4*)(kb + gb16 + r * 64 + c * 8);
        *(uint4*)(Kb + r * 64 + ((c ^ (r & 7)) * 8)) = kval;
        int d = id >> 5, c2 = id & 31;
        uint4 vval = *(const uint4*)(vt + gb16 + d * 256 + c2 * 8);
        *(uint4*)(Vt + d * 256 + ((c2 ^ (d & 7)) * 8)) = vval;
    }
    sE[tid]  = Eg[(size_t)bh * SS + tid];
    sPM[tid] = PMg[(size_t)bh * SS + tid];
    sL[tid]  = Lg[(size_t)bh * SS + tid];
    __syncthreads();

    f32x4 O[4][4] = {};
    float csum[4][4] = {};
    const int pmap[4] = {wv, 7 - wv, 8 + wv, 15 - wv};
    ushort* Pw = Pl + wv * 640;
    size_t obase = (size_t)(b * SS) * 256 + h * 64;

    #pragma unroll
    for (int rf = 0; rf < 4; ++rf) {
        int p = pmap[rf];
        int r0 = p * 16;
        short8 qf0 = *(const short8*)(qb + gb16 + (r0 + lr) * 64 + lg * 8);
        short8 qf1 = *(const short8*)(qb + gb16 + (r0 + lr) * 64 + 32 + lg * 8);
        float pmv[4], lv[4];
        #pragma unroll
        for (int r = 0; r < 4; ++r) { pmv[r] = sPM[r0 + g4 + r]; lv[r] = sL[r0 + g4 + r]; }
        int jtmax = r0 >> 5;
        #pragma unroll 1
        for (int jt = 0; jt <= jtmax; ++jt) {
            int jb = jt * 32;
            f32x4 s0 = {0.f, 0.f, 0.f, 0.f}, s1 = {0.f, 0.f, 0.f, 0.f};
            {
                int j = jb + lr;
                int sw = j & 7;
                short8 k00 = *(const short8*)(Kb + j * 64 + ((lg)     ^ sw) * 8);
                short8 k01 = *(const short8*)(Kb + j * 64 + ((4 + lg) ^ sw) * 8);
                int j2 = jb + 16 + lr;
                int sw2 = j2 & 7;
                short8 k10 = *(const short8*)(Kb + j2 * 64 + ((lg)     ^ sw2) * 8);
                short8 k11 = *(const short8*)(Kb + j2 * 64 + ((4 + lg) ^ sw2) * 8);
                s0 = __builtin_amdgcn_mfma_f32_16x16x32_bf16(qf0, k00, s0, 0, 0, 0);
                s0 = __builtin_amdgcn_mfma_f32_16x16x32_bf16(qf1, k01, s0, 0, 0, 0);
                s1 = __builtin_amdgcn_mfma_f32_16x16x32_bf16(qf0, k10, s1, 0, 0, 0);
                s1 = __builtin_amdgcn_mfma_f32_16x16x32_bf16(qf1, k11, s1, 0, 0, 0);
            }
            float e0 = sE[jb + lr], e1 = sE[jb + 16 + lr];
            int j0 = jb + lr, j1 = jb + 16 + lr;
            #pragma unroll
            for (int r = 0; r < 4; ++r) {
                int i = r0 + g4 + r;
                float sc0 = (j0 <= i) ? s0[r] * 0.125f * __expf(e0 - pmv[r]) : 0.f;
                float sc1 = (j1 <= i) ? s1[r] * 0.125f * __expf(e1 - pmv[r]) : 0.f;
                csum[rf][r] += sc0 + sc1;
                Pw[(g4 + r) * 40 + lr] = bf16u(sc0);
                Pw[(g4 + r) * 40 + 16 + lr] = bf16u(sc1);
            }
            WAVE_SYNC();
            short8 pf = *(const short8*)(Pw + lr * 40 + lg * 8);
            #pragma unroll
            for (int dc = 0; dc < 4; ++dc) {
                int d = dc * 16 + lr;
                int chunk = (jt * 4 + lg) ^ (d & 7);
                short8 vf = *(const short8*)(Vt + d * 256 + chunk * 8);
                O[rf][dc] = __builtin_amdgcn_mfma_f32_16x16x32_bf16(pf, vf, O[rf][dc], 0, 0, 0);
            }
        }
        float rinv[4];
        #pragma unroll
        for (int r = 0; r < 4; ++r) {
            float cs = csum[rf][r];
            cs += __shfl_xor(cs, 1); cs += __shfl_xor(cs, 2);
            cs += __shfl_xor(cs, 4); cs += __shfl_xor(cs, 8);
            float nrm = fmaxf(fabsf(cs), __expf(-(lv[r] + pmv[r]))) + 1e-6f;
            rinv[r] = 1.f / nrm;
        }
        #pragma unroll
        for (int dc = 0; dc < 4; ++dc)
            #pragma unroll
            for (int r = 0; r < 4; ++r)
                hmout[obase + (size_t)(r0 + g4 + r) * 256 + dc * 16 + lr] = O[rf][dc][r] * rinv[r];
    }
}

// ---------------- mLSTM post: group-LN(64) + skip + silu(z) -> bf16 [NR][256] ----------------
__global__ __launch_bounds__(256) void mpost_kernel(const float* __restrict__ hm,
        const ushort* __restrict__ xzb, const ushort* __restrict__ xcab,
        const float* __restrict__ onw, const float* __restrict__ skip,
        ushort* __restrict__ outb) {
    int row = blockIdx.x;
    int t = threadIdx.x;
    float hv = hm[(size_t)row * 256 + t];
    float s1 = hv, s2 = hv * hv;
    #pragma unroll
    for (int o = 32; o; o >>= 1) { s1 += __shfl_xor(s1, o); s2 += __shfl_xor(s2, o); }
    float mu = s1 * (1.f / 64.f);
    float var = s2 * (1.f / 64.f) - mu * mu;
    float xnv = (hv - mu) * rsqrtf(var + 1e-5f) * onw[t];
    float z = ubf(xzb[(size_t)row * 512 + 256 + t]);
    float val = (xnv + skip[t] * ubf(xcab[(size_t)row * 256 + t])) * siluf_(z);
    outb[(size_t)row * 256 + t] = bf16u(val);
}

// ---------------- sLSTM sequential scan: one wave per (b,h), packed-bf16 weights in registers ----------------
__global__ __launch_bounds__(64, 1) void slstm_scan_kernel(const float* __restrict__ gif,
        const float* __restrict__ gzo, const float* __restrict__ rec_w,
        const float* __restrict__ bias, const float* __restrict__ gnw,
        float* __restrict__ hbuf) {
    int bh = blockIdx.x;
    int b = bh >> 2, h = bh & 3;
    int l = threadIdx.x;
    int c = l & 31;
    bool lo = (l < 32);
    unsigned wpk[32];   // bf16(col 64+l) << 16 | bf16(col l)
    const float* wp = rec_w + (size_t)h * 4096 + l;
    #pragma unroll
    for (int d = 0; d < 32; ++d) {
        float w0v = wp[d * 128];
        float w1v = wp[d * 128 + 64];
        wpk[d] = ((unsigned)bf16u(w1v) << 16) | (unsigned)bf16u(w0v);
    }
    float b0 = bias[h * 128 + l];
    float b1 = bias[h * 128 + 64 + l];
    float gw = gnw[h * 32 + c];
    float cst = 0.f, nst = 0.f, mst = 0.f, hreg = 0.f;
    size_t gb = (size_t)b * SS * 256 + h * 64 + l;
    size_t hb = (size_t)b * SS * 128 + h * 32 + c;
    float pg0[4], pg1[4], ph[4];
    #pragma unroll
    for (int u = 0; u < 4; ++u) {
        pg0[u] = gif[gb + (size_t)u * 256];
        pg1[u] = gzo[gb + (size_t)u * 256];
        ph[u]  = hbuf[hb + (size_t)u * 128];
    }
    for (int s = 0; s < SS; s += 4) {
        #pragma unroll
        for (int u = 0; u < 4; ++u) {
            float a00 = 0.f, a01 = 0.f, a02 = 0.f, a03 = 0.f;
            float a10 = 0.f, a11 = 0.f, a12 = 0.f, a13 = 0.f;
            #pragma unroll
            for (int d = 0; d < 32; d += 4) {
                float h0 = rdlane(hreg, d);
                float h1 = rdlane(hreg, d + 1);
                float h2 = rdlane(hreg, d + 2);
                float h3 = rdlane(hreg, d + 3);
                unsigned p0 = wpk[d], p1 = wpk[d + 1], p2 = wpk[d + 2], p3 = wpk[d + 3];
                a00 += __uint_as_float(p0 << 16) * h0;
                a10 += __uint_as_float(p0) * h0;
                a01 += __uint_as_float(p1 << 16) * h1;
                a11 += __uint_as_float(p1) * h1;
                a02 += __uint_as_float(p2 << 16) * h2;
                a12 += __uint_as_float(p2) * h2;
                a03 += __uint_as_float(p3 << 16) * h3;
                a13 += __uint_as_float(p3) * h3;
            }
            float raw0 = pg0[u] + ((a00 + a01) + (a02 + a03)) + b0;
            float raw1 = pg1[u] + ((a10 + a11) + (a12 + a13)) + b1;
            float hcur = ph[u];
            int s4 = s + 4 + u;
            if (s4 < SS) {
                pg0[u] = gif[gb + (size_t)s4 * 256];
                pg1[u] = gzo[gb + (size_t)s4 * 256];
                ph[u]  = hbuf[hb + (size_t)s4 * 128];
            }
            i32x2 r0p = __builtin_amdgcn_permlane32_swap(__float_as_int(raw0), __float_as_int(raw0), false, false);
            i32x2 r1p = __builtin_amdgcn_permlane32_swap(__float_as_int(raw1), __float_as_int(raw1), false, false);
            float q0 = __int_as_float(lo ? r0p.y : r0p.x);
            float q1 = __int_as_float(lo ? r1p.y : r1p.x);
            float iraw = lo ? raw0 : q0;
            float zraw = lo ? raw1 : q1;
            float fraw = lo ? q0 : raw0;
            float oraw = lo ? q1 : raw1;
            float lfm = mst + fminf(fraw, 0.f) - __logf(1.f + __expf(-fabsf(fraw)));
            float mnew = fmaxf(iraw, lfm);
            float ig = __expf(iraw - mnew);
            float fg = __expf(lfm - mnew);
            float e2z = __expf(2.f * zraw);
            float tz = 1.f - 2.f * __builtin_amdgcn_rcpf(e2z + 1.f);
            cst = fg * cst + ig * tz;
            nst = fg * nst + ig;
            mst = mnew;
            float sg = __builtin_amdgcn_rcpf(1.f + __expf(-oraw));
            float hv = sg * cst * __builtin_amdgcn_rcpf(nst);
            hreg = hv;
            float s1 = hv, s2 = hv * hv;
            s1 = DPPADD(s1, 0x111); s2 = DPPADD(s2, 0x111);
            s1 = DPPADD(s1, 0x112); s2 = DPPADD(s2, 0x112);
            s1 = DPPADD(s1, 0x114); s2 = DPPADD(s2, 0x114);
            s1 = DPPADD(s1, 0x118); s2 = DPPADD(s2, 0x118);
            s1 = DPPADD(s1, 0x142); s2 = DPPADD(s2, 0x142);
            s1 = DPPADD(s1, 0x143); s2 = DPPADD(s2, 0x143);
            float mu = rdlane(s1, 63) * (1.f / 64.f);
            float var = rdlane(s2, 63) * (1.f / 64.f) - mu * mu;
            float outv = (hv - mu) * rsqrtf(var + 1e-5f) * gw;
            if (lo) hbuf[hb + (size_t)(s + u) * 128] = hcur + outv;
        }
    }
}

// ---------------- gated-GELU (exact erf): bf16 in [row][512] -> bf16 out [row][256] ----------------
__global__ __launch_bounds__(256) void geluglu_kernel(const ushort* __restrict__ xzb,
        ushort* __restrict__ gg, int total) {
    int i = blockIdx.x * 256 + threadIdx.x;
    if (i >= total) return;
    int c = i & 255;
    size_t row = (size_t)(i >> 8);
    float g = ubf(xzb[row * 512 + c]);
    float u = ubf(xzb[row * 512 + 256 + c]);
    float ge = 0.5f * g * (1.f + erff(g * 0.70710678118654752f));
    gg[i] = bf16u(ge * u);
}

extern "C" void kernel_launch(void* const* d_in, const int* in_sizes, int n_in,
                              void* d_out, int out_size, void* d_ws, size_t ws_size,
                              hipStream_t stream) {
    const int*   x        = (const int*)d_in[0];
    const float* emb      = (const float*)d_in[1];
    const float* m_ln_w   = (const float*)d_in[2];
    const float* m_up_w   = (const float*)d_in[3];
    const float* m_conv_w = (const float*)d_in[4];
    const float* m_conv_b = (const float*)d_in[5];
    const float* m_q_w    = (const float*)d_in[6];
    const float* m_k_w    = (const float*)d_in[7];
    const float* m_v_w    = (const float*)d_in[8];
    const float* m_ig_w   = (const float*)d_in[9];
    const float* m_ig_b   = (const float*)d_in[10];
    const float* m_fg_w   = (const float*)d_in[11];
    const float* m_fg_b   = (const float*)d_in[12];
    const float* m_on_w   = (const float*)d_in[13];
    const float* m_skip   = (const float*)d_in[14];
    const float* m_down_w = (const float*)d_in[15];
    const float* s_ln1_w  = (const float*)d_in[16];
    const float* s_conv_w = (const float*)d_in[17];
    const float* s_conv_b = (const float*)d_in[18];
    const float* s_ig_w   = (const float*)d_in[19];
    const float* s_fg_w   = (const float*)d_in[20];
    const float* s_zg_w   = (const float*)d_in[21];
    const float* s_og_w   = (const float*)d_in[22];
    const float* s_rec_w  = (const float*)d_in[23];
    const float* s_bias   = (const float*)d_in[24];
    const float* s_gn_w   = (const float*)d_in[25];
    const float* s_ln2_w  = (const float*)d_in[26];
    const float* s_ff_up_w   = (const float*)d_in[27];
    const float* s_ff_down_w = (const float*)d_in[28];
    const float* post_norm_w = (const float*)d_in[29];
    float* out = (float*)d_out;

    float* ws = (float*)d_ws;
    const size_t NR = NROWS;
    // fp32 regions
    float* h   = ws;                   // NR*128
    float* hm  = h   + NR * 128;       // NR*256 (mLSTM core out)
    float* gif = hm  + NR * 256;       // NR*256 (sLSTM gates; vtb bf16 aliases in mLSTM phase)
    float* gzo = gif + NR * 256;       // NR*256
    float* gip = gzo + NR * 256;       // 512*256
    float* gfp = gip + 512 * 256;
    float* gL  = gfp + 512 * 256;
    float* gE  = gL  + 512 * 256;
    float* gPM = gE  + 512 * 256;
    float* extra = gPM + 512 * 256;
    // bf16 regions (float-unit sizes halved)
    ushort* xnb   = (ushort*)extra;                    // NR*128 bf16 (NR*64 f)
    ushort* xzb   = xnb + NR * 128;                    // NR*512 bf16 (NR*256 f)
    ushort* xcab  = xzb + NR * 512;                    // NR*256 bf16 (ggb aliases later)
    ushort* qb16  = xcab + NR * 256;                   // NR*256 bf16 (xcb aliases later)
    ushort* vb16  = qb16 + NR * 256;                   // NR*256 bf16
    ushort* upb   = vb16 + NR * 256;                   // 512*128
    ushort* downb = upb + 512 * 128;                   // 128*256
    ushort* ffupb = downb + 128 * 256;                 // 2*512*128
    ushort* ffdownb = ffupb + 2 * 512 * 128;           // 2*128*256
    ushort* sgwb  = ffdownb + 2 * 128 * 256;           // 2*2*256*128
    ushort* w16b  = sgwb + 2 * 2 * 256 * 128;          // 16*768
    // aliases (regions dead at time of use)
    ushort* kb16   = (ushort*)out;    // NR*256 bf16 (d_out; final LN overwrites)
    ushort* vtb    = (ushort*)gif;    // NR*256 bf16 (dead before sLSTM gate GEMMs)
    ushort* mpostb = (ushort*)hm;     // no! hm is read by mpost... use gzo region instead
    mpostb = (ushort*)gzo;            // NR*256 bf16 (gzo unused until sLSTM)
    ushort* xcb    = qb16;            // NR*128 bf16 (qb16 dead after mlstm)
    ushort* ggb    = xcab;            // NR*256 bf16 (xcab dead after mpost)

    // ---- weight conversions ----
    tobf16_kernel<<<(512 * 128 + 255) / 256, 256, 0, stream>>>(m_up_w, upb, 512 * 128);
    tobf16_kernel<<<(128 * 256 + 255) / 256, 256, 0, stream>>>(m_down_w, downb, 128 * 256);
    tobf16_kernel<<<(2 * 512 * 128 + 255) / 256, 256, 0, stream>>>(s_ff_up_w, ffupb, 2 * 512 * 128);
    tobf16_kernel<<<(2 * 128 * 256 + 255) / 256, 256, 0, stream>>>(s_ff_down_w, ffdownb, 2 * 128 * 256);
    densify_kernel<<<(2 * 2 * 256 * 128) / 256, 256, 0, stream>>>(s_ig_w, s_fg_w, s_zg_w, s_og_w, sgwb);
    densify_mgate_kernel<<<(16 * 768 + 255) / 256, 256, 0, stream>>>(m_ig_w, m_fg_w, w16b);

    // ---- embedding + pre-LN (bf16 only) ----
    embed_kernel<<<(NR * 128) / 256, 256, 0, stream>>>(x, emb, h, NR * 128);
    ln128_kernel<<<NR, 64, 0, stream>>>(h, m_ln_w, nullptr, xnb);
    // ---- mLSTM up-projection -> bf16 xzb ----
    gemm_bf16_kernel<<<dim3(NR / 128, 4), 256, 0, stream>>>(xnb, 128, upb, nullptr, xzb, 512, 128, 0);
    // ---- fused conv+silu + block-diag q,k,v ----
    mqkv_kernel<<<(NR * 256) / 256, 256, 0, stream>>>(xzb, m_conv_w, m_conv_b,
            m_q_w, m_k_w, m_v_w, xcab, qb16, kb16, vb16, NR * 256);
    // ---- i/f gate projections via skinny MFMA GEMM ----
    gategemm_kernel<<<NR / 128, 256, 0, stream>>>(qb16, kb16, vb16, w16b, m_ig_b, m_fg_b, gip, gfp);
    // ---- decay prefix scan ----
    mprep_kernel<<<BB * NH, 64, 0, stream>>>(gip, gfp, gL, gE, gPM);
    // ---- V transpose (bf16 -> bf16, into gif region) ----
    vtrans_kernel<<<BB * NH * 4, 256, 0, stream>>>(vb16, vtb);
    // ---- mLSTM parallel core via MFMA -> hm fp32 ----
    mlstm_mfma_kernel<<<BB * NH, 256, 0, stream>>>(qb16, kb16, vtb, gL, gE, gPM, hm);
    // ---- post: group-LN + skip + silu(z) -> bf16 (into gzo region) ----
    mpost_kernel<<<NR, 256, 0, stream>>>(hm, xzb, xcab, m_on_w, m_skip, mpostb);
    // ---- down-projection + residual (fp32 accumulate into h) ----
    gemm_bf16_kernel<<<dim3(NR / 128, 1), 256, 0, stream>>>(mpostb, 256, downb, h, nullptr, 128, 256, 1);

    // ---- two sLSTM blocks ----
    for (int i2 = 0; i2 < 2; ++i2) {
        ln128_kernel<<<NR, 64, 0, stream>>>(h, s_ln1_w + i2 * 128, nullptr, xnb);
        conv_silu_s_kernel<<<(NR * 128) / 256, 256, 0, stream>>>(xnb, s_conv_w + i2 * 128 * 4,
                s_conv_b + i2 * 128, xcb, NR * 128);
        // gates via dense bf16 GEMMs: [i|f]-perm = xc @ Wif'^T, [z|o]-perm = xn @ Wzo'^T
        gemm_bf16_kernel<<<dim3(NR / 128, 2), 256, 0, stream>>>(xcb, 128, sgwb + (size_t)(i2 * 2 + 0) * 256 * 128, gif, nullptr, 256, 128, 0);
        gemm_bf16_kernel<<<dim3(NR / 128, 2), 256, 0, stream>>>(xnb, 128, sgwb + (size_t)(i2 * 2 + 1) * 256 * 128, gzo, nullptr, 256, 128, 0);
        // scan with fused group-LN + residual into h
        slstm_scan_kernel<<<BB * NH, 64, 0, stream>>>(gif, gzo,
                s_rec_w + i2 * 4 * 32 * 128, s_bias + i2 * 4 * 128, s_gn_w + i2 * 128, h);
        ln128_kernel<<<NR, 64, 0, stream>>>(h, s_ln2_w + i2 * 128, nullptr, xnb);
        gemm_bf16_kernel<<<dim3(NR / 128, 4), 256, 0, stream>>>(xnb, 128, ffupb + (size_t)i2 * 512 * 128, nullptr, xzb, 512, 128, 0);
        geluglu_kernel<<<(NR * 256) / 256, 256, 0, stream>>>(xzb, ggb, NR * 256);
        gemm_bf16_kernel<<<dim3(NR / 128, 1), 256, 0, stream>>>(ggb, 256, ffdownb + (size_t)i2 * 128 * 256, h, nullptr, 128, 256, 1);
    }
    // ---- final LN -> out ----
    ln128_kernel<<<NR, 64, 0, stream>>>(h, post_norm_w, out, xnb);
}

// Round 12
// 726.664 us; speedup vs baseline: 1.4647x; 1.3415x over previous
//
#include <hip/hip_runtime.h>
#include <hip/hip_bf16.h>

// Model dims (compile-time)
#define BB 128
#define SS 256
#define DD 128
#define DI 256      // 2*D
#define NH 4
#define DHM 64      // DI/NH
#define DHS 32      // D/NH
#define NROWS (BB*SS)   // 32768

#define WAVE_SYNC() do { asm volatile("s_waitcnt lgkmcnt(0)" ::: "memory"); __builtin_amdgcn_wave_barrier(); } while (0)

typedef __attribute__((ext_vector_type(8))) short short8;
typedef __attribute__((ext_vector_type(4))) float f32x4;
typedef __attribute__((ext_vector_type(2))) int i32x2;

__device__ __forceinline__ float sigmoidf_(float x) { return 1.f / (1.f + __expf(-x)); }
__device__ __forceinline__ float siluf_(float x) { return x / (1.f + __expf(-x)); }
// stable log_sigmoid
__device__ __forceinline__ float logsigf_(float x) {
    return (x >= 0.f) ? -log1pf(__expf(-x)) : x - log1pf(__expf(x));
}
__device__ __forceinline__ float geluf_(float g) {
    return 0.5f * g * (1.f + erff(g * 0.70710678118654752f));
}
// fp32 -> bf16 bits, round-to-nearest-even (inputs are finite)
__device__ __forceinline__ ushort bf16u(float x) {
    unsigned u = __float_as_uint(x);
    u += 0x7fffu + ((u >> 16) & 1u);
    return (ushort)(u >> 16);
}
__device__ __forceinline__ float ubf(ushort v) {
    return __uint_as_float((unsigned)v << 16);
}
__device__ __forceinline__ float rdlane(float v, int lane) {
    return __int_as_float(__builtin_amdgcn_readlane(__float_as_int(v), lane));
}
// DPP add: x + dpp(x) with given ctrl (VALU-speed cross-lane; bound_ctrl=1 -> 0 fill)
#define DPPADD(x, ctrl) ((x) + __int_as_float(__builtin_amdgcn_update_dpp(0, __float_as_int(x), (ctrl), 0xf, 0xf, true)))

// ---------------- fp32 -> bf16 copy ----------------
__global__ __launch_bounds__(256) void tobf16_kernel(const float* __restrict__ src,
        ushort* __restrict__ dst, int n) {
    int i = blockIdx.x * 256 + threadIdx.x;
    if (i < n) dst[i] = bf16u(src[i]);
}

// ---------------- densify sLSTM block-diag gate weights -> bf16 [i2][pair][256][128] ----------------
__global__ __launch_bounds__(256) void densify_kernel(const float* __restrict__ wi,
        const float* __restrict__ wf, const float* __restrict__ wz,
        const float* __restrict__ wo, ushort* __restrict__ dst) {
    int idx = blockIdx.x * 256 + threadIdx.x;   // 2*2*256*128 = 262144
    int t = idx & 127;
    int oc = (idx >> 7) & 255;
    int pair = (idx >> 15) & 1;
    int i2 = idx >> 16;
    int h = oc >> 6, l = oc & 63, gate = (l >> 5) & 1, e = l & 31;
    const float* w = pair == 0 ? (gate == 0 ? wi : wf) : (gate == 0 ? wz : wo);
    float val = ((t >> 5) == h) ? w[i2 * 4096 + h * 1024 + e * 32 + (t & 31)] : 0.f;
    dst[idx] = bf16u(val);
}

// ---------------- densify mLSTM gate weights -> bf16 [16][768] (rows 0-3 ig, 4-7 fg, 8-15 zero) ----------------
__global__ __launch_bounds__(256) void densify_mgate_kernel(const float* __restrict__ igw,
        const float* __restrict__ fgw, ushort* __restrict__ dst) {
    int idx = blockIdx.x * 256 + threadIdx.x;   // 16*768 = 12288
    if (idx >= 16 * 768) return;
    int t = idx % 768, j = idx / 768;
    float v = 0.f;
    if (j < 4) v = igw[j * 768 + t];
    else if (j < 8) v = fgw[(j - 4) * 768 + t];
    dst[idx] = bf16u(v);
}

// ---------------- embedding ----------------
__global__ __launch_bounds__(256) void embed_kernel(const int* __restrict__ x,
        const float* __restrict__ emb, float* __restrict__ h, int total) {
    int i = blockIdx.x * 256 + threadIdx.x;
    if (i >= total) return;
    int row = i >> 7;          // D=128
    int c = i & 127;
    h[i] = emb[x[row] * DD + c];
}

// ---------------- LayerNorm over D=128; 4 rows per 256-thread block; bf16 out + optional fp32 ----------------
__global__ __launch_bounds__(256) void ln128_kernel(const float* __restrict__ x,
        const float* __restrict__ w, float* __restrict__ out, ushort* __restrict__ outb) {
    int row = blockIdx.x * 4 + (threadIdx.x >> 6);
    int lane = threadIdx.x & 63;
    const float* xr = x + (size_t)row * DD;
    float a = xr[lane], b = xr[lane + 64];
    float s1 = a + b, s2 = a * a + b * b;
    #pragma unroll
    for (int o = 32; o; o >>= 1) { s1 += __shfl_xor(s1, o); s2 += __shfl_xor(s2, o); }
    float mu = s1 * (1.f / 128.f);
    float var = s2 * (1.f / 128.f) - mu * mu;
    float inv = rsqrtf(var + 1e-5f);
    float va = (a - mu) * inv * w[lane];
    float vb = (b - mu) * inv * w[lane + 64];
    if (out) {
        float* orow = out + (size_t)row * DD;
        orow[lane] = va; orow[lane + 64] = vb;
    }
    ushort* brow = outb + (size_t)row * DD;
    brow[lane] = bf16u(va); brow[lane + 64] = bf16u(vb);
}

// ---------------- bf16 MFMA GEMM: C[M,N] (+)= A[M,K](lda) @ W[N,K]^T ----------------
// 128x128 tile, BK=32, 4 waves (2x2 of 64x64), XOR-swizzled 16B chunks in LDS.
// Output: bf16 (Cb != null) or fp32 (with optional accumulate).
__global__ __launch_bounds__(256, 2) void gemm_bf16_kernel(const ushort* __restrict__ A, int lda,
        const ushort* __restrict__ W, float* __restrict__ C, ushort* __restrict__ Cb,
        int ldc, int K, int addC) {
    __shared__ ushort As[128 * 32];
    __shared__ ushort Bs[128 * 32];
    int m0 = blockIdx.x * 128;
    int n0 = blockIdx.y * 128;
    int tid = threadIdx.x;
    int wv = tid >> 6, l = tid & 63;
    int lr = l & 15, lg = l >> 4, g4 = lg * 4;
    int wr = wv >> 1, wc = wv & 1;
    int sr = tid >> 1;                  // staging row 0..127
    int sc = (tid & 1) * 2;             // staging chunk base {0,2}

    f32x4 acc[4][4] = {};
    for (int k0 = 0; k0 < K; k0 += 32) {
        __syncthreads();
        #pragma unroll
        for (int u = 0; u < 2; ++u) {
            int c = sc + u;
            uint4 av = *(const uint4*)(A + (size_t)(m0 + sr) * lda + k0 + c * 8);
            *(uint4*)(As + sr * 32 + ((c ^ (sr & 3)) * 8)) = av;
            uint4 wv4 = *(const uint4*)(W + (size_t)(n0 + sr) * K + k0 + c * 8);
            *(uint4*)(Bs + sr * 32 + ((c ^ (sr & 3)) * 8)) = wv4;
        }
        __syncthreads();
        short8 af[4], bf[4];
        #pragma unroll
        for (int fm = 0; fm < 4; ++fm) {
            int row = wr * 64 + fm * 16 + lr;
            af[fm] = *(const short8*)(As + row * 32 + ((lg ^ (row & 3)) * 8));
        }
        #pragma unroll
        for (int fn = 0; fn < 4; ++fn) {
            int row = wc * 64 + fn * 16 + lr;
            bf[fn] = *(const short8*)(Bs + row * 32 + ((lg ^ (row & 3)) * 8));
        }
        #pragma unroll
        for (int fm = 0; fm < 4; ++fm)
            #pragma unroll
            for (int fn = 0; fn < 4; ++fn)
                acc[fm][fn] = __builtin_amdgcn_mfma_f32_16x16x32_bf16(af[fm], bf[fn], acc[fm][fn], 0, 0, 0);
    }
    #pragma unroll
    for (int fm = 0; fm < 4; ++fm) {
        #pragma unroll
        for (int fn = 0; fn < 4; ++fn) {
            #pragma unroll
            for (int r = 0; r < 4; ++r) {
                size_t idx = (size_t)(m0 + wr * 64 + fm * 16 + g4 + r) * ldc + n0 + wc * 64 + fn * 16 + lr;
                if (Cb) Cb[idx] = bf16u(acc[fm][fn][r]);
                else if (addC) C[idx] += acc[fm][fn][r];
                else C[idx] = acc[fm][fn][r];
            }
        }
    }
}

// ---------------- fused GLU + down GEMM: C[M,128] += glu(xzb) @ W[128,256]^T ----------------
// A-transform in staging: a[row][k] = gelu(xzb[row][k]) * xzb[row][256+k]; K=256, N=128 (A staged once).
__global__ __launch_bounds__(256, 2) void gemm_glu_kernel(const ushort* __restrict__ xzb,
        const ushort* __restrict__ W, float* __restrict__ C) {
    __shared__ ushort As[128 * 32];
    __shared__ ushort Bs[128 * 32];
    int m0 = blockIdx.x * 128;
    int tid = threadIdx.x;
    int wv = tid >> 6, l = tid & 63;
    int lr = l & 15, lg = l >> 4, g4 = lg * 4;
    int wr = wv >> 1, wc = wv & 1;
    int sr = tid >> 1;
    int sc = (tid & 1) * 2;

    f32x4 acc[4][4] = {};
    for (int k0 = 0; k0 < 256; k0 += 32) {
        __syncthreads();
        #pragma unroll
        for (int u = 0; u < 2; ++u) {
            int c = sc + u;
            short8 g8 = *(const short8*)(xzb + (size_t)(m0 + sr) * 512 + k0 + c * 8);
            short8 u8 = *(const short8*)(xzb + (size_t)(m0 + sr) * 512 + 256 + k0 + c * 8);
            short8 o8;
            #pragma unroll
            for (int t = 0; t < 8; ++t)
                o8[t] = (short)bf16u(geluf_(ubf((ushort)g8[t])) * ubf((ushort)u8[t]));
            *(short8*)(As + sr * 32 + ((c ^ (sr & 3)) * 8)) = o8;
            uint4 wv4 = *(const uint4*)(W + (size_t)sr * 256 + k0 + c * 8);
            *(uint4*)(Bs + sr * 32 + ((c ^ (sr & 3)) * 8)) = wv4;
        }
        __syncthreads();
        short8 af[4], bf[4];
        #pragma unroll
        for (int fm = 0; fm < 4; ++fm) {
            int row = wr * 64 + fm * 16 + lr;
            af[fm] = *(const short8*)(As + row * 32 + ((lg ^ (row & 3)) * 8));
        }
        #pragma unroll
        for (int fn = 0; fn < 4; ++fn) {
            int row = wc * 64 + fn * 16 + lr;
            bf[fn] = *(const short8*)(Bs + row * 32 + ((lg ^ (row & 3)) * 8));
        }
        #pragma unroll
        for (int fm = 0; fm < 4; ++fm)
            #pragma unroll
            for (int fn = 0; fn < 4; ++fn)
                acc[fm][fn] = __builtin_amdgcn_mfma_f32_16x16x32_bf16(af[fm], bf[fn], acc[fm][fn], 0, 0, 0);
    }
    #pragma unroll
    for (int fm = 0; fm < 4; ++fm) {
        #pragma unroll
        for (int fn = 0; fn < 4; ++fn) {
            #pragma unroll
            for (int r = 0; r < 4; ++r) {
                size_t idx = (size_t)(m0 + wr * 64 + fm * 16 + g4 + r) * 128 + wc * 64 + fn * 16 + lr;
                C[idx] += acc[fm][fn][r];
            }
        }
    }
}

// ---------------- skinny gate GEMM: [ip|fp] = [q|k|v] @ W16^T + bias (M=NR, N=16(8 valid), K=768) ----------------
__global__ __launch_bounds__(256) void gategemm_kernel(const ushort* __restrict__ qb,
        const ushort* __restrict__ kb, const ushort* __restrict__ vb,
        const ushort* __restrict__ W16, const float* __restrict__ igb,
        const float* __restrict__ fgb, float* __restrict__ ip, float* __restrict__ fp) {
    int tid = threadIdx.x;
    int wv = tid >> 6, l = tid & 63;
    int lr = l & 15, lg = l >> 4, g4 = lg * 4;
    int row0 = blockIdx.x * 128 + wv * 32;
    f32x4 acc[2] = {};
    #pragma unroll
    for (int k0 = 0; k0 < 768; k0 += 32) {
        short8 bfr = *(const short8*)(W16 + lr * 768 + k0 + lg * 8);
        #pragma unroll
        for (int mi = 0; mi < 2; ++mi) {
            int row = row0 + mi * 16 + lr;
            int b = row >> 8, s = row & 255;
            const ushort* src;
            size_t addr;
            if (k0 < 256) {
                src = qb;
                addr = ((size_t)(b * 4 + (k0 >> 6)) * 256 + s) * 64 + (k0 & 63) + lg * 8;
            } else if (k0 < 512) {
                int kq = k0 - 256;
                src = kb;
                addr = ((size_t)(b * 4 + (kq >> 6)) * 256 + s) * 64 + (kq & 63) + lg * 8;
            } else {
                src = vb;
                addr = (size_t)row * 256 + (k0 - 512) + lg * 8;
            }
            short8 afr = *(const short8*)(src + addr);
            acc[mi] = __builtin_amdgcn_mfma_f32_16x16x32_bf16(afr, bfr, acc[mi], 0, 0, 0);
        }
    }
    if (lr < 8) {
        float bias = (lr < 4) ? igb[lr] : fgb[lr - 4];
        float* dst = (lr < 4) ? ip : fp;
        int hh = lr & 3;
        #pragma unroll
        for (int mi = 0; mi < 2; ++mi) {
            #pragma unroll
            for (int r = 0; r < 4; ++r) {
                int row = row0 + mi * 16 + g4 + r;
                int b = row >> 8, s = row & 255;
                dst[(size_t)(b * 4 + hh) * 256 + s] = acc[mi][r] + bias;
            }
        }
    }
}

// ---------------- sLSTM depthwise causal conv (K=4) + silu: bf16 in [row][128] -> bf16 out ----------------
__global__ __launch_bounds__(256) void conv_silu_s_kernel(const ushort* __restrict__ xb,
        const float* __restrict__ w, const float* __restrict__ bias,
        ushort* __restrict__ outb, int total) {
    int i = blockIdx.x * 256 + threadIdx.x;
    if (i >= total) return;
    int c = i & 127;
    size_t row = (size_t)(i >> 7);
    int s = (int)(row & (SS - 1));
    float acc = bias[c];
    #pragma unroll
    for (int j = 0; j < 4; ++j) {
        int ss = s - 3 + j;
        if (ss >= 0) acc += ubf(xb[(row + (size_t)(j - 3)) * 128 + c]) * w[c * 4 + j];
    }
    outb[i] = bf16u(siluf_(acc));
}

// ---------------- fused mLSTM conv+silu + block-diag q,k,v ----------------
__global__ __launch_bounds__(256) void mqkv_kernel(const ushort* __restrict__ xzb,
        const float* __restrict__ cw, const float* __restrict__ cb,
        const float* __restrict__ qw, const float* __restrict__ kw,
        const float* __restrict__ vw, ushort* __restrict__ xcab,
        ushort* __restrict__ qb16, ushort* __restrict__ kb16,
        ushort* __restrict__ vb16, int total) {
    int i = blockIdx.x * 256 + threadIdx.x;
    if (i >= total) return;
    int c = i & 255;
    size_t row = (size_t)(i >> 8);
    int nb = c >> 3, e = c & 7;
    int s = (int)(row & (SS - 1));
    float xin[4][8];
    #pragma unroll
    for (int j = 0; j < 4; ++j) {
        int ss = s - 3 + j;
        if (ss >= 0) {
            short8 v8 = *(const short8*)(xzb + (row + (size_t)(j - 3)) * 512 + nb * 8);
            #pragma unroll
            for (int t = 0; t < 8; ++t) xin[j][t] = ubf((ushort)v8[t]);
        } else {
            #pragma unroll
            for (int t = 0; t < 8; ++t) xin[j][t] = 0.f;
        }
    }
    float xc8[8];
    #pragma unroll
    for (int t = 0; t < 8; ++t) {
        int ch = nb * 8 + t;
        float acc = cb[ch];
        #pragma unroll
        for (int j = 0; j < 4; ++j) acc += xin[j][t] * cw[ch * 4 + j];
        xc8[t] = siluf_(acc);
    }
    const float* qw8 = qw + (size_t)(nb * 8 + e) * 8;
    const float* kw8 = kw + (size_t)(nb * 8 + e) * 8;
    const float* vw8 = vw + (size_t)(nb * 8 + e) * 8;
    float aq = 0.f, ak = 0.f, av = 0.f;
    #pragma unroll
    for (int t = 0; t < 8; ++t) {
        aq += xc8[t] * qw8[t];
        ak += xc8[t] * kw8[t];
        av += xin[3][t] * vw8[t];   // j=3 is the current row
    }
    xcab[row * 256 + c] = bf16u(xc8[e]);
    vb16[row * 256 + c] = bf16u(av);
    int h2 = c >> 6, dd = c & 63;
    size_t be = ((((row >> 8) << 2) + h2) * 256 + (row & 255)) * 64 + dd;
    qb16[be] = bf16u(aq);
    kb16[be] = bf16u(ak);
}

// ---------------- mLSTM decay prefix scan (wave-parallel): L, E = ip - L, PM = prefix-max(E) ----------------
__global__ __launch_bounds__(64) void mprep_kernel(const float* __restrict__ ip,
        const float* __restrict__ fp, float* __restrict__ L,
        float* __restrict__ E, float* __restrict__ PM) {
    int bh = blockIdx.x;
    int lane = threadIdx.x;
    size_t base = (size_t)bh * SS + lane * 4;
    float lsv[4], ipv[4];
    #pragma unroll
    for (int u = 0; u < 4; ++u) {
        lsv[u] = logsigf_(fp[base + u]);
        ipv[u] = ip[base + u];
    }
    float p0 = lsv[0], p1 = p0 + lsv[1], p2 = p1 + lsv[2], p3 = p2 + lsv[3];
    // wave inclusive scan of p3 -> exclusive offset
    float inc = p3;
    #pragma unroll
    for (int o = 1; o < 64; o <<= 1) {
        float wv = __shfl_up(inc, o);
        if (lane >= o) inc += wv;
    }
    float excl = inc - p3;
    float Lv[4] = {excl + p0, excl + p1, excl + p2, excl + p3};
    float Ev[4];
    #pragma unroll
    for (int u = 0; u < 4; ++u) Ev[u] = ipv[u] - Lv[u];
    float q0 = Ev[0], q1 = fmaxf(q0, Ev[1]), q2 = fmaxf(q1, Ev[2]), q3 = fmaxf(q2, Ev[3]);
    float incm = q3;
    #pragma unroll
    for (int o = 1; o < 64; o <<= 1) {
        float wv = __shfl_up(incm, o);
        if (lane >= o) incm = fmaxf(incm, wv);
    }
    float exm = __shfl_up(incm, 1);
    if (lane == 0) exm = -INFINITY;
    float qv[4] = {q0, q1, q2, q3};
    #pragma unroll
    for (int u = 0; u < 4; ++u) {
        L[base + u] = Lv[u];
        E[base + u] = Ev[u];
        PM[base + u] = fmaxf(exm, qv[u]);
    }
}

// ---------------- V transpose: bf16 [row][256] -> [bh][64][256] bf16 ----------------
__global__ __launch_bounds__(256) void vtrans_kernel(const ushort* __restrict__ vb,
        ushort* __restrict__ vt) {
    int blk = blockIdx.x;
    int st = blk & 3, bh = blk >> 2;
    int b = bh >> 2, h = bh & 3;
    int tid = threadIdx.x;
    __shared__ ushort tile[64][68];
    int s0 = st * 64;
    #pragma unroll
    for (int u = 0; u < 16; ++u) {
        int idx = u * 256 + tid;
        int sl = idx >> 6, dl = idx & 63;
        tile[sl][dl] = vb[((size_t)(b * 256 + s0 + sl)) * 256 + h * 64 + dl];
    }
    __syncthreads();
    #pragma unroll
    for (int u = 0; u < 16; ++u) {
        int idx = u * 256 + tid;
        int dl = idx >> 6, sl = idx & 63;
        vt[((size_t)bh * 64 + dl) * 256 + s0 + sl] = tile[sl][dl];
    }
}

// ---------------- mLSTM parallel core via MFMA (hm out: fp32 [row][256]) ----------------
__global__ __launch_bounds__(256, 2) void mlstm_mfma_kernel(
        const ushort* __restrict__ qb, const ushort* __restrict__ kb,
        const ushort* __restrict__ vt, const float* __restrict__ Lg,
        const float* __restrict__ Eg, const float* __restrict__ PMg,
        float* __restrict__ hmout) {
    int bh = blockIdx.x;
    int b = bh >> 2, h = bh & 3;
    int tid = threadIdx.x;
    int wv = tid >> 6, l = tid & 63;
    int lr = l & 15, lg = l >> 4, g4 = lg * 4;

    __shared__ ushort Kb[16384];     // 32 KB
    __shared__ ushort Vt[16384];     // 32 KB
    __shared__ ushort Pl[4 * 640];   // per-wave 16x40 bf16
    __shared__ float sE[SS], sPM[SS], sL[SS];

    const size_t gb16 = (size_t)bh * 16384;
    #pragma unroll
    for (int p2 = 0; p2 < 8; ++p2) {
        int id = p2 * 256 + tid;
        int r = id >> 3, c = id & 7;
        uint4 kval = *(const uint4*)(kb + gb16 + r * 64 + c * 8);
        *(uint4*)(Kb + r * 64 + ((c ^ (r & 7)) * 8)) = kval;
        int d = id >> 5, c2 = id & 31;
        uint4 vval = *(const uint4*)(vt + gb16 + d * 256 + c2 * 8);
        *(uint4*)(Vt + d * 256 + ((c2 ^ (d & 7)) * 8)) = vval;
    }
    sE[tid]  = Eg[(size_t)bh * SS + tid];
    sPM[tid] = PMg[(size_t)bh * SS + tid];
    sL[tid]  = Lg[(size_t)bh * SS + tid];
    __syncthreads();

    f32x4 O[4][4] = {};
    float csum[4][4] = {};
    const int pmap[4] = {wv, 7 - wv, 8 + wv, 15 - wv};
    ushort* Pw = Pl + wv * 640;
    size_t obase = (size_t)(b * SS) * 256 + h * 64;

    #pragma unroll
    for (int rf = 0; rf < 4; ++rf) {
        int p = pmap[rf];
        int r0 = p * 16;
        short8 qf0 = *(const short8*)(qb + gb16 + (r0 + lr) * 64 + lg * 8);
        short8 qf1 = *(const short8*)(qb + gb16 + (r0 + lr) * 64 + 32 + lg * 8);
        float pmv[4], lv[4];
        #pragma unroll
        for (int r = 0; r < 4; ++r) { pmv[r] = sPM[r0 + g4 + r]; lv[r] = sL[r0 + g4 + r]; }
        int jtmax = r0 >> 5;
        #pragma unroll 1
        for (int jt = 0; jt <= jtmax; ++jt) {
            int jb = jt * 32;
            f32x4 s0 = {0.f, 0.f, 0.f, 0.f}, s1 = {0.f, 0.f, 0.f, 0.f};
            {
                int j = jb + lr;
                int sw = j & 7;
                short8 k00 = *(const short8*)(Kb + j * 64 + ((lg)     ^ sw) * 8);
                short8 k01 = *(const short8*)(Kb + j * 64 + ((4 + lg) ^ sw) * 8);
                int j2 = jb + 16 + lr;
                int sw2 = j2 & 7;
                short8 k10 = *(const short8*)(Kb + j2 * 64 + ((lg)     ^ sw2) * 8);
                short8 k11 = *(const short8*)(Kb + j2 * 64 + ((4 + lg) ^ sw2) * 8);
                s0 = __builtin_amdgcn_mfma_f32_16x16x32_bf16(qf0, k00, s0, 0, 0, 0);
                s0 = __builtin_amdgcn_mfma_f32_16x16x32_bf16(qf1, k01, s0, 0, 0, 0);
                s1 = __builtin_amdgcn_mfma_f32_16x16x32_bf16(qf0, k10, s1, 0, 0, 0);
                s1 = __builtin_amdgcn_mfma_f32_16x16x32_bf16(qf1, k11, s1, 0, 0, 0);
            }
            float e0 = sE[jb + lr], e1 = sE[jb + 16 + lr];
            int j0 = jb + lr, j1 = jb + 16 + lr;
            #pragma unroll
            for (int r = 0; r < 4; ++r) {
                int i = r0 + g4 + r;
                float sc0 = (j0 <= i) ? s0[r] * 0.125f * __expf(e0 - pmv[r]) : 0.f;
                float sc1 = (j1 <= i) ? s1[r] * 0.125f * __expf(e1 - pmv[r]) : 0.f;
                csum[rf][r] += sc0 + sc1;
                Pw[(g4 + r) * 40 + lr] = bf16u(sc0);
                Pw[(g4 + r) * 40 + 16 + lr] = bf16u(sc1);
            }
            WAVE_SYNC();
            short8 pf = *(const short8*)(Pw + lr * 40 + lg * 8);
            #pragma unroll
            for (int dc = 0; dc < 4; ++dc) {
                int d = dc * 16 + lr;
                int chunk = (jt * 4 + lg) ^ (d & 7);
                short8 vf = *(const short8*)(Vt + d * 256 + chunk * 8);
                O[rf][dc] = __builtin_amdgcn_mfma_f32_16x16x32_bf16(pf, vf, O[rf][dc], 0, 0, 0);
            }
        }
        float rinv[4];
        #pragma unroll
        for (int r = 0; r < 4; ++r) {
            float cs = csum[rf][r];
            cs += __shfl_xor(cs, 1); cs += __shfl_xor(cs, 2);
            cs += __shfl_xor(cs, 4); cs += __shfl_xor(cs, 8);
            float nrm = fmaxf(fabsf(cs), __expf(-(lv[r] + pmv[r]))) + 1e-6f;
            rinv[r] = 1.f / nrm;
        }
        #pragma unroll
        for (int dc = 0; dc < 4; ++dc)
            #pragma unroll
            for (int r = 0; r < 4; ++r)
                hmout[obase + (size_t)(r0 + g4 + r) * 256 + dc * 16 + lr] = O[rf][dc][r] * rinv[r];
    }
}

// ---------------- mLSTM post: group-LN(64) + skip + silu(z) -> bf16 [NR][256] ----------------
__global__ __launch_bounds__(256) void mpost_kernel(const float* __restrict__ hm,
        const ushort* __restrict__ xzb, const ushort* __restrict__ xcab,
        const float* __restrict__ onw, const float* __restrict__ skip,
        ushort* __restrict__ outb) {
    int row = blockIdx.x;
    int t = threadIdx.x;
    float hv = hm[(size_t)row * 256 + t];
    float s1 = hv, s2 = hv * hv;
    #pragma unroll
    for (int o = 32; o; o >>= 1) { s1 += __shfl_xor(s1, o); s2 += __shfl_xor(s2, o); }
    float mu = s1 * (1.f / 64.f);
    float var = s2 * (1.f / 64.f) - mu * mu;
    float xnv = (hv - mu) * rsqrtf(var + 1e-5f) * onw[t];
    float z = ubf(xzb[(size_t)row * 512 + 256 + t]);
    float val = (xnv + skip[t] * ubf(xcab[(size_t)row * 256 + t])) * siluf_(z);
    outb[(size_t)row * 256 + t] = bf16u(val);
}

// ---------------- sLSTM sequential scan: one wave per (b,h), bf16 gates, no m-stabilizer ----------------
// c/n ratio is invariant under the e^m stabilizer scaling: C=sig(f)C+e^i*tanh(z), N=sig(f)N+e^i,
// h=sig(o)*C/N is exactly the reference recurrence. Shortens the serial trans chain by
// logsig(exp+log)+max+2exp per step. Overflow-safe: |iraw|<~10 -> N <= 256*e^10 << fp32 max.
__global__ __launch_bounds__(64, 1) void slstm_scan_kernel(const ushort* __restrict__ gifb,
        const ushort* __restrict__ gzob, const float* __restrict__ rec_w,
        const float* __restrict__ bias, const float* __restrict__ gnw,
        float* __restrict__ hbuf) {
    int bh = blockIdx.x;
    int b = bh >> 2, h = bh & 3;
    int l = threadIdx.x;
    int c = l & 31;
    bool lo = (l < 32);
    unsigned wpk[32];   // bf16(col 64+l) << 16 | bf16(col l)
    const float* wp = rec_w + (size_t)h * 4096 + l;
    #pragma unroll
    for (int d = 0; d < 32; ++d) {
        float w0v = wp[d * 128];
        float w1v = wp[d * 128 + 64];
        wpk[d] = ((unsigned)bf16u(w1v) << 16) | (unsigned)bf16u(w0v);
    }
    float b0 = bias[h * 128 + l];
    float b1 = bias[h * 128 + 64 + l];
    float gw = gnw[h * 32 + c];
    float cst = 0.f, nst = 0.f, hreg = 0.f;
    size_t gb = (size_t)b * SS * 256 + h * 64 + l;
    size_t hb = (size_t)b * SS * 128 + h * 32 + c;
    float pg0[4], pg1[4], ph[4];
    #pragma unroll
    for (int u = 0; u < 4; ++u) {
        pg0[u] = ubf(gifb[gb + (size_t)u * 256]);
        pg1[u] = ubf(gzob[gb + (size_t)u * 256]);
        ph[u]  = hbuf[hb + (size_t)u * 128];
    }
    for (int s = 0; s < SS; s += 4) {
        #pragma unroll
        for (int u = 0; u < 4; ++u) {
            float a00 = 0.f, a01 = 0.f, a02 = 0.f, a03 = 0.f;
            float a10 = 0.f, a11 = 0.f, a12 = 0.f, a13 = 0.f;
            #pragma unroll
            for (int d = 0; d < 32; d += 4) {
                float h0 = rdlane(hreg, d);
                float h1 = rdlane(hreg, d + 1);
                float h2 = rdlane(hreg, d + 2);
                float h3 = rdlane(hreg, d + 3);
                unsigned p0 = wpk[d], p1 = wpk[d + 1], p2 = wpk[d + 2], p3 = wpk[d + 3];
                a00 += __uint_as_float(p0 << 16) * h0;
                a10 += __uint_as_float(p0) * h0;
                a01 += __uint_as_float(p1 << 16) * h1;
                a11 += __uint_as_float(p1) * h1;
                a02 += __uint_as_float(p2 << 16) * h2;
                a12 += __uint_as_float(p2) * h2;
                a03 += __uint_as_float(p3 << 16) * h3;
                a13 += __uint_as_float(p3) * h3;
            }
            float raw0 = pg0[u] + ((a00 + a01) + (a02 + a03)) + b0;
            float raw1 = pg1[u] + ((a10 + a11) + (a12 + a13)) + b1;
            float hcur = ph[u];
            int s4 = s + 4 + u;
            if (s4 < SS) {
                pg0[u] = ubf(gifb[gb + (size_t)s4 * 256]);
                pg1[u] = ubf(gzob[gb + (size_t)s4 * 256]);
                ph[u]  = hbuf[hb + (size_t)s4 * 128];
            }
            i32x2 r0p = __builtin_amdgcn_permlane32_swap(__float_as_int(raw0), __float_as_int(raw0), false, false);
            i32x2 r1p = __builtin_amdgcn_permlane32_swap(__float_as_int(raw1), __float_as_int(raw1), false, false);
            float q0 = __int_as_float(lo ? r0p.y : r0p.x);
            float q1 = __int_as_float(lo ? r1p.y : r1p.x);
            float iraw = lo ? raw0 : q0;
            float zraw = lo ? raw1 : q1;
            float fraw = lo ? q0 : raw0;
            float oraw = lo ? q1 : raw1;
            float fg = __builtin_amdgcn_rcpf(1.f + __expf(-fraw));
            float ig = __expf(iraw);
            float e2z = __expf(2.f * zraw);
            float tz = 1.f - 2.f * __builtin_amdgcn_rcpf(e2z + 1.f);
            cst = fg * cst + ig * tz;
            nst = fg * nst + ig;
            float sg = __builtin_amdgcn_rcpf(1.f + __expf(-oraw));
            float hv = sg * cst * __builtin_amdgcn_rcpf(nst);
            hreg = hv;
            float s1 = hv, s2 = hv * hv;
            s1 = DPPADD(s1, 0x111); s2 = DPPADD(s2, 0x111);
            s1 = DPPADD(s1, 0x112); s2 = DPPADD(s2, 0x112);
            s1 = DPPADD(s1, 0x114); s2 = DPPADD(s2, 0x114);
            s1 = DPPADD(s1, 0x118); s2 = DPPADD(s2, 0x118);
            s1 = DPPADD(s1, 0x142); s2 = DPPADD(s2, 0x142);
            s1 = DPPADD(s1, 0x143); s2 = DPPADD(s2, 0x143);
            float mu = rdlane(s1, 63) * (1.f / 64.f);
            float var = rdlane(s2, 63) * (1.f / 64.f) - mu * mu;
            float outv = (hv - mu) * rsqrtf(var + 1e-5f) * gw;
            if (lo) hbuf[hb + (size_t)(s + u) * 128] = hcur + outv;
        }
    }
}

extern "C" void kernel_launch(void* const* d_in, const int* in_sizes, int n_in,
                              void* d_out, int out_size, void* d_ws, size_t ws_size,
                              hipStream_t stream) {
    const int*   x        = (const int*)d_in[0];
    const float* emb      = (const float*)d_in[1];
    const float* m_ln_w   = (const float*)d_in[2];
    const float* m_up_w   = (const float*)d_in[3];
    const float* m_conv_w = (const float*)d_in[4];
    const float* m_conv_b = (const float*)d_in[5];
    const float* m_q_w    = (const float*)d_in[6];
    const float* m_k_w    = (const float*)d_in[7];
    const float* m_v_w    = (const float*)d_in[8];
    const float* m_ig_w   = (const float*)d_in[9];
    const float* m_ig_b   = (const float*)d_in[10];
    const float* m_fg_w   = (const float*)d_in[11];
    const float* m_fg_b   = (const float*)d_in[12];
    const float* m_on_w   = (const float*)d_in[13];
    const float* m_skip   = (const float*)d_in[14];
    const float* m_down_w = (const float*)d_in[15];
    const float* s_ln1_w  = (const float*)d_in[16];
    const float* s_conv_w = (const float*)d_in[17];
    const float* s_conv_b = (const float*)d_in[18];
    const float* s_ig_w   = (const float*)d_in[19];
    const float* s_fg_w   = (const float*)d_in[20];
    const float* s_zg_w   = (const float*)d_in[21];
    const float* s_og_w   = (const float*)d_in[22];
    const float* s_rec_w  = (const float*)d_in[23];
    const float* s_bias   = (const float*)d_in[24];
    const float* s_gn_w   = (const float*)d_in[25];
    const float* s_ln2_w  = (const float*)d_in[26];
    const float* s_ff_up_w   = (const float*)d_in[27];
    const float* s_ff_down_w = (const float*)d_in[28];
    const float* post_norm_w = (const float*)d_in[29];
    float* out = (float*)d_out;

    float* ws = (float*)d_ws;
    const size_t NR = NROWS;
    // fp32 regions
    float* h   = ws;                   // NR*128
    float* hm  = h   + NR * 128;       // NR*256 (mLSTM core out)
    float* regA = hm  + NR * 256;      // NR*128 f: vtb (mLSTM) / gifb (sLSTM) as NR*256 ushort
    float* regB = regA + NR * 128;     // NR*128 f: mpostb (mLSTM) / gzob (sLSTM)
    float* gip = regB + NR * 128;      // 512*256
    float* gfp = gip + 512 * 256;
    float* gL  = gfp + 512 * 256;
    float* gE  = gL  + 512 * 256;
    float* gPM = gE  + 512 * 256;
    float* extra = gPM + 512 * 256;
    // bf16 regions
    ushort* xnb   = (ushort*)extra;                    // NR*128 bf16
    ushort* xzb   = xnb + NR * 128;                    // NR*512 bf16
    ushort* xcab  = xzb + NR * 512;                    // NR*256 bf16
    ushort* qb16  = xcab + NR * 256;                   // NR*256 bf16 (xcb aliases in sLSTM)
    ushort* vb16  = qb16 + NR * 256;                   // NR*256 bf16
    ushort* upb   = vb16 + NR * 256;                   // 512*128
    ushort* downb = upb + 512 * 128;                   // 128*256
    ushort* ffupb = downb + 128 * 256;                 // 2*512*128
    ushort* ffdownb = ffupb + 2 * 512 * 128;           // 2*128*256
    ushort* sgwb  = ffdownb + 2 * 128 * 256;           // 2*2*256*128
    ushort* w16b  = sgwb + 2 * 2 * 256 * 128;          // 16*768
    // aliases (regions dead at time of use)
    ushort* kb16   = (ushort*)out;    // NR*256 bf16 (d_out; final LN overwrites)
    ushort* vtb    = (ushort*)regA;   // NR*256 bf16 (mLSTM phase)
    ushort* gifb   = (ushort*)regA;   // NR*256 bf16 (sLSTM phase)
    ushort* mpostb = (ushort*)regB;   // NR*256 bf16 (mLSTM phase)
    ushort* gzob   = (ushort*)regB;   // NR*256 bf16 (sLSTM phase)
    ushort* xcb    = qb16;            // NR*128 bf16 (qb16 dead after mlstm)

    // ---- weight conversions ----
    tobf16_kernel<<<(512 * 128 + 255) / 256, 256, 0, stream>>>(m_up_w, upb, 512 * 128);
    tobf16_kernel<<<(128 * 256 + 255) / 256, 256, 0, stream>>>(m_down_w, downb, 128 * 256);
    tobf16_kernel<<<(2 * 512 * 128 + 255) / 256, 256, 0, stream>>>(s_ff_up_w, ffupb, 2 * 512 * 128);
    tobf16_kernel<<<(2 * 128 * 256 + 255) / 256, 256, 0, stream>>>(s_ff_down_w, ffdownb, 2 * 128 * 256);
    densify_kernel<<<(2 * 2 * 256 * 128) / 256, 256, 0, stream>>>(s_ig_w, s_fg_w, s_zg_w, s_og_w, sgwb);
    densify_mgate_kernel<<<(16 * 768 + 255) / 256, 256, 0, stream>>>(m_ig_w, m_fg_w, w16b);

    // ---- embedding + pre-LN ----
    embed_kernel<<<(NR * 128) / 256, 256, 0, stream>>>(x, emb, h, NR * 128);
    ln128_kernel<<<NR / 4, 256, 0, stream>>>(h, m_ln_w, nullptr, xnb);
    // ---- mLSTM up-projection -> bf16 xzb ----
    gemm_bf16_kernel<<<dim3(NR / 128, 4), 256, 0, stream>>>(xnb, 128, upb, nullptr, xzb, 512, 128, 0);
    // ---- fused conv+silu + block-diag q,k,v ----
    mqkv_kernel<<<(NR * 256) / 256, 256, 0, stream>>>(xzb, m_conv_w, m_conv_b,
            m_q_w, m_k_w, m_v_w, xcab, qb16, kb16, vb16, NR * 256);
    // ---- i/f gate projections via skinny MFMA GEMM ----
    gategemm_kernel<<<NR / 128, 256, 0, stream>>>(qb16, kb16, vb16, w16b, m_ig_b, m_fg_b, gip, gfp);
    // ---- decay prefix scan (wave-parallel) ----
    mprep_kernel<<<BB * NH, 64, 0, stream>>>(gip, gfp, gL, gE, gPM);
    // ---- V transpose ----
    vtrans_kernel<<<BB * NH * 4, 256, 0, stream>>>(vb16, vtb);
    // ---- mLSTM parallel core via MFMA -> hm fp32 ----
    mlstm_mfma_kernel<<<BB * NH, 256, 0, stream>>>(qb16, kb16, vtb, gL, gE, gPM, hm);
    // ---- post: group-LN + skip + silu(z) -> bf16 ----
    mpost_kernel<<<NR, 256, 0, stream>>>(hm, xzb, xcab, m_on_w, m_skip, mpostb);
    // ---- down-projection + residual (fp32 accumulate into h) ----
    gemm_bf16_kernel<<<dim3(NR / 128, 1), 256, 0, stream>>>(mpostb, 256, downb, h, nullptr, 128, 256, 1);

    // ---- two sLSTM blocks ----
    for (int i2 = 0; i2 < 2; ++i2) {
        ln128_kernel<<<NR / 4, 256, 0, stream>>>(h, s_ln1_w + i2 * 128, nullptr, xnb);
        conv_silu_s_kernel<<<(NR * 128) / 256, 256, 0, stream>>>(xnb, s_conv_w + i2 * 128 * 4,
                s_conv_b + i2 * 128, xcb, NR * 128);
        // gates via dense bf16 GEMMs -> bf16 out
        gemm_bf16_kernel<<<dim3(NR / 128, 2), 256, 0, stream>>>(xcb, 128, sgwb + (size_t)(i2 * 2 + 0) * 256 * 128, nullptr, gifb, 256, 128, 0);
        gemm_bf16_kernel<<<dim3(NR / 128, 2), 256, 0, stream>>>(xnb, 128, sgwb + (size_t)(i2 * 2 + 1) * 256 * 128, nullptr, gzob, 256, 128, 0);
        // scan with fused group-LN + residual into h
        slstm_scan_kernel<<<BB * NH, 64, 0, stream>>>(gifb, gzob,
                s_rec_w + i2 * 4 * 32 * 128, s_bias + i2 * 4 * 128, s_gn_w + i2 * 128, h);
        ln128_kernel<<<NR / 4, 256, 0, stream>>>(h, s_ln2_w + i2 * 128, nullptr, xnb);
        gemm_bf16_kernel<<<dim3(NR / 128, 4), 256, 0, stream>>>(xnb, 128, ffupb + (size_t)i2 * 512 * 128, nullptr, xzb, 512, 128, 0);
        // fused GLU + down-projection (+ residual into h)
        gemm_glu_kernel<<<NR / 128, 256, 0, stream>>>(xzb, ffdownb + (size_t)i2 * 128 * 256, h);
    }
    // ---- final LN -> out ----
    ln128_kernel<<<NR / 4, 256, 0, stream>>>(h, post_norm_w, out, xnb);
}

// Round 13
// 685.678 us; speedup vs baseline: 1.5523x; 1.0598x over previous
//
#include <hip/hip_runtime.h>
#include <hip/hip_bf16.h>

// Model dims (compile-time)
#define BB 128
#define SS 256
#define DD 128
#define DI 256      // 2*D
#define NH 4
#define DHM 64      // DI/NH
#define DHS 32      // D/NH
#define NROWS (BB*SS)   // 32768

#define WAVE_SYNC() do { asm volatile("s_waitcnt lgkmcnt(0)" ::: "memory"); __builtin_amdgcn_wave_barrier(); } while (0)

typedef __attribute__((ext_vector_type(8))) short short8;
typedef __attribute__((ext_vector_type(4))) float f32x4;
typedef __attribute__((ext_vector_type(2))) int i32x2;

__device__ __forceinline__ float sigmoidf_(float x) { return 1.f / (1.f + __expf(-x)); }
__device__ __forceinline__ float siluf_(float x) { return x / (1.f + __expf(-x)); }
// stable log_sigmoid
__device__ __forceinline__ float logsigf_(float x) {
    return (x >= 0.f) ? -log1pf(__expf(-x)) : x - log1pf(__expf(x));
}
__device__ __forceinline__ float geluf_(float g) {
    return 0.5f * g * (1.f + erff(g * 0.70710678118654752f));
}
// fp32 -> bf16 bits, round-to-nearest-even (inputs are finite)
__device__ __forceinline__ ushort bf16u(float x) {
    unsigned u = __float_as_uint(x);
    u += 0x7fffu + ((u >> 16) & 1u);
    return (ushort)(u >> 16);
}
__device__ __forceinline__ float ubf(ushort v) {
    return __uint_as_float((unsigned)v << 16);
}
__device__ __forceinline__ float rdlane(float v, int lane) {
    return __int_as_float(__builtin_amdgcn_readlane(__float_as_int(v), lane));
}
// DPP add: x + dpp(x) with given ctrl (VALU-speed cross-lane; bound_ctrl=1 -> 0 fill)
#define DPPADD(x, ctrl) ((x) + __int_as_float(__builtin_amdgcn_update_dpp(0, __float_as_int(x), (ctrl), 0xf, 0xf, true)))

// ---------------- fused weight prep: all bf16 conversions + densify in ONE launch ----------------
// regions (element index space):
// [0,65536) upb=m_up_w | [65536,98304) downb=m_down_w | [98304,229376) ffupb | [229376,294912) ffdownb
// [294912,557056) sgwb densify | [557056,569344) w16b mgate densify
__global__ __launch_bounds__(256) void wprep_kernel(const float* __restrict__ m_up_w,
        const float* __restrict__ m_down_w, const float* __restrict__ s_ff_up_w,
        const float* __restrict__ s_ff_down_w, const float* __restrict__ wi,
        const float* __restrict__ wf, const float* __restrict__ wz,
        const float* __restrict__ wo, const float* __restrict__ igw,
        const float* __restrict__ fgw,
        ushort* __restrict__ upb, ushort* __restrict__ downb,
        ushort* __restrict__ ffupb, ushort* __restrict__ ffdownb,
        ushort* __restrict__ sgwb, ushort* __restrict__ w16b) {
    int gid = blockIdx.x * 256 + threadIdx.x;
    if (gid < 65536) {
        upb[gid] = bf16u(m_up_w[gid]);
    } else if (gid < 98304) {
        int i = gid - 65536;
        downb[i] = bf16u(m_down_w[i]);
    } else if (gid < 229376) {
        int i = gid - 98304;
        ffupb[i] = bf16u(s_ff_up_w[i]);
    } else if (gid < 294912) {
        int i = gid - 229376;
        ffdownb[i] = bf16u(s_ff_down_w[i]);
    } else if (gid < 557056) {
        int idx = gid - 294912;
        int t = idx & 127;
        int oc = (idx >> 7) & 255;
        int pair = (idx >> 15) & 1;
        int i2 = idx >> 16;
        int h = oc >> 6, l = oc & 63, gate = (l >> 5) & 1, e = l & 31;
        const float* w = pair == 0 ? (gate == 0 ? wi : wf) : (gate == 0 ? wz : wo);
        float val = ((t >> 5) == h) ? w[i2 * 4096 + h * 1024 + e * 32 + (t & 31)] : 0.f;
        sgwb[idx] = bf16u(val);
    } else if (gid < 569344) {
        int idx = gid - 557056;
        int t = idx % 768, j = idx / 768;
        float v = 0.f;
        if (j < 4) v = igw[j * 768 + t];
        else if (j < 8) v = fgw[(j - 4) * 768 + t];
        w16b[idx] = bf16u(v);
    }
}

// ---------------- fused embedding + pre-LN: 4 rows per block; h fp32 + xnb bf16 ----------------
__global__ __launch_bounds__(256) void embed_ln_kernel(const int* __restrict__ x,
        const float* __restrict__ emb, const float* __restrict__ w,
        float* __restrict__ h, ushort* __restrict__ outb) {
    int row = blockIdx.x * 4 + (threadIdx.x >> 6);
    int lane = threadIdx.x & 63;
    int tok = x[row];
    float a = emb[tok * DD + lane], b = emb[tok * DD + 64 + lane];
    h[(size_t)row * DD + lane] = a;
    h[(size_t)row * DD + 64 + lane] = b;
    float s1 = a + b, s2 = a * a + b * b;
    #pragma unroll
    for (int o = 32; o; o >>= 1) { s1 += __shfl_xor(s1, o); s2 += __shfl_xor(s2, o); }
    float mu = s1 * (1.f / 128.f);
    float var = s2 * (1.f / 128.f) - mu * mu;
    float inv = rsqrtf(var + 1e-5f);
    ushort* brow = outb + (size_t)row * DD;
    brow[lane] = bf16u((a - mu) * inv * w[lane]);
    brow[lane + 64] = bf16u((b - mu) * inv * w[lane + 64]);
}

// ---------------- LayerNorm over D=128; 4 rows per 256-thread block; bf16 and/or fp32 out ----------------
__global__ __launch_bounds__(256) void ln128_kernel(const float* __restrict__ x,
        const float* __restrict__ w, float* __restrict__ out, ushort* __restrict__ outb) {
    int row = blockIdx.x * 4 + (threadIdx.x >> 6);
    int lane = threadIdx.x & 63;
    const float* xr = x + (size_t)row * DD;
    float a = xr[lane], b = xr[lane + 64];
    float s1 = a + b, s2 = a * a + b * b;
    #pragma unroll
    for (int o = 32; o; o >>= 1) { s1 += __shfl_xor(s1, o); s2 += __shfl_xor(s2, o); }
    float mu = s1 * (1.f / 128.f);
    float var = s2 * (1.f / 128.f) - mu * mu;
    float inv = rsqrtf(var + 1e-5f);
    float va = (a - mu) * inv * w[lane];
    float vb = (b - mu) * inv * w[lane + 64];
    if (out) {
        float* orow = out + (size_t)row * DD;
        orow[lane] = va; orow[lane + 64] = vb;
    }
    if (outb) {
        ushort* brow = outb + (size_t)row * DD;
        brow[lane] = bf16u(va); brow[lane + 64] = bf16u(vb);
    }
}

// ---------------- bf16 MFMA GEMM: C[M,N] (+)= A[M,K](lda) @ W[N,K]^T ----------------
__global__ __launch_bounds__(256, 2) void gemm_bf16_kernel(const ushort* __restrict__ A, int lda,
        const ushort* __restrict__ W, float* __restrict__ C, ushort* __restrict__ Cb,
        int ldc, int K, int addC) {
    __shared__ ushort As[128 * 32];
    __shared__ ushort Bs[128 * 32];
    int m0 = blockIdx.x * 128;
    int n0 = blockIdx.y * 128;
    int tid = threadIdx.x;
    int wv = tid >> 6, l = tid & 63;
    int lr = l & 15, lg = l >> 4, g4 = lg * 4;
    int wr = wv >> 1, wc = wv & 1;
    int sr = tid >> 1;
    int sc = (tid & 1) * 2;

    f32x4 acc[4][4] = {};
    for (int k0 = 0; k0 < K; k0 += 32) {
        __syncthreads();
        #pragma unroll
        for (int u = 0; u < 2; ++u) {
            int c = sc + u;
            uint4 av = *(const uint4*)(A + (size_t)(m0 + sr) * lda + k0 + c * 8);
            *(uint4*)(As + sr * 32 + ((c ^ (sr & 3)) * 8)) = av;
            uint4 wv4 = *(const uint4*)(W + (size_t)(n0 + sr) * K + k0 + c * 8);
            *(uint4*)(Bs + sr * 32 + ((c ^ (sr & 3)) * 8)) = wv4;
        }
        __syncthreads();
        short8 af[4], bf[4];
        #pragma unroll
        for (int fm = 0; fm < 4; ++fm) {
            int row = wr * 64 + fm * 16 + lr;
            af[fm] = *(const short8*)(As + row * 32 + ((lg ^ (row & 3)) * 8));
        }
        #pragma unroll
        for (int fn = 0; fn < 4; ++fn) {
            int row = wc * 64 + fn * 16 + lr;
            bf[fn] = *(const short8*)(Bs + row * 32 + ((lg ^ (row & 3)) * 8));
        }
        #pragma unroll
        for (int fm = 0; fm < 4; ++fm)
            #pragma unroll
            for (int fn = 0; fn < 4; ++fn)
                acc[fm][fn] = __builtin_amdgcn_mfma_f32_16x16x32_bf16(af[fm], bf[fn], acc[fm][fn], 0, 0, 0);
    }
    #pragma unroll
    for (int fm = 0; fm < 4; ++fm) {
        #pragma unroll
        for (int fn = 0; fn < 4; ++fn) {
            #pragma unroll
            for (int r = 0; r < 4; ++r) {
                size_t idx = (size_t)(m0 + wr * 64 + fm * 16 + g4 + r) * ldc + n0 + wc * 64 + fn * 16 + lr;
                if (Cb) Cb[idx] = bf16u(acc[fm][fn][r]);
                else if (addC) C[idx] += acc[fm][fn][r];
                else C[idx] = acc[fm][fn][r];
            }
        }
    }
}

// ---------------- merged sLSTM gate GEMMs: grid.y in [0,4): y<2 -> gif=xcb@Wif^T, y>=2 -> gzo=xnb@Wzo^T ----------------
__global__ __launch_bounds__(256, 2) void sgate_gemm_kernel(const ushort* __restrict__ xcb,
        const ushort* __restrict__ xnb, const ushort* __restrict__ Wif,
        const ushort* __restrict__ Wzo, ushort* __restrict__ gifb, ushort* __restrict__ gzob) {
    __shared__ ushort As[128 * 32];
    __shared__ ushort Bs[128 * 32];
    int y = blockIdx.y;
    const ushort* A = (y < 2) ? xcb : xnb;
    const ushort* W = (y < 2) ? Wif : Wzo;
    ushort* Cb = (y < 2) ? gifb : gzob;
    int m0 = blockIdx.x * 128;
    int n0 = (y & 1) * 128;
    int tid = threadIdx.x;
    int wv = tid >> 6, l = tid & 63;
    int lr = l & 15, lg = l >> 4, g4 = lg * 4;
    int wr = wv >> 1, wc = wv & 1;
    int sr = tid >> 1;
    int sc = (tid & 1) * 2;

    f32x4 acc[4][4] = {};
    for (int k0 = 0; k0 < 128; k0 += 32) {
        __syncthreads();
        #pragma unroll
        for (int u = 0; u < 2; ++u) {
            int c = sc + u;
            uint4 av = *(const uint4*)(A + (size_t)(m0 + sr) * 128 + k0 + c * 8);
            *(uint4*)(As + sr * 32 + ((c ^ (sr & 3)) * 8)) = av;
            uint4 wv4 = *(const uint4*)(W + (size_t)(n0 + sr) * 128 + k0 + c * 8);
            *(uint4*)(Bs + sr * 32 + ((c ^ (sr & 3)) * 8)) = wv4;
        }
        __syncthreads();
        short8 af[4], bf[4];
        #pragma unroll
        for (int fm = 0; fm < 4; ++fm) {
            int row = wr * 64 + fm * 16 + lr;
            af[fm] = *(const short8*)(As + row * 32 + ((lg ^ (row & 3)) * 8));
        }
        #pragma unroll
        for (int fn = 0; fn < 4; ++fn) {
            int row = wc * 64 + fn * 16 + lr;
            bf[fn] = *(const short8*)(Bs + row * 32 + ((lg ^ (row & 3)) * 8));
        }
        #pragma unroll
        for (int fm = 0; fm < 4; ++fm)
            #pragma unroll
            for (int fn = 0; fn < 4; ++fn)
                acc[fm][fn] = __builtin_amdgcn_mfma_f32_16x16x32_bf16(af[fm], bf[fn], acc[fm][fn], 0, 0, 0);
    }
    #pragma unroll
    for (int fm = 0; fm < 4; ++fm)
        #pragma unroll
        for (int fn = 0; fn < 4; ++fn)
            #pragma unroll
            for (int r = 0; r < 4; ++r) {
                size_t idx = (size_t)(m0 + wr * 64 + fm * 16 + g4 + r) * 256 + n0 + wc * 64 + fn * 16 + lr;
                Cb[idx] = bf16u(acc[fm][fn][r]);
            }
}

// ---------------- fused GLU + down GEMM: C[M,128] += glu(xzb) @ W[128,256]^T ----------------
__global__ __launch_bounds__(256, 2) void gemm_glu_kernel(const ushort* __restrict__ xzb,
        const ushort* __restrict__ W, float* __restrict__ C) {
    __shared__ ushort As[128 * 32];
    __shared__ ushort Bs[128 * 32];
    int m0 = blockIdx.x * 128;
    int tid = threadIdx.x;
    int wv = tid >> 6, l = tid & 63;
    int lr = l & 15, lg = l >> 4, g4 = lg * 4;
    int wr = wv >> 1, wc = wv & 1;
    int sr = tid >> 1;
    int sc = (tid & 1) * 2;

    f32x4 acc[4][4] = {};
    for (int k0 = 0; k0 < 256; k0 += 32) {
        __syncthreads();
        #pragma unroll
        for (int u = 0; u < 2; ++u) {
            int c = sc + u;
            short8 g8 = *(const short8*)(xzb + (size_t)(m0 + sr) * 512 + k0 + c * 8);
            short8 u8 = *(const short8*)(xzb + (size_t)(m0 + sr) * 512 + 256 + k0 + c * 8);
            short8 o8;
            #pragma unroll
            for (int t = 0; t < 8; ++t)
                o8[t] = (short)bf16u(geluf_(ubf((ushort)g8[t])) * ubf((ushort)u8[t]));
            *(short8*)(As + sr * 32 + ((c ^ (sr & 3)) * 8)) = o8;
            uint4 wv4 = *(const uint4*)(W + (size_t)sr * 256 + k0 + c * 8);
            *(uint4*)(Bs + sr * 32 + ((c ^ (sr & 3)) * 8)) = wv4;
        }
        __syncthreads();
        short8 af[4], bf[4];
        #pragma unroll
        for (int fm = 0; fm < 4; ++fm) {
            int row = wr * 64 + fm * 16 + lr;
            af[fm] = *(const short8*)(As + row * 32 + ((lg ^ (row & 3)) * 8));
        }
        #pragma unroll
        for (int fn = 0; fn < 4; ++fn) {
            int row = wc * 64 + fn * 16 + lr;
            bf[fn] = *(const short8*)(Bs + row * 32 + ((lg ^ (row & 3)) * 8));
        }
        #pragma unroll
        for (int fm = 0; fm < 4; ++fm)
            #pragma unroll
            for (int fn = 0; fn < 4; ++fn)
                acc[fm][fn] = __builtin_amdgcn_mfma_f32_16x16x32_bf16(af[fm], bf[fn], acc[fm][fn], 0, 0, 0);
    }
    #pragma unroll
    for (int fm = 0; fm < 4; ++fm)
        #pragma unroll
        for (int fn = 0; fn < 4; ++fn)
            #pragma unroll
            for (int r = 0; r < 4; ++r) {
                size_t idx = (size_t)(m0 + wr * 64 + fm * 16 + g4 + r) * 128 + wc * 64 + fn * 16 + lr;
                C[idx] += acc[fm][fn][r];
            }
}

// ---------------- skinny gate GEMM: [ip|fp] = [q|k|v] @ W16^T + bias ----------------
__global__ __launch_bounds__(256) void gategemm_kernel(const ushort* __restrict__ qb,
        const ushort* __restrict__ kb, const ushort* __restrict__ vb,
        const ushort* __restrict__ W16, const float* __restrict__ igb,
        const float* __restrict__ fgb, float* __restrict__ ip, float* __restrict__ fp) {
    int tid = threadIdx.x;
    int wv = tid >> 6, l = tid & 63;
    int lr = l & 15, lg = l >> 4, g4 = lg * 4;
    int row0 = blockIdx.x * 128 + wv * 32;
    f32x4 acc[2] = {};
    #pragma unroll
    for (int k0 = 0; k0 < 768; k0 += 32) {
        short8 bfr = *(const short8*)(W16 + lr * 768 + k0 + lg * 8);
        #pragma unroll
        for (int mi = 0; mi < 2; ++mi) {
            int row = row0 + mi * 16 + lr;
            int b = row >> 8, s = row & 255;
            const ushort* src;
            size_t addr;
            if (k0 < 256) {
                src = qb;
                addr = ((size_t)(b * 4 + (k0 >> 6)) * 256 + s) * 64 + (k0 & 63) + lg * 8;
            } else if (k0 < 512) {
                int kq = k0 - 256;
                src = kb;
                addr = ((size_t)(b * 4 + (kq >> 6)) * 256 + s) * 64 + (kq & 63) + lg * 8;
            } else {
                src = vb;
                addr = (size_t)row * 256 + (k0 - 512) + lg * 8;
            }
            short8 afr = *(const short8*)(src + addr);
            acc[mi] = __builtin_amdgcn_mfma_f32_16x16x32_bf16(afr, bfr, acc[mi], 0, 0, 0);
        }
    }
    if (lr < 8) {
        float bias = (lr < 4) ? igb[lr] : fgb[lr - 4];
        float* dst = (lr < 4) ? ip : fp;
        int hh = lr & 3;
        #pragma unroll
        for (int mi = 0; mi < 2; ++mi) {
            #pragma unroll
            for (int r = 0; r < 4; ++r) {
                int row = row0 + mi * 16 + g4 + r;
                int b = row >> 8, s = row & 255;
                dst[(size_t)(b * 4 + hh) * 256 + s] = acc[mi][r] + bias;
            }
        }
    }
}

// ---------------- sLSTM depthwise causal conv (K=4) + silu: bf16 -> bf16 ----------------
__global__ __launch_bounds__(256) void conv_silu_s_kernel(const ushort* __restrict__ xb,
        const float* __restrict__ w, const float* __restrict__ bias,
        ushort* __restrict__ outb, int total) {
    int i = blockIdx.x * 256 + threadIdx.x;
    if (i >= total) return;
    int c = i & 127;
    size_t row = (size_t)(i >> 7);
    int s = (int)(row & (SS - 1));
    float acc = bias[c];
    #pragma unroll
    for (int j = 0; j < 4; ++j) {
        int ss = s - 3 + j;
        if (ss >= 0) acc += ubf(xb[(row + (size_t)(j - 3)) * 128 + c]) * w[c * 4 + j];
    }
    outb[i] = bf16u(siluf_(acc));
}

// ---------------- fused mLSTM conv+silu + block-diag q,k,v ----------------
__global__ __launch_bounds__(256) void mqkv_kernel(const ushort* __restrict__ xzb,
        const float* __restrict__ cw, const float* __restrict__ cb,
        const float* __restrict__ qw, const float* __restrict__ kw,
        const float* __restrict__ vw, ushort* __restrict__ xcab,
        ushort* __restrict__ qb16, ushort* __restrict__ kb16,
        ushort* __restrict__ vb16, int total) {
    int i = blockIdx.x * 256 + threadIdx.x;
    if (i >= total) return;
    int c = i & 255;
    size_t row = (size_t)(i >> 8);
    int nb = c >> 3, e = c & 7;
    int s = (int)(row & (SS - 1));
    float xin[4][8];
    #pragma unroll
    for (int j = 0; j < 4; ++j) {
        int ss = s - 3 + j;
        if (ss >= 0) {
            short8 v8 = *(const short8*)(xzb + (row + (size_t)(j - 3)) * 512 + nb * 8);
            #pragma unroll
            for (int t = 0; t < 8; ++t) xin[j][t] = ubf((ushort)v8[t]);
        } else {
            #pragma unroll
            for (int t = 0; t < 8; ++t) xin[j][t] = 0.f;
        }
    }
    float xc8[8];
    #pragma unroll
    for (int t = 0; t < 8; ++t) {
        int ch = nb * 8 + t;
        float acc = cb[ch];
        #pragma unroll
        for (int j = 0; j < 4; ++j) acc += xin[j][t] * cw[ch * 4 + j];
        xc8[t] = siluf_(acc);
    }
    const float* qw8 = qw + (size_t)(nb * 8 + e) * 8;
    const float* kw8 = kw + (size_t)(nb * 8 + e) * 8;
    const float* vw8 = vw + (size_t)(nb * 8 + e) * 8;
    float aq = 0.f, ak = 0.f, av = 0.f;
    #pragma unroll
    for (int t = 0; t < 8; ++t) {
        aq += xc8[t] * qw8[t];
        ak += xc8[t] * kw8[t];
        av += xin[3][t] * vw8[t];   // j=3 is the current row
    }
    xcab[row * 256 + c] = bf16u(xc8[e]);
    vb16[row * 256 + c] = bf16u(av);
    int h2 = c >> 6, dd = c & 63;
    size_t be = ((((row >> 8) << 2) + h2) * 256 + (row & 255)) * 64 + dd;
    qb16[be] = bf16u(aq);
    kb16[be] = bf16u(ak);
}

// ---------------- mLSTM decay prefix scan (wave-parallel) ----------------
__global__ __launch_bounds__(64) void mprep_kernel(const float* __restrict__ ip,
        const float* __restrict__ fp, float* __restrict__ L,
        float* __restrict__ E, float* __restrict__ PM) {
    int bh = blockIdx.x;
    int lane = threadIdx.x;
    size_t base = (size_t)bh * SS + lane * 4;
    float lsv[4], ipv[4];
    #pragma unroll
    for (int u = 0; u < 4; ++u) {
        lsv[u] = logsigf_(fp[base + u]);
        ipv[u] = ip[base + u];
    }
    float p0 = lsv[0], p1 = p0 + lsv[1], p2 = p1 + lsv[2], p3 = p2 + lsv[3];
    float inc = p3;
    #pragma unroll
    for (int o = 1; o < 64; o <<= 1) {
        float wv = __shfl_up(inc, o);
        if (lane >= o) inc += wv;
    }
    float excl = inc - p3;
    float Lv[4] = {excl + p0, excl + p1, excl + p2, excl + p3};
    float Ev[4];
    #pragma unroll
    for (int u = 0; u < 4; ++u) Ev[u] = ipv[u] - Lv[u];
    float q0 = Ev[0], q1 = fmaxf(q0, Ev[1]), q2 = fmaxf(q1, Ev[2]), q3 = fmaxf(q2, Ev[3]);
    float incm = q3;
    #pragma unroll
    for (int o = 1; o < 64; o <<= 1) {
        float wv = __shfl_up(incm, o);
        if (lane >= o) incm = fmaxf(incm, wv);
    }
    float exm = __shfl_up(incm, 1);
    if (lane == 0) exm = -INFINITY;
    float qv[4] = {q0, q1, q2, q3};
    #pragma unroll
    for (int u = 0; u < 4; ++u) {
        L[base + u] = Lv[u];
        E[base + u] = Ev[u];
        PM[base + u] = fmaxf(exm, qv[u]);
    }
}

// ---------------- V transpose: bf16 [row][256] -> [bh][64][256] bf16 ----------------
__global__ __launch_bounds__(256) void vtrans_kernel(const ushort* __restrict__ vb,
        ushort* __restrict__ vt) {
    int blk = blockIdx.x;
    int st = blk & 3, bh = blk >> 2;
    int b = bh >> 2, h = bh & 3;
    int tid = threadIdx.x;
    __shared__ ushort tile[64][68];
    int s0 = st * 64;
    #pragma unroll
    for (int u = 0; u < 16; ++u) {
        int idx = u * 256 + tid;
        int sl = idx >> 6, dl = idx & 63;
        tile[sl][dl] = vb[((size_t)(b * 256 + s0 + sl)) * 256 + h * 64 + dl];
    }
    __syncthreads();
    #pragma unroll
    for (int u = 0; u < 16; ++u) {
        int idx = u * 256 + tid;
        int dl = idx >> 6, sl = idx & 63;
        vt[((size_t)bh * 64 + dl) * 256 + s0 + sl] = tile[sl][dl];
    }
}

// ---------------- mLSTM parallel core via MFMA + fused mpost (group-LN + skip + silu(z)) ----------------
// Epilogue LN: row's 64 head-channels live in one 16-lane group x 4 dc regs -> shfl_xor{1,2,4,8} reduce.
__global__ __launch_bounds__(256, 2) void mlstm_mfma_kernel(
        const ushort* __restrict__ qb, const ushort* __restrict__ kb,
        const ushort* __restrict__ vt, const float* __restrict__ Lg,
        const float* __restrict__ Eg, const float* __restrict__ PMg,
        const ushort* __restrict__ xzb, const ushort* __restrict__ xcab,
        const float* __restrict__ onw, const float* __restrict__ skip,
        ushort* __restrict__ outb) {
    int bh = blockIdx.x;
    int b = bh >> 2, h = bh & 3;
    int tid = threadIdx.x;
    int wv = tid >> 6, l = tid & 63;
    int lr = l & 15, lg = l >> 4, g4 = lg * 4;

    __shared__ ushort Kb[16384];     // 32 KB
    __shared__ ushort Vt[16384];     // 32 KB
    __shared__ ushort Pl[4 * 640];   // per-wave 16x40 bf16
    __shared__ float sE[SS], sPM[SS], sL[SS];

    const size_t gb16 = (size_t)bh * 16384;
    #pragma unroll
    for (int p2 = 0; p2 < 8; ++p2) {
        int id = p2 * 256 + tid;
        int r = id >> 3, c = id & 7;
        uint4 kval = *(const uint4*)(kb + gb16 + r * 64 + c * 8);
        *(uint4*)(Kb + r * 64 + ((c ^ (r & 7)) * 8)) = kval;
        int d = id >> 5, c2 = id & 31;
        uint4 vval = *(const uint4*)(vt + gb16 + d * 256 + c2 * 8);
        *(uint4*)(Vt + d * 256 + ((c2 ^ (d & 7)) * 8)) = vval;
    }
    sE[tid]  = Eg[(size_t)bh * SS + tid];
    sPM[tid] = PMg[(size_t)bh * SS + tid];
    sL[tid]  = Lg[(size_t)bh * SS + tid];
    __syncthreads();

    // per-lane channel constants for fused mpost
    float onwv[4], skipv[4];
    #pragma unroll
    for (int dc = 0; dc < 4; ++dc) {
        int ch = h * 64 + dc * 16 + lr;
        onwv[dc] = onw[ch];
        skipv[dc] = skip[ch];
    }

    f32x4 O[4][4] = {};
    float csum[4][4] = {};
    const int pmap[4] = {wv, 7 - wv, 8 + wv, 15 - wv};
    ushort* Pw = Pl + wv * 640;

    #pragma unroll
    for (int rf = 0; rf < 4; ++rf) {
        int p = pmap[rf];
        int r0 = p * 16;
        short8 qf0 = *(const short8*)(qb + gb16 + (r0 + lr) * 64 + lg * 8);
        short8 qf1 = *(const short8*)(qb + gb16 + (r0 + lr) * 64 + 32 + lg * 8);
        float pmv[4], lv[4];
        #pragma unroll
        for (int r = 0; r < 4; ++r) { pmv[r] = sPM[r0 + g4 + r]; lv[r] = sL[r0 + g4 + r]; }
        int jtmax = r0 >> 5;
        #pragma unroll 1
        for (int jt = 0; jt <= jtmax; ++jt) {
            int jb = jt * 32;
            f32x4 s0 = {0.f, 0.f, 0.f, 0.f}, s1 = {0.f, 0.f, 0.f, 0.f};
            {
                int j = jb + lr;
                int sw = j & 7;
                short8 k00 = *(const short8*)(Kb + j * 64 + ((lg)     ^ sw) * 8);
                short8 k01 = *(const short8*)(Kb + j * 64 + ((4 + lg) ^ sw) * 8);
                int j2 = jb + 16 + lr;
                int sw2 = j2 & 7;
                short8 k10 = *(const short8*)(Kb + j2 * 64 + ((lg)     ^ sw2) * 8);
                short8 k11 = *(const short8*)(Kb + j2 * 64 + ((4 + lg) ^ sw2) * 8);
                s0 = __builtin_amdgcn_mfma_f32_16x16x32_bf16(qf0, k00, s0, 0, 0, 0);
                s0 = __builtin_amdgcn_mfma_f32_16x16x32_bf16(qf1, k01, s0, 0, 0, 0);
                s1 = __builtin_amdgcn_mfma_f32_16x16x32_bf16(qf0, k10, s1, 0, 0, 0);
                s1 = __builtin_amdgcn_mfma_f32_16x16x32_bf16(qf1, k11, s1, 0, 0, 0);
            }
            float e0 = sE[jb + lr], e1 = sE[jb + 16 + lr];
            int j0 = jb + lr, j1 = jb + 16 + lr;
            #pragma unroll
            for (int r = 0; r < 4; ++r) {
                int i = r0 + g4 + r;
                float sc0 = (j0 <= i) ? s0[r] * 0.125f * __expf(e0 - pmv[r]) : 0.f;
                float sc1 = (j1 <= i) ? s1[r] * 0.125f * __expf(e1 - pmv[r]) : 0.f;
                csum[rf][r] += sc0 + sc1;
                Pw[(g4 + r) * 40 + lr] = bf16u(sc0);
                Pw[(g4 + r) * 40 + 16 + lr] = bf16u(sc1);
            }
            WAVE_SYNC();
            short8 pf = *(const short8*)(Pw + lr * 40 + lg * 8);
            #pragma unroll
            for (int dc = 0; dc < 4; ++dc) {
                int d = dc * 16 + lr;
                int chunk = (jt * 4 + lg) ^ (d & 7);
                short8 vf = *(const short8*)(Vt + d * 256 + chunk * 8);
                O[rf][dc] = __builtin_amdgcn_mfma_f32_16x16x32_bf16(pf, vf, O[rf][dc], 0, 0, 0);
            }
        }
        // epilogue: normalize + fused group-LN(64) + skip + silu(z) -> bf16
        #pragma unroll
        for (int r = 0; r < 4; ++r) {
            float cs = csum[rf][r];
            cs += __shfl_xor(cs, 1); cs += __shfl_xor(cs, 2);
            cs += __shfl_xor(cs, 4); cs += __shfl_xor(cs, 8);
            float nrm = fmaxf(fabsf(cs), __expf(-(lv[r] + pmv[r]))) + 1e-6f;
            float rinv = 1.f / nrm;
            float v0 = O[rf][0][r] * rinv, v1 = O[rf][1][r] * rinv;
            float v2 = O[rf][2][r] * rinv, v3 = O[rf][3][r] * rinv;
            float s1m = v0 + v1 + v2 + v3;
            float s2m = v0 * v0 + v1 * v1 + v2 * v2 + v3 * v3;
            s1m += __shfl_xor(s1m, 1); s2m += __shfl_xor(s2m, 1);
            s1m += __shfl_xor(s1m, 2); s2m += __shfl_xor(s2m, 2);
            s1m += __shfl_xor(s1m, 4); s2m += __shfl_xor(s2m, 4);
            s1m += __shfl_xor(s1m, 8); s2m += __shfl_xor(s2m, 8);
            float mu = s1m * (1.f / 64.f);
            float var = s2m * (1.f / 64.f) - mu * mu;
            float inv = rsqrtf(var + 1e-5f);
            int grow = b * 256 + r0 + g4 + r;
            float vv[4] = {v0, v1, v2, v3};
            #pragma unroll
            for (int dc = 0; dc < 4; ++dc) {
                int ch = h * 64 + dc * 16 + lr;
                float z = ubf(xzb[(size_t)grow * 512 + 256 + ch]);
                float xnv = (vv[dc] - mu) * inv * onwv[dc];
                float val = (xnv + skipv[dc] * ubf(xcab[(size_t)grow * 256 + ch])) * siluf_(z);
                outb[(size_t)grow * 256 + ch] = bf16u(val);
            }
        }
    }
}

// ---------------- sLSTM sequential scan: deferred-LN software pipeline ----------------
// LN+store of step s runs inside step s+1's body (between matvec and gates) — it is independent
// of the recurrence chain, so its instructions fill the matvec/trans dependency-stall slots.
// First iteration runs a dummy LN(0) that writes 0 to row 0; the real store overwrites it next substep.
__global__ __launch_bounds__(64, 1) void slstm_scan_kernel(const ushort* __restrict__ gifb,
        const ushort* __restrict__ gzob, const float* __restrict__ rec_w,
        const float* __restrict__ bias, const float* __restrict__ gnw,
        float* __restrict__ hbuf) {
    int bh = blockIdx.x;
    int b = bh >> 2, h = bh & 3;
    int l = threadIdx.x;
    int c = l & 31;
    bool lo = (l < 32);
    unsigned wpk[32];   // bf16(col 64+l) << 16 | bf16(col l)
    const float* wp = rec_w + (size_t)h * 4096 + l;
    #pragma unroll
    for (int d = 0; d < 32; ++d) {
        float w0v = wp[d * 128];
        float w1v = wp[d * 128 + 64];
        wpk[d] = ((unsigned)bf16u(w1v) << 16) | (unsigned)bf16u(w0v);
    }
    float b0 = bias[h * 128 + l];
    float b1 = bias[h * 128 + 64 + l];
    float gw = gnw[h * 32 + c];
    float cst = 0.f, nst = 0.f, hreg = 0.f;
    size_t gb = (size_t)b * SS * 256 + h * 64 + l;
    size_t hb = (size_t)b * SS * 128 + h * 32 + c;
    float pg0[4], pg1[4], ph[4];
    #pragma unroll
    for (int u = 0; u < 4; ++u) {
        pg0[u] = ubf(gifb[gb + (size_t)u * 256]);
        pg1[u] = ubf(gzob[gb + (size_t)u * 256]);
        ph[u]  = hbuf[hb + (size_t)u * 128];
    }
    float pend_hv = 0.f, pend_hcur = 0.f;
    int pend_off = 0;
    for (int s = 0; s < SS; s += 4) {
        #pragma unroll
        for (int u = 0; u < 4; ++u) {
            // recurrent matvec (depends on hreg)
            float a00 = 0.f, a01 = 0.f, a02 = 0.f, a03 = 0.f;
            float a10 = 0.f, a11 = 0.f, a12 = 0.f, a13 = 0.f;
            #pragma unroll
            for (int d = 0; d < 32; d += 4) {
                float h0 = rdlane(hreg, d);
                float h1 = rdlane(hreg, d + 1);
                float h2 = rdlane(hreg, d + 2);
                float h3 = rdlane(hreg, d + 3);
                unsigned p0 = wpk[d], p1 = wpk[d + 1], p2 = wpk[d + 2], p3 = wpk[d + 3];
                a00 += __uint_as_float(p0 << 16) * h0;
                a10 += __uint_as_float(p0) * h0;
                a01 += __uint_as_float(p1 << 16) * h1;
                a11 += __uint_as_float(p1) * h1;
                a02 += __uint_as_float(p2 << 16) * h2;
                a12 += __uint_as_float(p2) * h2;
                a03 += __uint_as_float(p3 << 16) * h3;
                a13 += __uint_as_float(p3) * h3;
            }
            float raw0 = pg0[u] + ((a00 + a01) + (a02 + a03)) + b0;
            float raw1 = pg1[u] + ((a10 + a11) + (a12 + a13)) + b1;
            float hcur = ph[u];
            // deferred group-LN + residual store of the PREVIOUS step (independent work)
            {
                float s1 = pend_hv, s2 = pend_hv * pend_hv;
                s1 = DPPADD(s1, 0x111); s2 = DPPADD(s2, 0x111);
                s1 = DPPADD(s1, 0x112); s2 = DPPADD(s2, 0x112);
                s1 = DPPADD(s1, 0x114); s2 = DPPADD(s2, 0x114);
                s1 = DPPADD(s1, 0x118); s2 = DPPADD(s2, 0x118);
                s1 = DPPADD(s1, 0x142); s2 = DPPADD(s2, 0x142);
                s1 = DPPADD(s1, 0x143); s2 = DPPADD(s2, 0x143);
                float mu = rdlane(s1, 63) * (1.f / 64.f);
                float var = rdlane(s2, 63) * (1.f / 64.f) - mu * mu;
                float outv = (pend_hv - mu) * rsqrtf(var + 1e-5f) * gw;
                if (lo) hbuf[hb + (size_t)pend_off * 128] = pend_hcur + outv;
            }
            // prefetch next gates + h row
            int s4 = s + 4 + u;
            if (s4 < SS) {
                pg0[u] = ubf(gifb[gb + (size_t)s4 * 256]);
                pg1[u] = ubf(gzob[gb + (size_t)s4 * 256]);
                ph[u]  = hbuf[hb + (size_t)s4 * 128];
            }
            // gates
            i32x2 r0p = __builtin_amdgcn_permlane32_swap(__float_as_int(raw0), __float_as_int(raw0), false, false);
            i32x2 r1p = __builtin_amdgcn_permlane32_swap(__float_as_int(raw1), __float_as_int(raw1), false, false);
            float q0 = __int_as_float(lo ? r0p.y : r0p.x);
            float q1 = __int_as_float(lo ? r1p.y : r1p.x);
            float iraw = lo ? raw0 : q0;
            float zraw = lo ? raw1 : q1;
            float fraw = lo ? q0 : raw0;
            float oraw = lo ? q1 : raw1;
            float fg = __builtin_amdgcn_rcpf(1.f + __expf(-fraw));
            float ig = __expf(iraw);
            float e2z = __expf(2.f * zraw);
            float tz = 1.f - 2.f * __builtin_amdgcn_rcpf(e2z + 1.f);
            cst = fg * cst + ig * tz;
            nst = fg * nst + ig;
            float sg = __builtin_amdgcn_rcpf(1.f + __expf(-oraw));
            float hv = sg * cst * __builtin_amdgcn_rcpf(nst);
            hreg = hv;
            pend_hv = hv;
            pend_hcur = hcur;
            pend_off = s + u;
        }
    }
    // epilogue: final pending LN + store (step 255)
    {
        float s1 = pend_hv, s2 = pend_hv * pend_hv;
        s1 = DPPADD(s1, 0x111); s2 = DPPADD(s2, 0x111);
        s1 = DPPADD(s1, 0x112); s2 = DPPADD(s2, 0x112);
        s1 = DPPADD(s1, 0x114); s2 = DPPADD(s2, 0x114);
        s1 = DPPADD(s1, 0x118); s2 = DPPADD(s2, 0x118);
        s1 = DPPADD(s1, 0x142); s2 = DPPADD(s2, 0x142);
        s1 = DPPADD(s1, 0x143); s2 = DPPADD(s2, 0x143);
        float mu = rdlane(s1, 63) * (1.f / 64.f);
        float var = rdlane(s2, 63) * (1.f / 64.f) - mu * mu;
        float outv = (pend_hv - mu) * rsqrtf(var + 1e-5f) * gw;
        if (lo) hbuf[hb + (size_t)pend_off * 128] = pend_hcur + outv;
    }
}

extern "C" void kernel_launch(void* const* d_in, const int* in_sizes, int n_in,
                              void* d_out, int out_size, void* d_ws, size_t ws_size,
                              hipStream_t stream) {
    const int*   x        = (const int*)d_in[0];
    const float* emb      = (const float*)d_in[1];
    const float* m_ln_w   = (const float*)d_in[2];
    const float* m_up_w   = (const float*)d_in[3];
    const float* m_conv_w = (const float*)d_in[4];
    const float* m_conv_b = (const float*)d_in[5];
    const float* m_q_w    = (const float*)d_in[6];
    const float* m_k_w    = (const float*)d_in[7];
    const float* m_v_w    = (const float*)d_in[8];
    const float* m_ig_w   = (const float*)d_in[9];
    const float* m_ig_b   = (const float*)d_in[10];
    const float* m_fg_w   = (const float*)d_in[11];
    const float* m_fg_b   = (const float*)d_in[12];
    const float* m_on_w   = (const float*)d_in[13];
    const float* m_skip   = (const float*)d_in[14];
    const float* m_down_w = (const float*)d_in[15];
    const float* s_ln1_w  = (const float*)d_in[16];
    const float* s_conv_w = (const float*)d_in[17];
    const float* s_conv_b = (const float*)d_in[18];
    const float* s_ig_w   = (const float*)d_in[19];
    const float* s_fg_w   = (const float*)d_in[20];
    const float* s_zg_w   = (const float*)d_in[21];
    const float* s_og_w   = (const float*)d_in[22];
    const float* s_rec_w  = (const float*)d_in[23];
    const float* s_bias   = (const float*)d_in[24];
    const float* s_gn_w   = (const float*)d_in[25];
    const float* s_ln2_w  = (const float*)d_in[26];
    const float* s_ff_up_w   = (const float*)d_in[27];
    const float* s_ff_down_w = (const float*)d_in[28];
    const float* post_norm_w = (const float*)d_in[29];
    float* out = (float*)d_out;

    float* ws = (float*)d_ws;
    const size_t NR = NROWS;
    // fp32 regions
    float* h   = ws;                   // NR*128
    float* regA = h   + NR * 128;      // NR*128 f: vtb (mLSTM) / gifb (sLSTM) as NR*256 ushort
    float* regB = regA + NR * 128;     // NR*128 f: mpostb (mLSTM) / gzob (sLSTM)
    float* gip = regB + NR * 128;      // 512*256
    float* gfp = gip + 512 * 256;
    float* gL  = gfp + 512 * 256;
    float* gE  = gL  + 512 * 256;
    float* gPM = gE  + 512 * 256;
    float* extra = gPM + 512 * 256;
    // bf16 regions
    ushort* xnb   = (ushort*)extra;                    // NR*128 bf16
    ushort* xzb   = xnb + NR * 128;                    // NR*512 bf16
    ushort* xcab  = xzb + NR * 512;                    // NR*256 bf16
    ushort* qb16  = xcab + NR * 256;                   // NR*256 bf16 (xcb aliases in sLSTM)
    ushort* vb16  = qb16 + NR * 256;                   // NR*256 bf16
    ushort* upb   = vb16 + NR * 256;                   // 512*128
    ushort* downb = upb + 512 * 128;                   // 128*256
    ushort* ffupb = downb + 128 * 256;                 // 2*512*128
    ushort* ffdownb = ffupb + 2 * 512 * 128;           // 2*128*256
    ushort* sgwb  = ffdownb + 2 * 128 * 256;           // 2*2*256*128
    ushort* w16b  = sgwb + 2 * 2 * 256 * 128;          // 16*768
    // aliases (regions dead at time of use)
    ushort* kb16   = (ushort*)out;    // NR*256 bf16 (d_out; final LN overwrites)
    ushort* vtb    = (ushort*)regA;   // NR*256 bf16 (mLSTM phase)
    ushort* gifb   = (ushort*)regA;   // NR*256 bf16 (sLSTM phase)
    ushort* mpostb = (ushort*)regB;   // NR*256 bf16 (mLSTM phase)
    ushort* gzob   = (ushort*)regB;   // NR*256 bf16 (sLSTM phase)
    ushort* xcb    = qb16;            // NR*128 bf16 (qb16 dead after mlstm)

    // ---- all weight conversions in ONE launch ----
    wprep_kernel<<<(569344 + 255) / 256, 256, 0, stream>>>(m_up_w, m_down_w, s_ff_up_w,
            s_ff_down_w, s_ig_w, s_fg_w, s_zg_w, s_og_w, m_ig_w, m_fg_w,
            upb, downb, ffupb, ffdownb, sgwb, w16b);

    // ---- fused embedding + pre-LN ----
    embed_ln_kernel<<<NR / 4, 256, 0, stream>>>(x, emb, m_ln_w, h, xnb);
    // ---- mLSTM up-projection -> bf16 xzb ----
    gemm_bf16_kernel<<<dim3(NR / 128, 4), 256, 0, stream>>>(xnb, 128, upb, nullptr, xzb, 512, 128, 0);
    // ---- fused conv+silu + block-diag q,k,v ----
    mqkv_kernel<<<(NR * 256) / 256, 256, 0, stream>>>(xzb, m_conv_w, m_conv_b,
            m_q_w, m_k_w, m_v_w, xcab, qb16, kb16, vb16, NR * 256);
    // ---- i/f gate projections via skinny MFMA GEMM ----
    gategemm_kernel<<<NR / 128, 256, 0, stream>>>(qb16, kb16, vb16, w16b, m_ig_b, m_fg_b, gip, gfp);
    // ---- decay prefix scan (wave-parallel) ----
    mprep_kernel<<<BB * NH, 64, 0, stream>>>(gip, gfp, gL, gE, gPM);
    // ---- V transpose ----
    vtrans_kernel<<<BB * NH * 4, 256, 0, stream>>>(vb16, vtb);
    // ---- mLSTM core via MFMA + fused mpost -> bf16 mpostb ----
    mlstm_mfma_kernel<<<BB * NH, 256, 0, stream>>>(qb16, kb16, vtb, gL, gE, gPM,
            xzb, xcab, m_on_w, m_skip, mpostb);
    // ---- down-projection + residual (fp32 accumulate into h) ----
    gemm_bf16_kernel<<<dim3(NR / 128, 1), 256, 0, stream>>>(mpostb, 256, downb, h, nullptr, 128, 256, 1);

    // ---- two sLSTM blocks ----
    for (int i2 = 0; i2 < 2; ++i2) {
        ln128_kernel<<<NR / 4, 256, 0, stream>>>(h, s_ln1_w + i2 * 128, nullptr, xnb);
        conv_silu_s_kernel<<<(NR * 128) / 256, 256, 0, stream>>>(xnb, s_conv_w + i2 * 128 * 4,
                s_conv_b + i2 * 128, xcb, NR * 128);
        // both gate GEMMs in one launch
        sgate_gemm_kernel<<<dim3(NR / 128, 4), 256, 0, stream>>>(xcb, xnb,
                sgwb + (size_t)(i2 * 2 + 0) * 256 * 128, sgwb + (size_t)(i2 * 2 + 1) * 256 * 128,
                gifb, gzob);
        // scan with pipelined group-LN + residual into h
        slstm_scan_kernel<<<BB * NH, 64, 0, stream>>>(gifb, gzob,
                s_rec_w + i2 * 4 * 32 * 128, s_bias + i2 * 4 * 128, s_gn_w + i2 * 128, h);
        ln128_kernel<<<NR / 4, 256, 0, stream>>>(h, s_ln2_w + i2 * 128, nullptr, xnb);
        gemm_bf16_kernel<<<dim3(NR / 128, 4), 256, 0, stream>>>(xnb, 128, ffupb + (size_t)i2 * 512 * 128, nullptr, xzb, 512, 128, 0);
        // fused GLU + down-projection (+ residual into h)
        gemm_glu_kernel<<<NR / 128, 256, 0, stream>>>(xzb, ffdownb + (size_t)i2 * 128 * 256, h);
    }
    // ---- final LN -> out (fp32 only) ----
    ln128_kernel<<<NR / 4, 256, 0, stream>>>(h, post_norm_w, out, nullptr);
}

// Round 14
// 682.894 us; speedup vs baseline: 1.5586x; 1.0041x over previous
//
#include <hip/hip_runtime.h>
#include <hip/hip_bf16.h>

// Model dims (compile-time)
#define BB 128
#define SS 256
#define DD 128
#define DI 256      // 2*D
#define NH 4
#define DHM 64      // DI/NH
#define DHS 32      // D/NH
#define NROWS (BB*SS)   // 32768

#define WAVE_SYNC() do { asm volatile("s_waitcnt lgkmcnt(0)" ::: "memory"); __builtin_amdgcn_wave_barrier(); } while (0)

typedef __attribute__((ext_vector_type(8))) short short8;
typedef __attribute__((ext_vector_type(4))) float f32x4;
typedef __attribute__((ext_vector_type(2))) int i32x2;

__device__ __forceinline__ float sigmoidf_(float x) { return 1.f / (1.f + __expf(-x)); }
__device__ __forceinline__ float siluf_(float x) { return x / (1.f + __expf(-x)); }
// stable log_sigmoid
__device__ __forceinline__ float logsigf_(float x) {
    return (x >= 0.f) ? -log1pf(__expf(-x)) : x - log1pf(__expf(x));
}
__device__ __forceinline__ float geluf_(float g) {
    return 0.5f * g * (1.f + erff(g * 0.70710678118654752f));
}
// fp32 -> bf16 bits, round-to-nearest-even (inputs are finite)
__device__ __forceinline__ ushort bf16u(float x) {
    unsigned u = __float_as_uint(x);
    u += 0x7fffu + ((u >> 16) & 1u);
    return (ushort)(u >> 16);
}
__device__ __forceinline__ float ubf(ushort v) {
    return __uint_as_float((unsigned)v << 16);
}
__device__ __forceinline__ float rdlane(float v, int lane) {
    return __int_as_float(__builtin_amdgcn_readlane(__float_as_int(v), lane));
}
// DPP add: x + dpp(x) with given ctrl (VALU-speed cross-lane; bound_ctrl=1 -> 0 fill)
#define DPPADD(x, ctrl) ((x) + __int_as_float(__builtin_amdgcn_update_dpp(0, __float_as_int(x), (ctrl), 0xf, 0xf, true)))

// ---------------- fused weight prep: all bf16 conversions + densify in ONE launch ----------------
__global__ __launch_bounds__(256) void wprep_kernel(const float* __restrict__ m_up_w,
        const float* __restrict__ m_down_w, const float* __restrict__ s_ff_up_w,
        const float* __restrict__ s_ff_down_w, const float* __restrict__ wi,
        const float* __restrict__ wf, const float* __restrict__ wz,
        const float* __restrict__ wo, const float* __restrict__ igw,
        const float* __restrict__ fgw,
        ushort* __restrict__ upb, ushort* __restrict__ downb,
        ushort* __restrict__ ffupb, ushort* __restrict__ ffdownb,
        ushort* __restrict__ sgwb, ushort* __restrict__ w16b) {
    int gid = blockIdx.x * 256 + threadIdx.x;
    if (gid < 65536) {
        upb[gid] = bf16u(m_up_w[gid]);
    } else if (gid < 98304) {
        int i = gid - 65536;
        downb[i] = bf16u(m_down_w[i]);
    } else if (gid < 229376) {
        int i = gid - 98304;
        ffupb[i] = bf16u(s_ff_up_w[i]);
    } else if (gid < 294912) {
        int i = gid - 229376;
        ffdownb[i] = bf16u(s_ff_down_w[i]);
    } else if (gid < 557056) {
        int idx = gid - 294912;
        int t = idx & 127;
        int oc = (idx >> 7) & 255;
        int pair = (idx >> 15) & 1;
        int i2 = idx >> 16;
        int h = oc >> 6, l = oc & 63, gate = (l >> 5) & 1, e = l & 31;
        const float* w = pair == 0 ? (gate == 0 ? wi : wf) : (gate == 0 ? wz : wo);
        float val = ((t >> 5) == h) ? w[i2 * 4096 + h * 1024 + e * 32 + (t & 31)] : 0.f;
        sgwb[idx] = bf16u(val);
    } else if (gid < 569344) {
        int idx = gid - 557056;
        int t = idx % 768, j = idx / 768;
        float v = 0.f;
        if (j < 4) v = igw[j * 768 + t];
        else if (j < 8) v = fgw[(j - 4) * 768 + t];
        w16b[idx] = bf16u(v);
    }
}

// ---------------- fused embedding + pre-LN: 4 rows per block; h fp32 + xnb bf16 ----------------
__global__ __launch_bounds__(256) void embed_ln_kernel(const int* __restrict__ x,
        const float* __restrict__ emb, const float* __restrict__ w,
        float* __restrict__ h, ushort* __restrict__ outb) {
    int row = blockIdx.x * 4 + (threadIdx.x >> 6);
    int lane = threadIdx.x & 63;
    int tok = x[row];
    float a = emb[tok * DD + lane], b = emb[tok * DD + 64 + lane];
    h[(size_t)row * DD + lane] = a;
    h[(size_t)row * DD + 64 + lane] = b;
    float s1 = a + b, s2 = a * a + b * b;
    #pragma unroll
    for (int o = 32; o; o >>= 1) { s1 += __shfl_xor(s1, o); s2 += __shfl_xor(s2, o); }
    float mu = s1 * (1.f / 128.f);
    float var = s2 * (1.f / 128.f) - mu * mu;
    float inv = rsqrtf(var + 1e-5f);
    ushort* brow = outb + (size_t)row * DD;
    brow[lane] = bf16u((a - mu) * inv * w[lane]);
    brow[lane + 64] = bf16u((b - mu) * inv * w[lane + 64]);
}

// ---------------- LayerNorm over D=128; 4 rows per 256-thread block; bf16 and/or fp32 out ----------------
__global__ __launch_bounds__(256) void ln128_kernel(const float* __restrict__ x,
        const float* __restrict__ w, float* __restrict__ out, ushort* __restrict__ outb) {
    int row = blockIdx.x * 4 + (threadIdx.x >> 6);
    int lane = threadIdx.x & 63;
    const float* xr = x + (size_t)row * DD;
    float a = xr[lane], b = xr[lane + 64];
    float s1 = a + b, s2 = a * a + b * b;
    #pragma unroll
    for (int o = 32; o; o >>= 1) { s1 += __shfl_xor(s1, o); s2 += __shfl_xor(s2, o); }
    float mu = s1 * (1.f / 128.f);
    float var = s2 * (1.f / 128.f) - mu * mu;
    float inv = rsqrtf(var + 1e-5f);
    float va = (a - mu) * inv * w[lane];
    float vb = (b - mu) * inv * w[lane + 64];
    if (out) {
        float* orow = out + (size_t)row * DD;
        orow[lane] = va; orow[lane + 64] = vb;
    }
    if (outb) {
        ushort* brow = outb + (size_t)row * DD;
        brow[lane] = bf16u(va); brow[lane + 64] = bf16u(vb);
    }
}

// ---------------- fused sLSTM pre-LN + causal conv + silu ----------------
// Block = (b, 64-row tile). LN of rows [r0-3, r0+64) into LDS (bf16), conv reads LDS.
// Writes xnb (LN out, bf16) and xcb (conv+silu out, bf16) for its 64 rows.
__global__ __launch_bounds__(256) void ln_conv_s_kernel(const float* __restrict__ hsrc,
        const float* __restrict__ lnw, const float* __restrict__ cw,
        const float* __restrict__ cb, ushort* __restrict__ xnb, ushort* __restrict__ xcb) {
    __shared__ ushort lnbuf[67][128];
    int blk = blockIdx.x;
    int st = blk & 3, b = blk >> 2;
    int r0 = st * 64;
    int tid = threadIdx.x;
    int wv = tid >> 6, lane = tid & 63;
    #pragma unroll
    for (int p = 0; p < 17; ++p) {
        int rl = p * 4 + wv;            // 0..67
        if (rl < 67) {
            int s = r0 - 3 + rl;
            if (s >= 0) {
                const float* xr = hsrc + ((size_t)(b * 256 + s)) * 128;
                float a = xr[lane], c2 = xr[lane + 64];
                float s1 = a + c2, s2 = a * a + c2 * c2;
                #pragma unroll
                for (int o = 32; o; o >>= 1) { s1 += __shfl_xor(s1, o); s2 += __shfl_xor(s2, o); }
                float mu = s1 * (1.f / 128.f);
                float var = s2 * (1.f / 128.f) - mu * mu;
                float inv = rsqrtf(var + 1e-5f);
                lnbuf[rl][lane] = bf16u((a - mu) * inv * lnw[lane]);
                lnbuf[rl][lane + 64] = bf16u((c2 - mu) * inv * lnw[lane + 64]);
            } else {
                lnbuf[rl][lane] = 0;
                lnbuf[rl][lane + 64] = 0;
            }
        }
    }
    __syncthreads();
    int ch = tid & 127;
    int half = tid >> 7;        // 0/1
    float w0 = cw[ch * 4 + 0], w1 = cw[ch * 4 + 1], w2 = cw[ch * 4 + 2], w3 = cw[ch * 4 + 3];
    float bias = cb[ch];
    #pragma unroll 4
    for (int i = 0; i < 32; ++i) {
        int rr = half * 32 + i;         // 0..63
        int rl = 3 + rr;
        float acc = bias
            + ubf(lnbuf[rl - 3][ch]) * w0
            + ubf(lnbuf[rl - 2][ch]) * w1
            + ubf(lnbuf[rl - 1][ch]) * w2
            + ubf(lnbuf[rl][ch]) * w3;
        size_t gr = (size_t)(b * 256 + r0 + rr);
        xcb[gr * 128 + ch] = bf16u(siluf_(acc));
        xnb[gr * 128 + ch] = lnbuf[rl][ch];
    }
}

// ---------------- bf16 MFMA GEMM: C[M,N] (+)= A[M,K](lda) @ W[N,K]^T ----------------
__global__ __launch_bounds__(256, 2) void gemm_bf16_kernel(const ushort* __restrict__ A, int lda,
        const ushort* __restrict__ W, float* __restrict__ C, ushort* __restrict__ Cb,
        int ldc, int K, int addC) {
    __shared__ ushort As[128 * 32];
    __shared__ ushort Bs[128 * 32];
    int m0 = blockIdx.x * 128;
    int n0 = blockIdx.y * 128;
    int tid = threadIdx.x;
    int wv = tid >> 6, l = tid & 63;
    int lr = l & 15, lg = l >> 4, g4 = lg * 4;
    int wr = wv >> 1, wc = wv & 1;
    int sr = tid >> 1;
    int sc = (tid & 1) * 2;

    f32x4 acc[4][4] = {};
    for (int k0 = 0; k0 < K; k0 += 32) {
        __syncthreads();
        #pragma unroll
        for (int u = 0; u < 2; ++u) {
            int c = sc + u;
            uint4 av = *(const uint4*)(A + (size_t)(m0 + sr) * lda + k0 + c * 8);
            *(uint4*)(As + sr * 32 + ((c ^ (sr & 3)) * 8)) = av;
            uint4 wv4 = *(const uint4*)(W + (size_t)(n0 + sr) * K + k0 + c * 8);
            *(uint4*)(Bs + sr * 32 + ((c ^ (sr & 3)) * 8)) = wv4;
        }
        __syncthreads();
        short8 af[4], bf[4];
        #pragma unroll
        for (int fm = 0; fm < 4; ++fm) {
            int row = wr * 64 + fm * 16 + lr;
            af[fm] = *(const short8*)(As + row * 32 + ((lg ^ (row & 3)) * 8));
        }
        #pragma unroll
        for (int fn = 0; fn < 4; ++fn) {
            int row = wc * 64 + fn * 16 + lr;
            bf[fn] = *(const short8*)(Bs + row * 32 + ((lg ^ (row & 3)) * 8));
        }
        #pragma unroll
        for (int fm = 0; fm < 4; ++fm)
            #pragma unroll
            for (int fn = 0; fn < 4; ++fn)
                acc[fm][fn] = __builtin_amdgcn_mfma_f32_16x16x32_bf16(af[fm], bf[fn], acc[fm][fn], 0, 0, 0);
    }
    #pragma unroll
    for (int fm = 0; fm < 4; ++fm) {
        #pragma unroll
        for (int fn = 0; fn < 4; ++fn) {
            #pragma unroll
            for (int r = 0; r < 4; ++r) {
                size_t idx = (size_t)(m0 + wr * 64 + fm * 16 + g4 + r) * ldc + n0 + wc * 64 + fn * 16 + lr;
                if (Cb) Cb[idx] = bf16u(acc[fm][fn][r]);
                else if (addC) C[idx] += acc[fm][fn][r];
                else C[idx] = acc[fm][fn][r];
            }
        }
    }
}

// ---------------- merged sLSTM gate GEMMs: grid.y in [0,4) ----------------
__global__ __launch_bounds__(256, 2) void sgate_gemm_kernel(const ushort* __restrict__ xcb,
        const ushort* __restrict__ xnb, const ushort* __restrict__ Wif,
        const ushort* __restrict__ Wzo, ushort* __restrict__ gifb, ushort* __restrict__ gzob) {
    __shared__ ushort As[128 * 32];
    __shared__ ushort Bs[128 * 32];
    int y = blockIdx.y;
    const ushort* A = (y < 2) ? xcb : xnb;
    const ushort* W = (y < 2) ? Wif : Wzo;
    ushort* Cb = (y < 2) ? gifb : gzob;
    int m0 = blockIdx.x * 128;
    int n0 = (y & 1) * 128;
    int tid = threadIdx.x;
    int wv = tid >> 6, l = tid & 63;
    int lr = l & 15, lg = l >> 4, g4 = lg * 4;
    int wr = wv >> 1, wc = wv & 1;
    int sr = tid >> 1;
    int sc = (tid & 1) * 2;

    f32x4 acc[4][4] = {};
    for (int k0 = 0; k0 < 128; k0 += 32) {
        __syncthreads();
        #pragma unroll
        for (int u = 0; u < 2; ++u) {
            int c = sc + u;
            uint4 av = *(const uint4*)(A + (size_t)(m0 + sr) * 128 + k0 + c * 8);
            *(uint4*)(As + sr * 32 + ((c ^ (sr & 3)) * 8)) = av;
            uint4 wv4 = *(const uint4*)(W + (size_t)(n0 + sr) * 128 + k0 + c * 8);
            *(uint4*)(Bs + sr * 32 + ((c ^ (sr & 3)) * 8)) = wv4;
        }
        __syncthreads();
        short8 af[4], bf[4];
        #pragma unroll
        for (int fm = 0; fm < 4; ++fm) {
            int row = wr * 64 + fm * 16 + lr;
            af[fm] = *(const short8*)(As + row * 32 + ((lg ^ (row & 3)) * 8));
        }
        #pragma unroll
        for (int fn = 0; fn < 4; ++fn) {
            int row = wc * 64 + fn * 16 + lr;
            bf[fn] = *(const short8*)(Bs + row * 32 + ((lg ^ (row & 3)) * 8));
        }
        #pragma unroll
        for (int fm = 0; fm < 4; ++fm)
            #pragma unroll
            for (int fn = 0; fn < 4; ++fn)
                acc[fm][fn] = __builtin_amdgcn_mfma_f32_16x16x32_bf16(af[fm], bf[fn], acc[fm][fn], 0, 0, 0);
    }
    #pragma unroll
    for (int fm = 0; fm < 4; ++fm)
        #pragma unroll
        for (int fn = 0; fn < 4; ++fn)
            #pragma unroll
            for (int r = 0; r < 4; ++r) {
                size_t idx = (size_t)(m0 + wr * 64 + fm * 16 + g4 + r) * 256 + n0 + wc * 64 + fn * 16 + lr;
                Cb[idx] = bf16u(acc[fm][fn][r]);
            }
}

// ---------------- fused GLU + down GEMM: C[M,128] += glu(xzb) @ W[128,256]^T ----------------
__global__ __launch_bounds__(256, 2) void gemm_glu_kernel(const ushort* __restrict__ xzb,
        const ushort* __restrict__ W, float* __restrict__ C) {
    __shared__ ushort As[128 * 32];
    __shared__ ushort Bs[128 * 32];
    int m0 = blockIdx.x * 128;
    int tid = threadIdx.x;
    int wv = tid >> 6, l = tid & 63;
    int lr = l & 15, lg = l >> 4, g4 = lg * 4;
    int wr = wv >> 1, wc = wv & 1;
    int sr = tid >> 1;
    int sc = (tid & 1) * 2;

    f32x4 acc[4][4] = {};
    for (int k0 = 0; k0 < 256; k0 += 32) {
        __syncthreads();
        #pragma unroll
        for (int u = 0; u < 2; ++u) {
            int c = sc + u;
            short8 g8 = *(const short8*)(xzb + (size_t)(m0 + sr) * 512 + k0 + c * 8);
            short8 u8 = *(const short8*)(xzb + (size_t)(m0 + sr) * 512 + 256 + k0 + c * 8);
            short8 o8;
            #pragma unroll
            for (int t = 0; t < 8; ++t)
                o8[t] = (short)bf16u(geluf_(ubf((ushort)g8[t])) * ubf((ushort)u8[t]));
            *(short8*)(As + sr * 32 + ((c ^ (sr & 3)) * 8)) = o8;
            uint4 wv4 = *(const uint4*)(W + (size_t)sr * 256 + k0 + c * 8);
            *(uint4*)(Bs + sr * 32 + ((c ^ (sr & 3)) * 8)) = wv4;
        }
        __syncthreads();
        short8 af[4], bf[4];
        #pragma unroll
        for (int fm = 0; fm < 4; ++fm) {
            int row = wr * 64 + fm * 16 + lr;
            af[fm] = *(const short8*)(As + row * 32 + ((lg ^ (row & 3)) * 8));
        }
        #pragma unroll
        for (int fn = 0; fn < 4; ++fn) {
            int row = wc * 64 + fn * 16 + lr;
            bf[fn] = *(const short8*)(Bs + row * 32 + ((lg ^ (row & 3)) * 8));
        }
        #pragma unroll
        for (int fm = 0; fm < 4; ++fm)
            #pragma unroll
            for (int fn = 0; fn < 4; ++fn)
                acc[fm][fn] = __builtin_amdgcn_mfma_f32_16x16x32_bf16(af[fm], bf[fn], acc[fm][fn], 0, 0, 0);
    }
    #pragma unroll
    for (int fm = 0; fm < 4; ++fm)
        #pragma unroll
        for (int fn = 0; fn < 4; ++fn)
            #pragma unroll
            for (int r = 0; r < 4; ++r) {
                size_t idx = (size_t)(m0 + wr * 64 + fm * 16 + g4 + r) * 128 + wc * 64 + fn * 16 + lr;
                C[idx] += acc[fm][fn][r];
            }
}

// ---------------- skinny gate GEMM: [ip|fp] = [q|k|v] @ W16^T + bias ----------------
__global__ __launch_bounds__(256) void gategemm_kernel(const ushort* __restrict__ qb,
        const ushort* __restrict__ kb, const ushort* __restrict__ vb,
        const ushort* __restrict__ W16, const float* __restrict__ igb,
        const float* __restrict__ fgb, float* __restrict__ ip, float* __restrict__ fp) {
    int tid = threadIdx.x;
    int wv = tid >> 6, l = tid & 63;
    int lr = l & 15, lg = l >> 4, g4 = lg * 4;
    int row0 = blockIdx.x * 128 + wv * 32;
    f32x4 acc[2] = {};
    #pragma unroll
    for (int k0 = 0; k0 < 768; k0 += 32) {
        short8 bfr = *(const short8*)(W16 + lr * 768 + k0 + lg * 8);
        #pragma unroll
        for (int mi = 0; mi < 2; ++mi) {
            int row = row0 + mi * 16 + lr;
            int b = row >> 8, s = row & 255;
            const ushort* src;
            size_t addr;
            if (k0 < 256) {
                src = qb;
                addr = ((size_t)(b * 4 + (k0 >> 6)) * 256 + s) * 64 + (k0 & 63) + lg * 8;
            } else if (k0 < 512) {
                int kq = k0 - 256;
                src = kb;
                addr = ((size_t)(b * 4 + (kq >> 6)) * 256 + s) * 64 + (kq & 63) + lg * 8;
            } else {
                src = vb;
                addr = (size_t)row * 256 + (k0 - 512) + lg * 8;
            }
            short8 afr = *(const short8*)(src + addr);
            acc[mi] = __builtin_amdgcn_mfma_f32_16x16x32_bf16(afr, bfr, acc[mi], 0, 0, 0);
        }
    }
    if (lr < 8) {
        float bias = (lr < 4) ? igb[lr] : fgb[lr - 4];
        float* dst = (lr < 4) ? ip : fp;
        int hh = lr & 3;
        #pragma unroll
        for (int mi = 0; mi < 2; ++mi) {
            #pragma unroll
            for (int r = 0; r < 4; ++r) {
                int row = row0 + mi * 16 + g4 + r;
                int b = row >> 8, s = row & 255;
                dst[(size_t)(b * 4 + hh) * 256 + s] = acc[mi][r] + bias;
            }
        }
    }
}

// ---------------- fused mLSTM conv+silu + block-diag q,k,v: one 8-ch oct per thread ----------------
// Reads xzb x_in once (4 uint4 taps), short8 stores for xcab/vb16/qb16/kb16.
__global__ __launch_bounds__(256) void mqkv_kernel(const ushort* __restrict__ xzb,
        const float* __restrict__ cw, const float* __restrict__ cb,
        const float* __restrict__ qw, const float* __restrict__ kw,
        const float* __restrict__ vw, ushort* __restrict__ xcab,
        ushort* __restrict__ qb16, ushort* __restrict__ kb16,
        ushort* __restrict__ vb16) {
    int gid = blockIdx.x * 256 + threadIdx.x;   // NR*32
    int oct = gid & 31;
    int row = gid >> 5;
    int s = row & 255;
    int b = row >> 8;
    float xin[4][8];
    #pragma unroll
    for (int j = 0; j < 4; ++j) {
        int ss = s - 3 + j;
        if (ss >= 0) {
            short8 v8 = *(const short8*)(xzb + ((size_t)row + j - 3) * 512 + oct * 8);
            #pragma unroll
            for (int t = 0; t < 8; ++t) xin[j][t] = ubf((ushort)v8[t]);
        } else {
            #pragma unroll
            for (int t = 0; t < 8; ++t) xin[j][t] = 0.f;
        }
    }
    float xc8[8];
    #pragma unroll
    for (int t = 0; t < 8; ++t) {
        int ch = oct * 8 + t;
        float acc = cb[ch];
        #pragma unroll
        for (int j = 0; j < 4; ++j) acc += xin[j][t] * cw[ch * 4 + j];
        xc8[t] = siluf_(acc);
    }
    short8 qs, ks, vs, xs;
    #pragma unroll
    for (int e = 0; e < 8; ++e) {
        const float* qw8 = qw + (size_t)(oct * 8 + e) * 8;
        const float* kw8 = kw + (size_t)(oct * 8 + e) * 8;
        const float* vw8 = vw + (size_t)(oct * 8 + e) * 8;
        float aq = 0.f, ak = 0.f, av = 0.f;
        #pragma unroll
        for (int t = 0; t < 8; ++t) {
            aq += xc8[t] * qw8[t];
            ak += xc8[t] * kw8[t];
            av += xin[3][t] * vw8[t];
        }
        qs[e] = (short)bf16u(aq);
        ks[e] = (short)bf16u(ak);
        vs[e] = (short)bf16u(av);
        xs[e] = (short)bf16u(xc8[e]);
    }
    *(short8*)(xcab + (size_t)row * 256 + oct * 8) = xs;
    *(short8*)(vb16 + (size_t)row * 256 + oct * 8) = vs;
    int h2 = oct >> 3, dd = (oct & 7) * 8;
    size_t be = ((size_t)(b * 4 + h2) * 256 + s) * 64 + dd;
    *(short8*)(qb16 + be) = qs;
    *(short8*)(kb16 + be) = ks;
}

// ---------------- mLSTM decay prefix scan (wave-parallel) ----------------
__global__ __launch_bounds__(64) void mprep_kernel(const float* __restrict__ ip,
        const float* __restrict__ fp, float* __restrict__ L,
        float* __restrict__ E, float* __restrict__ PM) {
    int bh = blockIdx.x;
    int lane = threadIdx.x;
    size_t base = (size_t)bh * SS + lane * 4;
    float lsv[4], ipv[4];
    #pragma unroll
    for (int u = 0; u < 4; ++u) {
        lsv[u] = logsigf_(fp[base + u]);
        ipv[u] = ip[base + u];
    }
    float p0 = lsv[0], p1 = p0 + lsv[1], p2 = p1 + lsv[2], p3 = p2 + lsv[3];
    float inc = p3;
    #pragma unroll
    for (int o = 1; o < 64; o <<= 1) {
        float wv = __shfl_up(inc, o);
        if (lane >= o) inc += wv;
    }
    float excl = inc - p3;
    float Lv[4] = {excl + p0, excl + p1, excl + p2, excl + p3};
    float Ev[4];
    #pragma unroll
    for (int u = 0; u < 4; ++u) Ev[u] = ipv[u] - Lv[u];
    float q0 = Ev[0], q1 = fmaxf(q0, Ev[1]), q2 = fmaxf(q1, Ev[2]), q3 = fmaxf(q2, Ev[3]);
    float incm = q3;
    #pragma unroll
    for (int o = 1; o < 64; o <<= 1) {
        float wv = __shfl_up(incm, o);
        if (lane >= o) incm = fmaxf(incm, wv);
    }
    float exm = __shfl_up(incm, 1);
    if (lane == 0) exm = -INFINITY;
    float qv[4] = {q0, q1, q2, q3};
    #pragma unroll
    for (int u = 0; u < 4; ++u) {
        L[base + u] = Lv[u];
        E[base + u] = Ev[u];
        PM[base + u] = fmaxf(exm, qv[u]);
    }
}

// ---------------- V transpose: bf16 [row][256] -> [bh][64][256] bf16 ----------------
__global__ __launch_bounds__(256) void vtrans_kernel(const ushort* __restrict__ vb,
        ushort* __restrict__ vt) {
    int blk = blockIdx.x;
    int st = blk & 3, bh = blk >> 2;
    int b = bh >> 2, h = bh & 3;
    int tid = threadIdx.x;
    __shared__ ushort tile[64][68];
    int s0 = st * 64;
    #pragma unroll
    for (int u = 0; u < 16; ++u) {
        int idx = u * 256 + tid;
        int sl = idx >> 6, dl = idx & 63;
        tile[sl][dl] = vb[((size_t)(b * 256 + s0 + sl)) * 256 + h * 64 + dl];
    }
    __syncthreads();
    #pragma unroll
    for (int u = 0; u < 16; ++u) {
        int idx = u * 256 + tid;
        int dl = idx >> 6, sl = idx & 63;
        vt[((size_t)bh * 64 + dl) * 256 + s0 + sl] = tile[sl][dl];
    }
}

// ---------------- mLSTM parallel core via MFMA + fused mpost ----------------
__global__ __launch_bounds__(256, 2) void mlstm_mfma_kernel(
        const ushort* __restrict__ qb, const ushort* __restrict__ kb,
        const ushort* __restrict__ vt, const float* __restrict__ Lg,
        const float* __restrict__ Eg, const float* __restrict__ PMg,
        const ushort* __restrict__ xzb, const ushort* __restrict__ xcab,
        const float* __restrict__ onw, const float* __restrict__ skip,
        ushort* __restrict__ outb) {
    int bh = blockIdx.x;
    int b = bh >> 2, h = bh & 3;
    int tid = threadIdx.x;
    int wv = tid >> 6, l = tid & 63;
    int lr = l & 15, lg = l >> 4, g4 = lg * 4;

    __shared__ ushort Kb[16384];     // 32 KB
    __shared__ ushort Vt[16384];     // 32 KB
    __shared__ ushort Pl[4 * 640];   // per-wave 16x40 bf16
    __shared__ float sE[SS], sPM[SS], sL[SS];

    const size_t gb16 = (size_t)bh * 16384;
    #pragma unroll
    for (int p2 = 0; p2 < 8; ++p2) {
        int id = p2 * 256 + tid;
        int r = id >> 3, c = id & 7;
        uint4 kval = *(const uint4*)(kb + gb16 + r * 64 + c * 8);
        *(uint4*)(Kb + r * 64 + ((c ^ (r & 7)) * 8)) = kval;
        int d = id >> 5, c2 = id & 31;
        uint4 vval = *(const uint4*)(vt + gb16 + d * 256 + c2 * 8);
        *(uint4*)(Vt + d * 256 + ((c2 ^ (d & 7)) * 8)) = vval;
    }
    sE[tid]  = Eg[(size_t)bh * SS + tid];
    sPM[tid] = PMg[(size_t)bh * SS + tid];
    sL[tid]  = Lg[(size_t)bh * SS + tid];
    __syncthreads();

    float onwv[4], skipv[4];
    #pragma unroll
    for (int dc = 0; dc < 4; ++dc) {
        int ch = h * 64 + dc * 16 + lr;
        onwv[dc] = onw[ch];
        skipv[dc] = skip[ch];
    }

    f32x4 O[4][4] = {};
    float csum[4][4] = {};
    const int pmap[4] = {wv, 7 - wv, 8 + wv, 15 - wv};
    ushort* Pw = Pl + wv * 640;

    #pragma unroll
    for (int rf = 0; rf < 4; ++rf) {
        int p = pmap[rf];
        int r0 = p * 16;
        short8 qf0 = *(const short8*)(qb + gb16 + (r0 + lr) * 64 + lg * 8);
        short8 qf1 = *(const short8*)(qb + gb16 + (r0 + lr) * 64 + 32 + lg * 8);
        float pmv[4], lv[4];
        #pragma unroll
        for (int r = 0; r < 4; ++r) { pmv[r] = sPM[r0 + g4 + r]; lv[r] = sL[r0 + g4 + r]; }
        int jtmax = r0 >> 5;
        #pragma unroll 1
        for (int jt = 0; jt <= jtmax; ++jt) {
            int jb = jt * 32;
            f32x4 s0 = {0.f, 0.f, 0.f, 0.f}, s1 = {0.f, 0.f, 0.f, 0.f};
            {
                int j = jb + lr;
                int sw = j & 7;
                short8 k00 = *(const short8*)(Kb + j * 64 + ((lg)     ^ sw) * 8);
                short8 k01 = *(const short8*)(Kb + j * 64 + ((4 + lg) ^ sw) * 8);
                int j2 = jb + 16 + lr;
                int sw2 = j2 & 7;
                short8 k10 = *(const short8*)(Kb + j2 * 64 + ((lg)     ^ sw2) * 8);
                short8 k11 = *(const short8*)(Kb + j2 * 64 + ((4 + lg) ^ sw2) * 8);
                s0 = __builtin_amdgcn_mfma_f32_16x16x32_bf16(qf0, k00, s0, 0, 0, 0);
                s0 = __builtin_amdgcn_mfma_f32_16x16x32_bf16(qf1, k01, s0, 0, 0, 0);
                s1 = __builtin_amdgcn_mfma_f32_16x16x32_bf16(qf0, k10, s1, 0, 0, 0);
                s1 = __builtin_amdgcn_mfma_f32_16x16x32_bf16(qf1, k11, s1, 0, 0, 0);
            }
            float e0 = sE[jb + lr], e1 = sE[jb + 16 + lr];
            int j0 = jb + lr, j1 = jb + 16 + lr;
            #pragma unroll
            for (int r = 0; r < 4; ++r) {
                int i = r0 + g4 + r;
                float sc0 = (j0 <= i) ? s0[r] * 0.125f * __expf(e0 - pmv[r]) : 0.f;
                float sc1 = (j1 <= i) ? s1[r] * 0.125f * __expf(e1 - pmv[r]) : 0.f;
                csum[rf][r] += sc0 + sc1;
                Pw[(g4 + r) * 40 + lr] = bf16u(sc0);
                Pw[(g4 + r) * 40 + 16 + lr] = bf16u(sc1);
            }
            WAVE_SYNC();
            short8 pf = *(const short8*)(Pw + lr * 40 + lg * 8);
            #pragma unroll
            for (int dc = 0; dc < 4; ++dc) {
                int d = dc * 16 + lr;
                int chunk = (jt * 4 + lg) ^ (d & 7);
                short8 vf = *(const short8*)(Vt + d * 256 + chunk * 8);
                O[rf][dc] = __builtin_amdgcn_mfma_f32_16x16x32_bf16(pf, vf, O[rf][dc], 0, 0, 0);
            }
        }
        #pragma unroll
        for (int r = 0; r < 4; ++r) {
            float cs = csum[rf][r];
            cs += __shfl_xor(cs, 1); cs += __shfl_xor(cs, 2);
            cs += __shfl_xor(cs, 4); cs += __shfl_xor(cs, 8);
            float nrm = fmaxf(fabsf(cs), __expf(-(lv[r] + pmv[r]))) + 1e-6f;
            float rinv = 1.f / nrm;
            float v0 = O[rf][0][r] * rinv, v1 = O[rf][1][r] * rinv;
            float v2 = O[rf][2][r] * rinv, v3 = O[rf][3][r] * rinv;
            float s1m = v0 + v1 + v2 + v3;
            float s2m = v0 * v0 + v1 * v1 + v2 * v2 + v3 * v3;
            s1m += __shfl_xor(s1m, 1); s2m += __shfl_xor(s2m, 1);
            s1m += __shfl_xor(s1m, 2); s2m += __shfl_xor(s2m, 2);
            s1m += __shfl_xor(s1m, 4); s2m += __shfl_xor(s2m, 4);
            s1m += __shfl_xor(s1m, 8); s2m += __shfl_xor(s2m, 8);
            float mu = s1m * (1.f / 64.f);
            float var = s2m * (1.f / 64.f) - mu * mu;
            float inv = rsqrtf(var + 1e-5f);
            int grow = b * 256 + r0 + g4 + r;
            float vv[4] = {v0, v1, v2, v3};
            #pragma unroll
            for (int dc = 0; dc < 4; ++dc) {
                int ch = h * 64 + dc * 16 + lr;
                float z = ubf(xzb[(size_t)grow * 512 + 256 + ch]);
                float xnv = (vv[dc] - mu) * inv * onwv[dc];
                float val = (xnv + skipv[dc] * ubf(xcab[(size_t)grow * 256 + ch])) * siluf_(z);
                outb[(size_t)grow * 256 + ch] = bf16u(val);
            }
        }
    }
}

// ---------------- sLSTM sequential scan: deferred-LN software pipeline ----------------
__global__ __launch_bounds__(64, 1) void slstm_scan_kernel(const ushort* __restrict__ gifb,
        const ushort* __restrict__ gzob, const float* __restrict__ rec_w,
        const float* __restrict__ bias, const float* __restrict__ gnw,
        float* __restrict__ hbuf) {
    int bh = blockIdx.x;
    int b = bh >> 2, h = bh & 3;
    int l = threadIdx.x;
    int c = l & 31;
    bool lo = (l < 32);
    unsigned wpk[32];   // bf16(col 64+l) << 16 | bf16(col l)
    const float* wp = rec_w + (size_t)h * 4096 + l;
    #pragma unroll
    for (int d = 0; d < 32; ++d) {
        float w0v = wp[d * 128];
        float w1v = wp[d * 128 + 64];
        wpk[d] = ((unsigned)bf16u(w1v) << 16) | (unsigned)bf16u(w0v);
    }
    float b0 = bias[h * 128 + l];
    float b1 = bias[h * 128 + 64 + l];
    float gw = gnw[h * 32 + c];
    float cst = 0.f, nst = 0.f, hreg = 0.f;
    size_t gb = (size_t)b * SS * 256 + h * 64 + l;
    size_t hb = (size_t)b * SS * 128 + h * 32 + c;
    float pg0[4], pg1[4], ph[4];
    #pragma unroll
    for (int u = 0; u < 4; ++u) {
        pg0[u] = ubf(gifb[gb + (size_t)u * 256]);
        pg1[u] = ubf(gzob[gb + (size_t)u * 256]);
        ph[u]  = hbuf[hb + (size_t)u * 128];
    }
    float pend_hv = 0.f, pend_hcur = 0.f;
    int pend_off = 0;
    for (int s = 0; s < SS; s += 4) {
        #pragma unroll
        for (int u = 0; u < 4; ++u) {
            float a00 = 0.f, a01 = 0.f, a02 = 0.f, a03 = 0.f;
            float a10 = 0.f, a11 = 0.f, a12 = 0.f, a13 = 0.f;
            #pragma unroll
            for (int d = 0; d < 32; d += 4) {
                float h0 = rdlane(hreg, d);
                float h1 = rdlane(hreg, d + 1);
                float h2 = rdlane(hreg, d + 2);
                float h3 = rdlane(hreg, d + 3);
                unsigned p0 = wpk[d], p1 = wpk[d + 1], p2 = wpk[d + 2], p3 = wpk[d + 3];
                a00 += __uint_as_float(p0 << 16) * h0;
                a10 += __uint_as_float(p0) * h0;
                a01 += __uint_as_float(p1 << 16) * h1;
                a11 += __uint_as_float(p1) * h1;
                a02 += __uint_as_float(p2 << 16) * h2;
                a12 += __uint_as_float(p2) * h2;
                a03 += __uint_as_float(p3 << 16) * h3;
                a13 += __uint_as_float(p3) * h3;
            }
            float raw0 = pg0[u] + ((a00 + a01) + (a02 + a03)) + b0;
            float raw1 = pg1[u] + ((a10 + a11) + (a12 + a13)) + b1;
            float hcur = ph[u];
            {
                float s1 = pend_hv, s2 = pend_hv * pend_hv;
                s1 = DPPADD(s1, 0x111); s2 = DPPADD(s2, 0x111);
                s1 = DPPADD(s1, 0x112); s2 = DPPADD(s2, 0x112);
                s1 = DPPADD(s1, 0x114); s2 = DPPADD(s2, 0x114);
                s1 = DPPADD(s1, 0x118); s2 = DPPADD(s2, 0x118);
                s1 = DPPADD(s1, 0x142); s2 = DPPADD(s2, 0x142);
                s1 = DPPADD(s1, 0x143); s2 = DPPADD(s2, 0x143);
                float mu = rdlane(s1, 63) * (1.f / 64.f);
                float var = rdlane(s2, 63) * (1.f / 64.f) - mu * mu;
                float outv = (pend_hv - mu) * rsqrtf(var + 1e-5f) * gw;
                if (lo) hbuf[hb + (size_t)pend_off * 128] = pend_hcur + outv;
            }
            int s4 = s + 4 + u;
            if (s4 < SS) {
                pg0[u] = ubf(gifb[gb + (size_t)s4 * 256]);
                pg1[u] = ubf(gzob[gb + (size_t)s4 * 256]);
                ph[u]  = hbuf[hb + (size_t)s4 * 128];
            }
            i32x2 r0p = __builtin_amdgcn_permlane32_swap(__float_as_int(raw0), __float_as_int(raw0), false, false);
            i32x2 r1p = __builtin_amdgcn_permlane32_swap(__float_as_int(raw1), __float_as_int(raw1), false, false);
            float q0 = __int_as_float(lo ? r0p.y : r0p.x);
            float q1 = __int_as_float(lo ? r1p.y : r1p.x);
            float iraw = lo ? raw0 : q0;
            float zraw = lo ? raw1 : q1;
            float fraw = lo ? q0 : raw0;
            float oraw = lo ? q1 : raw1;
            float fg = __builtin_amdgcn_rcpf(1.f + __expf(-fraw));
            float ig = __expf(iraw);
            float e2z = __expf(2.f * zraw);
            float tz = 1.f - 2.f * __builtin_amdgcn_rcpf(e2z + 1.f);
            cst = fg * cst + ig * tz;
            nst = fg * nst + ig;
            float sg = __builtin_amdgcn_rcpf(1.f + __expf(-oraw));
            float hv = sg * cst * __builtin_amdgcn_rcpf(nst);
            hreg = hv;
            pend_hv = hv;
            pend_hcur = hcur;
            pend_off = s + u;
        }
    }
    {
        float s1 = pend_hv, s2 = pend_hv * pend_hv;
        s1 = DPPADD(s1, 0x111); s2 = DPPADD(s2, 0x111);
        s1 = DPPADD(s1, 0x112); s2 = DPPADD(s2, 0x112);
        s1 = DPPADD(s1, 0x114); s2 = DPPADD(s2, 0x114);
        s1 = DPPADD(s1, 0x118); s2 = DPPADD(s2, 0x118);
        s1 = DPPADD(s1, 0x142); s2 = DPPADD(s2, 0x142);
        s1 = DPPADD(s1, 0x143); s2 = DPPADD(s2, 0x143);
        float mu = rdlane(s1, 63) * (1.f / 64.f);
        float var = rdlane(s2, 63) * (1.f / 64.f) - mu * mu;
        float outv = (pend_hv - mu) * rsqrtf(var + 1e-5f) * gw;
        if (lo) hbuf[hb + (size_t)pend_off * 128] = pend_hcur + outv;
    }
}

extern "C" void kernel_launch(void* const* d_in, const int* in_sizes, int n_in,
                              void* d_out, int out_size, void* d_ws, size_t ws_size,
                              hipStream_t stream) {
    const int*   x        = (const int*)d_in[0];
    const float* emb      = (const float*)d_in[1];
    const float* m_ln_w   = (const float*)d_in[2];
    const float* m_up_w   = (const float*)d_in[3];
    const float* m_conv_w = (const float*)d_in[4];
    const float* m_conv_b = (const float*)d_in[5];
    const float* m_q_w    = (const float*)d_in[6];
    const float* m_k_w    = (const float*)d_in[7];
    const float* m_v_w    = (const float*)d_in[8];
    const float* m_ig_w   = (const float*)d_in[9];
    const float* m_ig_b   = (const float*)d_in[10];
    const float* m_fg_w   = (const float*)d_in[11];
    const float* m_fg_b   = (const float*)d_in[12];
    const float* m_on_w   = (const float*)d_in[13];
    const float* m_skip   = (const float*)d_in[14];
    const float* m_down_w = (const float*)d_in[15];
    const float* s_ln1_w  = (const float*)d_in[16];
    const float* s_conv_w = (const float*)d_in[17];
    const float* s_conv_b = (const float*)d_in[18];
    const float* s_ig_w   = (const float*)d_in[19];
    const float* s_fg_w   = (const float*)d_in[20];
    const float* s_zg_w   = (const float*)d_in[21];
    const float* s_og_w   = (const float*)d_in[22];
    const float* s_rec_w  = (const float*)d_in[23];
    const float* s_bias   = (const float*)d_in[24];
    const float* s_gn_w   = (const float*)d_in[25];
    const float* s_ln2_w  = (const float*)d_in[26];
    const float* s_ff_up_w   = (const float*)d_in[27];
    const float* s_ff_down_w = (const float*)d_in[28];
    const float* post_norm_w = (const float*)d_in[29];
    float* out = (float*)d_out;

    float* ws = (float*)d_ws;
    const size_t NR = NROWS;
    // fp32 regions
    float* h   = ws;                   // NR*128
    float* regA = h   + NR * 128;      // NR*128 f: vtb (mLSTM) / gifb (sLSTM) as NR*256 ushort
    float* regB = regA + NR * 128;     // NR*128 f: mpostb (mLSTM) / gzob (sLSTM)
    float* gip = regB + NR * 128;      // 512*256
    float* gfp = gip + 512 * 256;
    float* gL  = gfp + 512 * 256;
    float* gE  = gL  + 512 * 256;
    float* gPM = gE  + 512 * 256;
    float* extra = gPM + 512 * 256;
    // bf16 regions
    ushort* xnb   = (ushort*)extra;                    // NR*128 bf16
    ushort* xzb   = xnb + NR * 128;                    // NR*512 bf16
    ushort* xcab  = xzb + NR * 512;                    // NR*256 bf16
    ushort* qb16  = xcab + NR * 256;                   // NR*256 bf16 (xcb aliases in sLSTM)
    ushort* vb16  = qb16 + NR * 256;                   // NR*256 bf16
    ushort* upb   = vb16 + NR * 256;                   // 512*128
    ushort* downb = upb + 512 * 128;                   // 128*256
    ushort* ffupb = downb + 128 * 256;                 // 2*512*128
    ushort* ffdownb = ffupb + 2 * 512 * 128;           // 2*128*256
    ushort* sgwb  = ffdownb + 2 * 128 * 256;           // 2*2*256*128
    ushort* w16b  = sgwb + 2 * 2 * 256 * 128;          // 16*768
    // aliases (regions dead at time of use)
    ushort* kb16   = (ushort*)out;    // NR*256 bf16 (d_out; final LN overwrites)
    ushort* vtb    = (ushort*)regA;   // NR*256 bf16 (mLSTM phase)
    ushort* gifb   = (ushort*)regA;   // NR*256 bf16 (sLSTM phase)
    ushort* mpostb = (ushort*)regB;   // NR*256 bf16 (mLSTM phase)
    ushort* gzob   = (ushort*)regB;   // NR*256 bf16 (sLSTM phase)
    ushort* xcb    = qb16;            // NR*128 bf16 (qb16 dead after mlstm)

    // ---- all weight conversions in ONE launch ----
    wprep_kernel<<<(569344 + 255) / 256, 256, 0, stream>>>(m_up_w, m_down_w, s_ff_up_w,
            s_ff_down_w, s_ig_w, s_fg_w, s_zg_w, s_og_w, m_ig_w, m_fg_w,
            upb, downb, ffupb, ffdownb, sgwb, w16b);

    // ---- fused embedding + pre-LN ----
    embed_ln_kernel<<<NR / 4, 256, 0, stream>>>(x, emb, m_ln_w, h, xnb);
    // ---- mLSTM up-projection -> bf16 xzb ----
    gemm_bf16_kernel<<<dim3(NR / 128, 4), 256, 0, stream>>>(xnb, 128, upb, nullptr, xzb, 512, 128, 0);
    // ---- fused conv+silu + block-diag q,k,v (oct-per-thread) ----
    mqkv_kernel<<<(NR * 32) / 256, 256, 0, stream>>>(xzb, m_conv_w, m_conv_b,
            m_q_w, m_k_w, m_v_w, xcab, qb16, kb16, vb16);
    // ---- i/f gate projections via skinny MFMA GEMM ----
    gategemm_kernel<<<NR / 128, 256, 0, stream>>>(qb16, kb16, vb16, w16b, m_ig_b, m_fg_b, gip, gfp);
    // ---- decay prefix scan (wave-parallel) ----
    mprep_kernel<<<BB * NH, 64, 0, stream>>>(gip, gfp, gL, gE, gPM);
    // ---- V transpose ----
    vtrans_kernel<<<BB * NH * 4, 256, 0, stream>>>(vb16, vtb);
    // ---- mLSTM core via MFMA + fused mpost -> bf16 mpostb ----
    mlstm_mfma_kernel<<<BB * NH, 256, 0, stream>>>(qb16, kb16, vtb, gL, gE, gPM,
            xzb, xcab, m_on_w, m_skip, mpostb);
    // ---- down-projection + residual (fp32 accumulate into h) ----
    gemm_bf16_kernel<<<dim3(NR / 128, 1), 256, 0, stream>>>(mpostb, 256, downb, h, nullptr, 128, 256, 1);

    // ---- two sLSTM blocks ----
    for (int i2 = 0; i2 < 2; ++i2) {
        // fused pre-LN + conv+silu -> xnb, xcb
        ln_conv_s_kernel<<<BB * 4, 256, 0, stream>>>(h, s_ln1_w + i2 * 128,
                s_conv_w + i2 * 128 * 4, s_conv_b + i2 * 128, xnb, xcb);
        // both gate GEMMs in one launch
        sgate_gemm_kernel<<<dim3(NR / 128, 4), 256, 0, stream>>>(xcb, xnb,
                sgwb + (size_t)(i2 * 2 + 0) * 256 * 128, sgwb + (size_t)(i2 * 2 + 1) * 256 * 128,
                gifb, gzob);
        // scan with pipelined group-LN + residual into h
        slstm_scan_kernel<<<BB * NH, 64, 0, stream>>>(gifb, gzob,
                s_rec_w + i2 * 4 * 32 * 128, s_bias + i2 * 4 * 128, s_gn_w + i2 * 128, h);
        ln128_kernel<<<NR / 4, 256, 0, stream>>>(h, s_ln2_w + i2 * 128, nullptr, xnb);
        gemm_bf16_kernel<<<dim3(NR / 128, 4), 256, 0, stream>>>(xnb, 128, ffupb + (size_t)i2 * 512 * 128, nullptr, xzb, 512, 128, 0);
        // fused GLU + down-projection (+ residual into h)
        gemm_glu_kernel<<<NR / 128, 256, 0, stream>>>(xzb, ffdownb + (size_t)i2 * 128 * 256, h);
    }
    // ---- final LN -> out (fp32 only) ----
    ln128_kernel<<<NR / 4, 256, 0, stream>>>(h, post_norm_w, out, nullptr);
}